// Round 7
// baseline (326.891 us; speedup 1.0000x reference)
//
#include <hip/hip_runtime.h>
#include <hip/hip_bf16.h>
#include <math.h>

#define NH 16
#define NOPE 128
#define ROPE 64
#define VDIM 128
#define HD 192          // HEAD_DIM
#define SEQ 2048
#define DIM 2048
#define QKD (NH * HD)   // 3072
#define VD  (NH * VDIM) // 2048
#define QKVS 8192       // fused q|k|v row stride (shorts): [q 3072][k 3072][v 2048]

typedef __attribute__((ext_vector_type(8))) short short8;   // 8 bf16 = 4 VGPRs
typedef __attribute__((ext_vector_type(4))) short short4v;
typedef __attribute__((ext_vector_type(4))) float f32x4;
typedef unsigned int u32;

// s_waitcnt immediates (gfx9 encoding: vmcnt[3:0]@0, expcnt@4, lgkmcnt@8, vmcnt[5:4]@14)
#define WAIT_VM8  0x0F78   // vmcnt(8)
#define WAIT_VM6  0x0F76   // vmcnt(6)
#define WAIT_VM4  0x0F74   // vmcnt(4)
#define WAIT_VM0  0x0F70   // vmcnt(0)
#define WAIT_LGKM 0xC07F   // lgkmcnt(0), vmcnt/exp no-wait

static __device__ inline short f2bf(float f) {
  union { float f; unsigned u; } v; v.f = f;
  unsigned r = (v.u + 0x7fffu + ((v.u >> 16) & 1u)) >> 16;
  return (short)r;
}
static __device__ inline float bf2f(unsigned short u) {
  union { unsigned u; float f; } v; v.u = ((unsigned)u) << 16;
  return v.f;
}

// async global->LDS, 16B/lane. LDS dest = wave-uniform base + lane*16.
static __device__ __forceinline__ void gload16(const short* g, short* l) {
  __builtin_amdgcn_global_load_lds(
      (const __attribute__((address_space(1))) u32*)g,
      (__attribute__((address_space(3))) u32*)l, 16, 0, 0);
}

// ---------------------------------------------------------------------------
// 256x256 bf16 GEMM, C = A * B^T. R7: 2 phases/K-tile (was 4), 32 MFMA per
// barrier-pair (was 16) -> barriers/tile 8->4, lgkm drains 4->2.
// Stage ladder (unit staged one barrier after its region's last reader):
//   T.PhaseA reads A[p][0],B[p][0]; stages {A1,B1}(T+1)   [regions last read T-1.PhB]
//   T.PhaseB reads A[p][1],B[p][1]; stages {A0,B0}(T+2)   [regions last read T.PhA]
// vmcnt(8) at EVERY phase end: queue = 12 -> drains exactly the 4 loads the
// next phase reads; 8 loads always in flight mid-loop (never drains to 0).
// XCD partition 8Mx4N (R6): footprint 12 MB/XCD, B read from HBM once.
// ---------------------------------------------------------------------------

#define RDA(pp, hh, mh) do { \
  const char* Lb_ = Lsm + ((pp) * 32768) + ((hh) * 16384) + aoff; \
  afr[(mh) * 4 + 0] = *(const short8*)(Lb_ + ((mh) * 4096) + 0); \
  afr[(mh) * 4 + 1] = *(const short8*)(Lb_ + ((mh) * 4096) + 1024); \
  afr[(mh) * 4 + 2] = *(const short8*)(Lb_ + ((mh) * 4096) + 2048); \
  afr[(mh) * 4 + 3] = *(const short8*)(Lb_ + ((mh) * 4096) + 3072); \
} while (0)

#define RDB(pp, hh) do { \
  const char* Lb_ = Lsm + 65536 + ((pp) * 32768) + ((hh) * 16384) + boff; \
  bfr[0] = *(const short8*)(Lb_ + 0); \
  bfr[1] = *(const short8*)(Lb_ + 1024); \
  bfr[2] = *(const short8*)(Lb_ + 2048); \
  bfr[3] = *(const short8*)(Lb_ + 3072); \
} while (0)

#define SA(kt, h) do { \
  char* d_ = Lsm + (((kt) & 1) * 32768) + ((h) * 16384) + wv * 1024; \
  gload16(gA0 + (kt) * 64 + (h) * 32, (short*)d_); \
  gload16(gA1 + (kt) * 64 + (h) * 32, (short*)(d_ + 8192)); \
} while (0)

#define SB(kt, h) do { \
  char* d_ = Lsm + 65536 + (((kt) & 1) * 32768) + ((h) * 16384) + wv * 1024; \
  gload16(gB0 + (kt) * 64 + (h) * 32, (short*)d_); \
  gload16(gB1 + (kt) * 64 + (h) * 32, (short*)(d_ + 8192)); \
} while (0)

#define MFMA1(mi, ni) \
  acc[mi][ni] = __builtin_amdgcn_mfma_f32_16x16x32_bf16(afr[mi], bfr[ni], acc[mi][ni], 0, 0, 0)

// 32 MFMAs: n outer, m inner (8 independent ops between acc reuse)
#define MM2() do { \
  MFMA1(0,0); MFMA1(1,0); MFMA1(2,0); MFMA1(3,0); \
  MFMA1(4,0); MFMA1(5,0); MFMA1(6,0); MFMA1(7,0); \
  MFMA1(0,1); MFMA1(1,1); MFMA1(2,1); MFMA1(3,1); \
  MFMA1(4,1); MFMA1(5,1); MFMA1(6,1); MFMA1(7,1); \
  MFMA1(0,2); MFMA1(1,2); MFMA1(2,2); MFMA1(3,2); \
  MFMA1(4,2); MFMA1(5,2); MFMA1(6,2); MFMA1(7,2); \
  MFMA1(0,3); MFMA1(1,3); MFMA1(2,3); MFMA1(3,3); \
  MFMA1(4,3); MFMA1(5,3); MFMA1(6,3); MFMA1(7,3); \
} while (0)

#define GBAR() __builtin_amdgcn_s_barrier()
#define GLGKM0() __builtin_amdgcn_s_waitcnt(WAIT_LGKM)
#define GPRIO1() __builtin_amdgcn_s_setprio(1)
#define GPRIO0() __builtin_amdgcn_s_setprio(0)
#define GNOP ((void)0)

// One K-tile = 2 phases. S1,S2 staged in PhaseA; S3,S4 in PhaseB.
#define TILE2(pp, S1, S2, W1, S3, S4, W2) do { \
  RDA(pp, 0, 0); RDA(pp, 0, 1); RDB(pp, 0); S1; S2; \
  GBAR(); GLGKM0(); GPRIO1(); MM2(); GPRIO0(); W1; GBAR(); \
  RDA(pp, 1, 0); RDA(pp, 1, 1); RDB(pp, 1); S3; S4; \
  GBAR(); GLGKM0(); GPRIO1(); MM2(); GPRIO0(); W2; GBAR(); \
} while (0)

__global__ __launch_bounds__(512, 2) void gemm256_bt(
    const short* __restrict__ A, const short* __restrict__ B,
    short* __restrict__ C, int K, int lda, int ldb, int ldc) {
  __shared__ __align__(16) char Lsm[131072];

  const int tid = threadIdx.x;
  const int lane = tid & 63;
  const int l15 = lane & 15;
  const int quad = lane >> 4;      // 0..3
  const int wv = tid >> 6;         // 0..7
  const int wr = wv >> 2, wc = wv & 3;

  // 8Mx4N per-XCD partition (R6).
  const int bid = blockIdx.x;
  const int xcd = bid & 7;
  const int idx = bid >> 3;              // 0..31 within XCD
  const int m0 = (idx & 7) * 256;        // 8 M panels
  const int n0 = (xcd * 4 + (idx >> 3)) * 256;  // 4 N panels per XCD

  const short* gA0 = A + (size_t)(m0 + wv * 16 + l15) * lda + quad * 8;
  const short* gA1 = gA0 + (size_t)128 * lda;
  const short* gB0 = B + (size_t)(n0 + wv * 16 + l15) * ldb + quad * 8;
  const short* gB1 = gB0 + (size_t)128 * ldb;

  const int aoff = wr * 8192 + lane * 16;
  const int boff = wc * 4096 + lane * 16;

  f32x4 acc[8][4];
#pragma unroll
  for (int i = 0; i < 8; ++i)
#pragma unroll
    for (int j = 0; j < 4; ++j) acc[i][j] = (f32x4)(0.f);
  short8 afr[8], bfr[4];

  const int NT = K >> 6;   // even, >= 4

  // prologue: tile0 all 4 units + tile1 {A0,B0} = 12 loads/thread.
  // vmcnt(8) drains tile0 {A0,B0}; 8 loads stay in flight (steady-state entry).
  SA(0, 0); SB(0, 0); SA(0, 1); SB(0, 1);
  SA(1, 0); SB(1, 0);
  __builtin_amdgcn_s_waitcnt(WAIT_VM8);
  GBAR();

  int kt = 0;
  for (; kt + 4 <= NT; kt += 2) {
    TILE2(0, SA(kt + 1, 1), SB(kt + 1, 1), __builtin_amdgcn_s_waitcnt(WAIT_VM8),
             SA(kt + 2, 0), SB(kt + 2, 0), __builtin_amdgcn_s_waitcnt(WAIT_VM8));
    TILE2(1, SA(kt + 2, 1), SB(kt + 2, 1), __builtin_amdgcn_s_waitcnt(WAIT_VM8),
             SA(kt + 3, 0), SB(kt + 3, 0), __builtin_amdgcn_s_waitcnt(WAIT_VM8));
  }
  // tail: tile NT-2 stages {A1,B1}(NT-1) then drains; tile NT-1 stages nothing.
  TILE2(0, SA(kt + 1, 1), SB(kt + 1, 1), __builtin_amdgcn_s_waitcnt(WAIT_VM8),
           GNOP, GNOP, __builtin_amdgcn_s_waitcnt(WAIT_VM4));
  TILE2(1, GNOP, GNOP, __builtin_amdgcn_s_waitcnt(WAIT_VM0),
           GNOP, GNOP, GNOP);

#pragma unroll
  for (int m = 0; m < 8; ++m) {
    const size_t rb = (size_t)(m0 + wr * 128 + m * 16 + quad * 4) * ldc +
                      n0 + wc * 64 + l15;
#pragma unroll
    for (int n = 0; n < 4; ++n)
#pragma unroll
      for (int r = 0; r < 4; ++r)
        C[rb + (size_t)r * ldc + n * 16] = f2bf(acc[m][n][r]);
  }
}

// ---------------------------------------------------------------------------
// bf16 MFMA GEMM v2 (128^2): kept for the output projection.
// ---------------------------------------------------------------------------
template <bool BF16OUT>
__global__ __launch_bounds__(256) void gemm_bt(
    const short* __restrict__ A, const short* __restrict__ B,
    void* __restrict__ Cv, int K, int lda, int ldb, int ldc, float oscale) {
  __shared__ __align__(16) short Ls[4][2][4096];

  const int tid = threadIdx.x;
  const int lane = tid & 63;
  const int wave = tid >> 6;
  const int wr = wave >> 1, wc = wave & 1;
  const int lane15 = lane & 15, quad = lane >> 4;
  const int m0 = blockIdx.y * 128, n0 = blockIdx.x * 128;

  const short* gA[4]; const short* gB[4];
#pragma unroll
  for (int i = 0; i < 4; ++i) {
    int gidx = i * 64 + lane;
    int r = gidx >> 2, p = gidx & 3;
    int g = (p ^ ((r >> 1) & 3)) * 8;
    gA[i] = A + (size_t)(m0 + wr * 64 + r) * lda + g;
    gB[i] = B + (size_t)(n0 + wc * 64 + r) * ldb + g;
  }

  f32x4 acc[4][4];
#pragma unroll
  for (int i = 0; i < 4; ++i)
#pragma unroll
    for (int j = 0; j < 4; ++j) acc[i][j] = (f32x4)(0.f);

#pragma unroll
  for (int i = 0; i < 4; ++i) gload16(gA[i], &Ls[wave][0][i * 512]);
#pragma unroll
  for (int i = 0; i < 4; ++i) gload16(gB[i], &Ls[wave][0][2048 + i * 512]);

  const int rsw = (lane15 >> 1) & 3;
  for (int k0 = 0; k0 < K; k0 += 32) {
    const int cur = (k0 >> 5) & 1;
    __builtin_amdgcn_s_waitcnt(WAIT_LGKM);
    if (k0 + 32 < K) {
      const int nxt = cur ^ 1;
#pragma unroll
      for (int i = 0; i < 4; ++i) gload16(gA[i] + k0 + 32, &Ls[wave][nxt][i * 512]);
#pragma unroll
      for (int i = 0; i < 4; ++i) gload16(gB[i] + k0 + 32, &Ls[wave][nxt][2048 + i * 512]);
      __builtin_amdgcn_s_waitcnt(WAIT_VM8);
    } else {
      __builtin_amdgcn_s_waitcnt(WAIT_VM0);
    }
    const short* bufp = &Ls[wave][cur][0];
    short8 af[4], bfv[4];
#pragma unroll
    for (int i = 0; i < 4; ++i)
      af[i] = *(const short8*)&bufp[(i * 16 + lane15) * 32 + (quad ^ rsw) * 8];
#pragma unroll
    for (int j = 0; j < 4; ++j)
      bfv[j] = *(const short8*)&bufp[2048 + (j * 16 + lane15) * 32 + (quad ^ rsw) * 8];
#pragma unroll
    for (int i = 0; i < 4; ++i)
#pragma unroll
      for (int j = 0; j < 4; ++j)
        acc[i][j] = __builtin_amdgcn_mfma_f32_16x16x32_bf16(af[i], bfv[j], acc[i][j], 0, 0, 0);
  }

#pragma unroll
  for (int i = 0; i < 4; ++i)
#pragma unroll
    for (int j = 0; j < 4; ++j)
#pragma unroll
      for (int r = 0; r < 4; ++r) {
        size_t idx = (size_t)(m0 + wr * 64 + i * 16 + quad * 4 + r) * ldc +
                     n0 + wc * 64 + j * 16 + lane15;
        if (BF16OUT)
          ((short*)Cv)[idx] = f2bf(acc[i][j][r] * oscale);
        else
          ((float*)Cv)[idx] = acc[i][j][r];
      }
}

// ---------------------------------------------------------------------------
// RoPE in-place on fused qkv bf16 [SEQ][QKVS].
// ---------------------------------------------------------------------------
__global__ __launch_bounds__(256) void rope_qk(
    short* __restrict__ qk, const float* __restrict__ cosf, const float* __restrict__ sinf) {
  int idx = blockIdx.x * blockDim.x + threadIdx.x;
  int j = idx & 31;
  int h = (idx >> 5) & (NH - 1);
  int s = idx >> 9;
  if (s >= SEQ) return;

  float c = cosf[s * 32 + j];
  float sn = sinf[s * 32 + j];
  size_t rowb = (size_t)s * QKVS + h * HD + NOPE + 2 * j;

  u32* pq = (u32*)(qk + rowb);
  u32 w = *pq;
  float a = bf2f((unsigned short)(w & 0xffff));
  float b = bf2f((unsigned short)(w >> 16));
  *pq = (u32)(unsigned short)f2bf(a * c - b * sn) |
        ((u32)(unsigned short)f2bf(a * sn + b * c) << 16);

  u32* pk = (u32*)(qk + rowb + QKD);
  w = *pk;
  a = bf2f((unsigned short)(w & 0xffff));
  b = bf2f((unsigned short)(w >> 16));
  *pk = (u32)(unsigned short)f2bf(a * c - b * sn) |
        ((u32)(unsigned short)f2bf(a * sn + b * c) << 16);
}

// ---------------------------------------------------------------------------
// Converts.
// ---------------------------------------------------------------------------
__global__ __launch_bounds__(256) void bf16_convert(
    const float* __restrict__ in, short* __restrict__ out, int n4) {
  int i = blockIdx.x * 256 + threadIdx.x;
  if (i >= n4) return;
  float4 f = ((const float4*)in)[i];
  short4v o;
  o.x = f2bf(f.x); o.y = f2bf(f.y); o.z = f2bf(f.z); o.w = f2bf(f.w);
  ((short4v*)out)[i] = o;
}

__global__ __launch_bounds__(256) void conv_wqkv(
    const float* __restrict__ wq, const float* __restrict__ wk,
    const float* __restrict__ wv, short* __restrict__ wqkv, int n4) {
  int i = blockIdx.x * 256 + threadIdx.x;
  if (i >= n4) return;
  int row = i >> 9;
  float4 f;
  if (row < QKD) f = ((const float4*)wq)[i];
  else if (row < 2 * QKD) f = ((const float4*)wk)[i - QKD * (DIM / 4)];
  else f = ((const float4*)wv)[i - 2 * QKD * (DIM / 4)];
  short4v o;
  o.x = f2bf(f.x); o.y = f2bf(f.y); o.z = f2bf(f.z); o.w = f2bf(f.w);
  ((short4v*)wqkv)[i] = o;
}

// ---------------------------------------------------------------------------
// v bf16 -> vtb bf16 [h][d][t] transpose.
// ---------------------------------------------------------------------------
__global__ __launch_bounds__(256) void vt_bf16(
    const short* __restrict__ vb, short* __restrict__ vtb) {
  __shared__ short tile[64][74];
  const int t0 = blockIdx.x * 64;
  const int c0 = blockIdx.y * 64;
  const int tid = threadIdx.x;
#pragma unroll
  for (int i = 0; i < 16; ++i) {
    int idx = i * 256 + tid;
    int r = idx >> 6, c = idx & 63;
    tile[r][c] = vb[(size_t)(t0 + r) * QKVS + c0 + c];
  }
  __syncthreads();
  const int h = c0 >> 7;
  const int dbase = c0 & 127;
#pragma unroll
  for (int i = 0; i < 16; ++i) {
    int idx = i * 256 + tid;
    int d = idx >> 6, t = idx & 63;
    vtb[(size_t)h * VDIM * SEQ + (size_t)(dbase + d) * SEQ + t0 + t] = tile[t][d];
  }
}

// ---------------------------------------------------------------------------
// Split-T flash attention v4 (unchanged from R5): BQ=128 via 8 waves.
// LDS: 24576 (K) + 16384 (V) + 19456 (Ps) = 60416 -> 2 blocks/CU.
// ---------------------------------------------------------------------------
#define BQ 128
#define BT 64
#define CHT 8
#define PSTR 76
#define MFIX 8.0f

__global__ __launch_bounds__(512, 4) void attn_part(
    const short* __restrict__ qk,   // [SEQ][QKVS] bf16
    const short* __restrict__ vtb,  // [NH][VDIM][SEQ] bf16
    short* __restrict__ Opart,      // [640][128][128] bf16
    float* __restrict__ lpart)      // [640][128] fp32
{
  __shared__ __align__(16) short Ks[BT * 192];      // 24576 B
  __shared__ __align__(16) short Vt[VDIM * BT];     // 16384 B
  __shared__ __align__(16) short Ps[8 * 16 * PSTR]; // 19456 B

  // decode: xcd owns heads {xcd, xcd+8}; heavy qt-blocks first.
  const int xcd = blockIdx.x;          // 0..7
  const int i0 = blockIdx.y;           // 0..79
  const int h = xcd + ((i0 >= 40) ? 8 : 0);
  int jj = (i0 >= 40) ? (i0 - 40) : i0;  // 0..39
  int qtb = 15;
  while (jj >= (qtb >> 2) + 1) { jj -= (qtb >> 2) + 1; --qtb; }
  const int chk = jj;                   // 0..(qtb>>2)

  const int tid = threadIdx.x;
  const int wave = tid >> 6;            // 0..7
  const int lane = tid & 63;
  const int lane15 = lane & 15;
  const int quad = lane >> 4;
  const int g = qtb >> 2;
  const int slot = h * 40 + (g + 1) * (2 * g + (qtb & 3)) + chk;
  const int R0 = qtb * BQ;
  const int NT = 2 * qtb + 2;
  const int kt_beg = chk * CHT;
  const int kt_end = min(kt_beg + CHT, NT);
  const float scale = 0.072168784f;  // 1/sqrt(192)

  // Q A-frags: wave's 16 rows
  const int qrow = R0 + wave * 16 + lane15;
  short8 qf[6];
  const short* qbase = qk + (size_t)qrow * QKVS + h * HD + quad * 8;
#pragma unroll
  for (int kc = 0; kc < 6; ++kc) qf[kc] = *(const short8*)(qbase + kc * 32);

  // staging descriptors (XOR-swizzled), 512 threads: K 3/thread, V 2/thread
  const short* kb = qk + QKD;
  int lKoff[3]; const short* gK[3];
#pragma unroll
  for (int i = 0; i < 3; ++i) {
    int id = i * 512 + tid;
    int row = id / 24, cX = id - row * 24;
    int ch = cX ^ (row & 7);
    lKoff[i] = id * 8;
    gK[i] = kb + (size_t)row * QKVS + h * HD + ch * 8;
  }
  const short* gV[2]; short* lV[2];
#pragma unroll
  for (int i = 0; i < 2; ++i) {
    int id = i * 512 + tid;
    int row = id >> 3, cX = id & 7;
    int ch = cX ^ (row & 7);
    lV[i] = &Vt[id * 8];
    gV[i] = vtb + (size_t)h * VDIM * SEQ + (size_t)row * SEQ + ch * 8;
  }

  f32x4 oacc[8];
#pragma unroll
  for (int i = 0; i < 8; ++i) oacc[i] = (f32x4)(0.f);
  float lsum[4] = {0.f, 0.f, 0.f, 0.f};

  short* pw = &Ps[wave * 16 * PSTR];

  for (int kt = kt_beg; kt < kt_end; ++kt) {
    const int t0 = kt * BT;
    __syncthreads();
#pragma unroll
    for (int i = 0; i < 3; ++i) gload16(gK[i] + (size_t)t0 * QKVS, &Ks[lKoff[i]]);
#pragma unroll
    for (int i = 0; i < 2; ++i) gload16(gV[i] + t0, lV[i]);
    __syncthreads();

    // S = Q K^T
    f32x4 sacc[4];
    __builtin_amdgcn_s_setprio(1);
#pragma unroll
    for (int c = 0; c < 4; ++c) {
      sacc[c] = (f32x4)(0.f);
      const int row = c * 16 + lane15;
#pragma unroll
      for (int kc = 0; kc < 6; ++kc) {
        int cX = (4 * kc + quad) ^ (lane15 & 7);
        short8 kf = *(const short8*)&Ks[row * 192 + cX * 8];
        sacc[c] = __builtin_amdgcn_mfma_f32_16x16x32_bf16(qf[kc], kf, sacc[c], 0, 0, 0);
      }
    }
    __builtin_amdgcn_s_setprio(0);

    if (kt >= 2 * qtb) {  // tiles possibly crossing the diagonal
#pragma unroll
      for (int c = 0; c < 4; ++c)
#pragma unroll
        for (int r = 0; r < 4; ++r) {
          int tg = t0 + c * 16 + lane15;
          int qg = R0 + wave * 16 + quad * 4 + r;
          if (tg > qg) sacc[c][r] = -1e30f;
        }
    }

    // P = exp(S*scale - MFIX); partial row sums; stage P bf16 (wave-local)
#pragma unroll
    for (int c = 0; c < 4; ++c)
#pragma unroll
      for (int r = 0; r < 4; ++r) {
        float p = __expf(sacc[c][r] * scale - MFIX);
        lsum[r] += p;
        pw[(quad * 4 + r) * PSTR + c * 16 + lane15] = f2bf(p);
      }

    short8 pf0 = *(const short8*)&pw[lane15 * PSTR + quad * 8];
    short8 pf1 = *(const short8*)&pw[lane15 * PSTR + 32 + quad * 8];
    __builtin_amdgcn_s_setprio(1);
#pragma unroll
    for (int ch = 0; ch < 8; ++ch) {
      const int row = ch * 16 + lane15;
      int cX0 = quad ^ (lane15 & 7);
      int cX1 = (4 + quad) ^ (lane15 & 7);
      short8 vf0 = *(const short8*)&Vt[row * 64 + cX0 * 8];
      short8 vf1 = *(const short8*)&Vt[row * 64 + cX1 * 8];
      oacc[ch] = __builtin_amdgcn_mfma_f32_16x16x32_bf16(pf0, vf0, oacc[ch], 0, 0, 0);
      oacc[ch] = __builtin_amdgcn_mfma_f32_16x16x32_bf16(pf1, vf1, oacc[ch], 0, 0, 0);
    }
    __builtin_amdgcn_s_setprio(0);
  }

  // epilogue: write unnormalized partials ([128][128] per slot)
  short* op = Opart + (size_t)slot * (128 * 128);
#pragma unroll
  for (int ch = 0; ch < 8; ++ch)
#pragma unroll
    for (int r = 0; r < 4; ++r)
      op[(wave * 16 + quad * 4 + r) * 128 + ch * 16 + lane15] = f2bf(oacc[ch][r]);

  float red[4];
#pragma unroll
  for (int r = 0; r < 4; ++r) {
    float s = lsum[r];
    s += __shfl_xor(s, 1, 64);
    s += __shfl_xor(s, 2, 64);
    s += __shfl_xor(s, 4, 64);
    s += __shfl_xor(s, 8, 64);
    red[r] = s;
  }
  if (lane15 == 0) {
#pragma unroll
    for (int r = 0; r < 4; ++r)
      lpart[(size_t)slot * 128 + wave * 16 + quad * 4 + r] = red[r];
  }
}

// ---------------------------------------------------------------------------
// Phase B: sum chunk partials, normalize, write aob (into v-cols of qkv).
// blockIdx.x = qt64 (0..31, 64-row half of a 128-row qt-block), .y = head.
// ---------------------------------------------------------------------------
__global__ __launch_bounds__(256) void attn_combine(
    const short* __restrict__ Opart, const float* __restrict__ lpart,
    short* __restrict__ aob) {   // aob = qkv + 6144, row stride QKVS
  const int qt64 = blockIdx.x, h = blockIdx.y;
  const int qtb = qt64 >> 1;
  const int half = qt64 & 1;
  const int g = qtb >> 2;
  const int nact = g + 1;
  const int base = h * 40 + (g + 1) * (2 * g + (qtb & 3));
  const int tid = threadIdx.x;
  const int row = tid >> 2;            // 0..63
  const int cg = (tid & 3) * 32;

  float acc[32];
#pragma unroll
  for (int e = 0; e < 32; ++e) acc[e] = 0.f;
  float lsum = 0.f;

  for (int c = 0; c < nact; ++c) {
    const short* sp = Opart + (size_t)(base + c) * (128 * 128) +
                      (half * 64 + row) * 128 + cg;
    lsum += lpart[(size_t)(base + c) * 128 + half * 64 + row];
#pragma unroll
    for (int gg = 0; gg < 4; ++gg) {
      short8 vv = *(const short8*)(sp + gg * 8);
#pragma unroll
      for (int e = 0; e < 8; ++e) acc[gg * 8 + e] += bf2f((unsigned short)vv[e]);
    }
  }

  float inv = 1.f / lsum;
#pragma unroll
  for (int gg = 0; gg < 4; ++gg) {
    short8 ov;
#pragma unroll
    for (int e = 0; e < 8; ++e) ov[e] = f2bf(acc[gg * 8 + e] * inv);
    *(short8*)(aob + (size_t)(qt64 * 64 + row) * QKVS + h * 128 + cg + gg * 8) = ov;
  }
}

// ---------------------------------------------------------------------------
// Workspace (bytes), peak 75,497,472 (< proven 79,691,776):
//   [0,        8388608)  xb  -> wo_b (after qkv gemm)
//   [8388608, 41943040)  wqkv -> {vtb@8388608, Opart@16777216 (640x128x128x2
//                        = 20,971,520), lpart@37748736 (640x128x4 = 327,680)}
//   [41943040,75497472)  qkv bf16 [2048][8192]; aob lives in v-cols (6144+)
// ---------------------------------------------------------------------------
extern "C" void kernel_launch(void* const* d_in, const int* in_sizes, int n_in,
                              void* d_out, int out_size, void* d_ws, size_t ws_size,
                              hipStream_t stream) {
  const float* x  = (const float*)d_in[0];
  const float* wq = (const float*)d_in[1];
  const float* wk = (const float*)d_in[2];
  const float* wv = (const float*)d_in[3];
  const float* wo = (const float*)d_in[4];
  const float* fc = (const float*)d_in[5];
  const float* fs = (const float*)d_in[6];

  char* ws8 = (char*)d_ws;
  short* xb    = (short*)(ws8 + 0);
  short* wo_b  = (short*)(ws8 + 0);
  short* wqkv  = (short*)(ws8 + 8388608);
  short* vtb   = (short*)(ws8 + 8388608);
  short* Opart = (short*)(ws8 + 16777216);
  float* lpart = (float*)(ws8 + 37748736);
  short* qkv   = (short*)(ws8 + 41943040);
  float* out   = (float*)d_out;

  const int NX4 = DIM * DIM / 4;
  const int NQKV4 = QKVS * DIM / 4;
  const int ROPE_GRID = (SEQ * NH * 32) / 256;

  bf16_convert<<<(NX4 + 255) / 256, 256, 0, stream>>>(x, xb, NX4);
  conv_wqkv<<<(NQKV4 + 255) / 256, 256, 0, stream>>>(wq, wk, wv, wqkv, NQKV4);

  // fused QKV projection: qkv [2048][8192] via 256^2 2-phase kernel.
  gemm256_bt<<<dim3((QKVS / 256) * (SEQ / 256)), 512, 0, stream>>>(
      xb, wqkv, qkv, DIM, DIM, DIM, QKVS);
  rope_qk<<<ROPE_GRID, 256, 0, stream>>>(qkv, fc, fs);
  vt_bf16<<<dim3(SEQ / 64, VD / 64), 256, 0, stream>>>(qkv + 2 * QKD, vtb);

  // wo convert (xb dead after qkv gemm)
  bf16_convert<<<(NX4 + 255) / 256, 256, 0, stream>>>(wo, wo_b, NX4);

  // split-T attention: grid (8 xcd, 80 chunks) = 640 blocks, 512 threads
  attn_part<<<dim3(8, 80), 512, 0, stream>>>(qkv, vtb, Opart, lpart);
  attn_combine<<<dim3(SEQ / 64, NH), 256, 0, stream>>>(Opart, lpart, qkv + 2 * QKD);

  // output projection (A = aob in v-cols, lda = QKVS)
  gemm_bt<false><<<dim3(DIM / 128, SEQ / 128), 256, 0, stream>>>(
      qkv + 2 * QKD, wo_b, out, DIM, QKVS, DIM, DIM, 1.0f);
}

// Round 8
// 314.532 us; speedup vs baseline: 1.0393x; 1.0393x over previous
//
#include <hip/hip_runtime.h>
#include <hip/hip_bf16.h>
#include <math.h>

#define NH 16
#define NOPE 128
#define ROPE 64
#define VDIM 128
#define HD 192          // HEAD_DIM
#define SEQ 2048
#define DIM 2048
#define QKD (NH * HD)   // 3072
#define VD  (NH * VDIM) // 2048
#define QKVS 8192       // fused q|k|v row stride (shorts): [q 3072][k 3072][v 2048]

typedef __attribute__((ext_vector_type(8))) short short8;   // 8 bf16 = 4 VGPRs
typedef __attribute__((ext_vector_type(4))) short short4v;
typedef __attribute__((ext_vector_type(4))) float f32x4;
typedef unsigned int u32;

// s_waitcnt immediates (gfx9 encoding: vmcnt[3:0]@0, expcnt@4, lgkmcnt@8, vmcnt[5:4]@14)
#define WAIT_VM8  0x0F78   // vmcnt(8)
#define WAIT_VM6  0x0F76   // vmcnt(6)
#define WAIT_VM4  0x0F74   // vmcnt(4)
#define WAIT_VM0  0x0F70   // vmcnt(0)
#define WAIT_LGKM 0xC07F   // lgkmcnt(0), vmcnt/exp no-wait

static __device__ inline short f2bf(float f) {
  union { float f; unsigned u; } v; v.f = f;
  unsigned r = (v.u + 0x7fffu + ((v.u >> 16) & 1u)) >> 16;
  return (short)r;
}
static __device__ inline float bf2f(unsigned short u) {
  union { unsigned u; float f; } v; v.u = ((unsigned)u) << 16;
  return v.f;
}

// async global->LDS, 16B/lane. LDS dest = wave-uniform base + lane*16.
static __device__ __forceinline__ void gload16(const short* g, short* l) {
  __builtin_amdgcn_global_load_lds(
      (const __attribute__((address_space(1))) u32*)g,
      (__attribute__((address_space(3))) u32*)l, 16, 0, 0);
}

// ---------------------------------------------------------------------------
// 256x256 bf16 GEMM, C = A * B^T.  R8: m201-faithful LDS layout + staging.
//  - LDS per operand: row-major [256 rows][64 K-shorts] bf16 with XOR swizzle
//    byte_col ^= (row&7)<<4, realized as: LINEAR gload_lds dest + inverse-
//    swizzled GLOBAL source + swizzled ds_read (rule #21). The source XOR
//    permutes 16B chunks within each 128B row -> a wave's staging load still
//    reads 8 full cache lines (coalesced), vs R7's 16x64B scatter.
//  - ds_read conflict-free: per b128, all 32 banks uniformly 8-pass.
//  - 4 phases/K-tile (16 MFMA each); chunk-lifetime staging ladder:
//    t.P1 stages G2(t+1)={A-c1,c3,B-c2,c3}; t.P4 stages G1(t+2)={A-c0,c2,
//    B-c0,c1}. One vmcnt(4)/tile at P4: 12 outstanding -> proves tile t+1's 8,
//    keeps 4 in flight (never 0 mid-loop).
//  - XCD partition 8Mx4N (R6): footprint 12 MB/XCD, B read from HBM once.
// ---------------------------------------------------------------------------

#define LSA(pp) (Lsm + (pp) * 65536)
#define LSB(pp) (Lsm + (pp) * 65536 + 32768)

#define RDA(pp, kh, mh) do { \
  const char* p_ = LSA(pp) + abase + (mh) * 8192 + ((kh) ? cx1 : cx0); \
  afr[(mh) * 4 + 0] = *(const short8*)(p_ + 0); \
  afr[(mh) * 4 + 1] = *(const short8*)(p_ + 2048); \
  afr[(mh) * 4 + 2] = *(const short8*)(p_ + 4096); \
  afr[(mh) * 4 + 3] = *(const short8*)(p_ + 6144); \
} while (0)

#define RDB(pp, kh) do { \
  const char* p_ = LSB(pp) + bbase + ((kh) ? cx1 : cx0); \
  bfr[0] = *(const short8*)(p_ + 0); \
  bfr[1] = *(const short8*)(p_ + 2048); \
  bfr[2] = *(const short8*)(p_ + 4096); \
  bfr[3] = *(const short8*)(p_ + 6144); \
} while (0)

#define SGA(kt, c) gload16(srcA[c] + (kt) * 64, (short*)(LSA((kt) & 1) + ((c) * 512 + tid) * 16))
#define SGB(kt, c) gload16(srcB[c] + (kt) * 64, (short*)(LSB((kt) & 1) + ((c) * 512 + tid) * 16))
#define G1S(kt) do { SGA(kt, 0); SGA(kt, 2); SGB(kt, 0); SGB(kt, 1); } while (0)
#define G2S(kt) do { SGA(kt, 1); SGA(kt, 3); SGB(kt, 2); SGB(kt, 3); } while (0)

#define MFMA1(mi, ni) \
  acc[mi][ni] = __builtin_amdgcn_mfma_f32_16x16x32_bf16(afr[mi], bfr[ni], acc[mi][ni], 0, 0, 0)

#define MM(mh) do { \
  MFMA1((mh)*4+0, 0); MFMA1((mh)*4+1, 0); MFMA1((mh)*4+2, 0); MFMA1((mh)*4+3, 0); \
  MFMA1((mh)*4+0, 1); MFMA1((mh)*4+1, 1); MFMA1((mh)*4+2, 1); MFMA1((mh)*4+3, 1); \
  MFMA1((mh)*4+0, 2); MFMA1((mh)*4+1, 2); MFMA1((mh)*4+2, 2); MFMA1((mh)*4+3, 2); \
  MFMA1((mh)*4+0, 3); MFMA1((mh)*4+1, 3); MFMA1((mh)*4+2, 3); MFMA1((mh)*4+3, 3); \
} while (0)

#define GBAR() __builtin_amdgcn_s_barrier()
#define GLGKM0() __builtin_amdgcn_s_waitcnt(WAIT_LGKM)
#define GPRIO1() __builtin_amdgcn_s_setprio(1)
#define GPRIO0() __builtin_amdgcn_s_setprio(0)
#define GNOP ((void)0)

// One K-tile = 4 phases; SP1 staged in P1, SP4 + counted wait in P4.
#define TILE(pp, SP1, SP4, VMW) do { \
  RDA(pp, 0, 0); RDB(pp, 0); SP1; \
  GBAR(); GLGKM0(); GPRIO1(); MM(0); GPRIO0(); GBAR(); \
  RDA(pp, 0, 1); \
  GBAR(); GLGKM0(); GPRIO1(); MM(1); GPRIO0(); GBAR(); \
  RDA(pp, 1, 0); RDB(pp, 1); \
  GBAR(); GLGKM0(); GPRIO1(); MM(0); GPRIO0(); GBAR(); \
  RDA(pp, 1, 1); SP4; \
  GBAR(); GLGKM0(); GPRIO1(); MM(1); GPRIO0(); VMW; GBAR(); \
} while (0)

__global__ __launch_bounds__(512, 2) void gemm256_bt(
    const short* __restrict__ A, const short* __restrict__ B,
    short* __restrict__ C, int K, int lda, int ldb, int ldc) {
  __shared__ __align__(16) char Lsm[131072];

  const int tid = threadIdx.x;
  const int lane = tid & 63;
  const int l15 = lane & 15;
  const int quad = lane >> 4;      // 0..3
  const int wv = tid >> 6;         // 0..7
  const int wr = wv >> 2, wc = wv & 3;

  // 8Mx4N per-XCD partition (R6).
  const int bid = blockIdx.x;
  const int xcd = bid & 7;
  const int idx = bid >> 3;              // 0..31 within XCD
  const int m0 = (idx & 7) * 256;        // 8 M panels
  const int n0 = (xcd * 4 + (idx >> 3)) * 256;  // 4 N panels per XCD

  // staging sources: thread covers row trow of each 64-row chunk, with the
  // col chunk pre-XORed (inverse swizzle) so linear LDS = swizzled layout.
  // A wave = 8 consecutive rows x 8 permuted 16B chunks = 8 full 128B lines.
  const int trow = tid >> 3;                               // 0..63
  const int scol = ((tid & 7) * 8) ^ ((trow & 7) * 8);     // shorts
  const short* srcA[4]; const short* srcB[4];
#pragma unroll
  for (int c = 0; c < 4; ++c) {
    srcA[c] = A + (size_t)(m0 + c * 64 + trow) * lda + scol;
    srcB[c] = B + (size_t)(n0 + c * 64 + trow) * ldb + scol;
  }

  // ds_read bases (bytes): row = {wr*128|wc*64} + sub + l15; swizzled col.
  const int abase = (wr * 128 + l15) * 128;
  const int bbase = (wc * 64 + l15) * 128;
  const int cx0 = (quad * 16) ^ ((l15 & 7) * 16);          // kh = 0
  const int cx1 = (64 + quad * 16) ^ ((l15 & 7) * 16);     // kh = 1

  f32x4 acc[8][4];
#pragma unroll
  for (int i = 0; i < 8; ++i)
#pragma unroll
    for (int j = 0; j < 4; ++j) acc[i][j] = (f32x4)(0.f);
  short8 afr[8], bfr[4];

  const int NT = K >> 6;   // even, >= 4

  // prologue: tile0 fully (8) + G1(tile1) (4); vmcnt(4) proves tile0.
  G1S(0); G2S(0); G1S(1);
  __builtin_amdgcn_s_waitcnt(WAIT_VM4);
  GBAR();

  int kt = 0;
  for (; kt + 4 <= NT; kt += 2) {
    TILE(0, G2S(kt + 1), G1S(kt + 2), __builtin_amdgcn_s_waitcnt(WAIT_VM4));
    TILE(1, G2S(kt + 2), G1S(kt + 3), __builtin_amdgcn_s_waitcnt(WAIT_VM4));
  }
  // tail: kt == NT-2. P1 stages G2(NT-1); vmcnt(0) proves NT-1; last tile bare.
  TILE(0, G2S(kt + 1), GNOP, __builtin_amdgcn_s_waitcnt(WAIT_VM0));
  TILE(1, GNOP, GNOP, GNOP);

#pragma unroll
  for (int m = 0; m < 8; ++m) {
    const size_t rb = (size_t)(m0 + wr * 128 + m * 16 + quad * 4) * ldc +
                      n0 + wc * 64 + l15;
#pragma unroll
    for (int n = 0; n < 4; ++n)
#pragma unroll
      for (int r = 0; r < 4; ++r)
        C[rb + (size_t)r * ldc + n * 16] = f2bf(acc[m][n][r]);
  }
}

// ---------------------------------------------------------------------------
// bf16 MFMA GEMM v2 (128^2): kept for the output projection.
// ---------------------------------------------------------------------------
template <bool BF16OUT>
__global__ __launch_bounds__(256) void gemm_bt(
    const short* __restrict__ A, const short* __restrict__ B,
    void* __restrict__ Cv, int K, int lda, int ldb, int ldc, float oscale) {
  __shared__ __align__(16) short Ls[4][2][4096];

  const int tid = threadIdx.x;
  const int lane = tid & 63;
  const int wave = tid >> 6;
  const int wr = wave >> 1, wc = wave & 1;
  const int lane15 = lane & 15, quad = lane >> 4;
  const int m0 = blockIdx.y * 128, n0 = blockIdx.x * 128;

  const short* gA[4]; const short* gB[4];
#pragma unroll
  for (int i = 0; i < 4; ++i) {
    int gidx = i * 64 + lane;
    int r = gidx >> 2, p = gidx & 3;
    int g = (p ^ ((r >> 1) & 3)) * 8;
    gA[i] = A + (size_t)(m0 + wr * 64 + r) * lda + g;
    gB[i] = B + (size_t)(n0 + wc * 64 + r) * ldb + g;
  }

  f32x4 acc[4][4];
#pragma unroll
  for (int i = 0; i < 4; ++i)
#pragma unroll
    for (int j = 0; j < 4; ++j) acc[i][j] = (f32x4)(0.f);

#pragma unroll
  for (int i = 0; i < 4; ++i) gload16(gA[i], &Ls[wave][0][i * 512]);
#pragma unroll
  for (int i = 0; i < 4; ++i) gload16(gB[i], &Ls[wave][0][2048 + i * 512]);

  const int rsw = (lane15 >> 1) & 3;
  for (int k0 = 0; k0 < K; k0 += 32) {
    const int cur = (k0 >> 5) & 1;
    __builtin_amdgcn_s_waitcnt(WAIT_LGKM);
    if (k0 + 32 < K) {
      const int nxt = cur ^ 1;
#pragma unroll
      for (int i = 0; i < 4; ++i) gload16(gA[i] + k0 + 32, &Ls[wave][nxt][i * 512]);
#pragma unroll
      for (int i = 0; i < 4; ++i) gload16(gB[i] + k0 + 32, &Ls[wave][nxt][2048 + i * 512]);
      __builtin_amdgcn_s_waitcnt(WAIT_VM8);
    } else {
      __builtin_amdgcn_s_waitcnt(WAIT_VM0);
    }
    const short* bufp = &Ls[wave][cur][0];
    short8 af[4], bfv[4];
#pragma unroll
    for (int i = 0; i < 4; ++i)
      af[i] = *(const short8*)&bufp[(i * 16 + lane15) * 32 + (quad ^ rsw) * 8];
#pragma unroll
    for (int j = 0; j < 4; ++j)
      bfv[j] = *(const short8*)&bufp[2048 + (j * 16 + lane15) * 32 + (quad ^ rsw) * 8];
#pragma unroll
    for (int i = 0; i < 4; ++i)
#pragma unroll
      for (int j = 0; j < 4; ++j)
        acc[i][j] = __builtin_amdgcn_mfma_f32_16x16x32_bf16(af[i], bfv[j], acc[i][j], 0, 0, 0);
  }

#pragma unroll
  for (int i = 0; i < 4; ++i)
#pragma unroll
    for (int j = 0; j < 4; ++j)
#pragma unroll
      for (int r = 0; r < 4; ++r) {
        size_t idx = (size_t)(m0 + wr * 64 + i * 16 + quad * 4 + r) * ldc +
                     n0 + wc * 64 + j * 16 + lane15;
        if (BF16OUT)
          ((short*)Cv)[idx] = f2bf(acc[i][j][r] * oscale);
        else
          ((float*)Cv)[idx] = acc[i][j][r];
      }
}

// ---------------------------------------------------------------------------
// RoPE in-place on fused qkv bf16 [SEQ][QKVS].
// ---------------------------------------------------------------------------
__global__ __launch_bounds__(256) void rope_qk(
    short* __restrict__ qk, const float* __restrict__ cosf, const float* __restrict__ sinf) {
  int idx = blockIdx.x * blockDim.x + threadIdx.x;
  int j = idx & 31;
  int h = (idx >> 5) & (NH - 1);
  int s = idx >> 9;
  if (s >= SEQ) return;

  float c = cosf[s * 32 + j];
  float sn = sinf[s * 32 + j];
  size_t rowb = (size_t)s * QKVS + h * HD + NOPE + 2 * j;

  u32* pq = (u32*)(qk + rowb);
  u32 w = *pq;
  float a = bf2f((unsigned short)(w & 0xffff));
  float b = bf2f((unsigned short)(w >> 16));
  *pq = (u32)(unsigned short)f2bf(a * c - b * sn) |
        ((u32)(unsigned short)f2bf(a * sn + b * c) << 16);

  u32* pk = (u32*)(qk + rowb + QKD);
  w = *pk;
  a = bf2f((unsigned short)(w & 0xffff));
  b = bf2f((unsigned short)(w >> 16));
  *pk = (u32)(unsigned short)f2bf(a * c - b * sn) |
        ((u32)(unsigned short)f2bf(a * sn + b * c) << 16);
}

// ---------------------------------------------------------------------------
// Converts.
// ---------------------------------------------------------------------------
__global__ __launch_bounds__(256) void bf16_convert(
    const float* __restrict__ in, short* __restrict__ out, int n4) {
  int i = blockIdx.x * 256 + threadIdx.x;
  if (i >= n4) return;
  float4 f = ((const float4*)in)[i];
  short4v o;
  o.x = f2bf(f.x); o.y = f2bf(f.y); o.z = f2bf(f.z); o.w = f2bf(f.w);
  ((short4v*)out)[i] = o;
}

__global__ __launch_bounds__(256) void conv_wqkv(
    const float* __restrict__ wq, const float* __restrict__ wk,
    const float* __restrict__ wv, short* __restrict__ wqkv, int n4) {
  int i = blockIdx.x * 256 + threadIdx.x;
  if (i >= n4) return;
  int row = i >> 9;
  float4 f;
  if (row < QKD) f = ((const float4*)wq)[i];
  else if (row < 2 * QKD) f = ((const float4*)wk)[i - QKD * (DIM / 4)];
  else f = ((const float4*)wv)[i - 2 * QKD * (DIM / 4)];
  short4v o;
  o.x = f2bf(f.x); o.y = f2bf(f.y); o.z = f2bf(f.z); o.w = f2bf(f.w);
  ((short4v*)wqkv)[i] = o;
}

// ---------------------------------------------------------------------------
// v bf16 -> vtb bf16 [h][d][t] transpose.
// ---------------------------------------------------------------------------
__global__ __launch_bounds__(256) void vt_bf16(
    const short* __restrict__ vb, short* __restrict__ vtb) {
  __shared__ short tile[64][74];
  const int t0 = blockIdx.x * 64;
  const int c0 = blockIdx.y * 64;
  const int tid = threadIdx.x;
#pragma unroll
  for (int i = 0; i < 16; ++i) {
    int idx = i * 256 + tid;
    int r = idx >> 6, c = idx & 63;
    tile[r][c] = vb[(size_t)(t0 + r) * QKVS + c0 + c];
  }
  __syncthreads();
  const int h = c0 >> 7;
  const int dbase = c0 & 127;
#pragma unroll
  for (int i = 0; i < 16; ++i) {
    int idx = i * 256 + tid;
    int d = idx >> 6, t = idx & 63;
    vtb[(size_t)h * VDIM * SEQ + (size_t)(dbase + d) * SEQ + t0 + t] = tile[t][d];
  }
}

// ---------------------------------------------------------------------------
// Split-T flash attention v4 (unchanged from R5): BQ=128 via 8 waves.
// LDS: 24576 (K) + 16384 (V) + 19456 (Ps) = 60416 -> 2 blocks/CU.
// ---------------------------------------------------------------------------
#define BQ 128
#define BT 64
#define CHT 8
#define PSTR 76
#define MFIX 8.0f

__global__ __launch_bounds__(512, 4) void attn_part(
    const short* __restrict__ qk,   // [SEQ][QKVS] bf16
    const short* __restrict__ vtb,  // [NH][VDIM][SEQ] bf16
    short* __restrict__ Opart,      // [640][128][128] bf16
    float* __restrict__ lpart)      // [640][128] fp32
{
  __shared__ __align__(16) short Ks[BT * 192];      // 24576 B
  __shared__ __align__(16) short Vt[VDIM * BT];     // 16384 B
  __shared__ __align__(16) short Ps[8 * 16 * PSTR]; // 19456 B

  // decode: xcd owns heads {xcd, xcd+8}; heavy qt-blocks first.
  const int xcd = blockIdx.x;          // 0..7
  const int i0 = blockIdx.y;           // 0..79
  const int h = xcd + ((i0 >= 40) ? 8 : 0);
  int jj = (i0 >= 40) ? (i0 - 40) : i0;  // 0..39
  int qtb = 15;
  while (jj >= (qtb >> 2) + 1) { jj -= (qtb >> 2) + 1; --qtb; }
  const int chk = jj;                   // 0..(qtb>>2)

  const int tid = threadIdx.x;
  const int wave = tid >> 6;            // 0..7
  const int lane = tid & 63;
  const int lane15 = lane & 15;
  const int quad = lane >> 4;
  const int g = qtb >> 2;
  const int slot = h * 40 + (g + 1) * (2 * g + (qtb & 3)) + chk;
  const int R0 = qtb * BQ;
  const int NT = 2 * qtb + 2;
  const int kt_beg = chk * CHT;
  const int kt_end = min(kt_beg + CHT, NT);
  const float scale = 0.072168784f;  // 1/sqrt(192)

  // Q A-frags: wave's 16 rows
  const int qrow = R0 + wave * 16 + lane15;
  short8 qf[6];
  const short* qbase = qk + (size_t)qrow * QKVS + h * HD + quad * 8;
#pragma unroll
  for (int kc = 0; kc < 6; ++kc) qf[kc] = *(const short8*)(qbase + kc * 32);

  // staging descriptors (XOR-swizzled), 512 threads: K 3/thread, V 2/thread
  const short* kb = qk + QKD;
  int lKoff[3]; const short* gK[3];
#pragma unroll
  for (int i = 0; i < 3; ++i) {
    int id = i * 512 + tid;
    int row = id / 24, cX = id - row * 24;
    int ch = cX ^ (row & 7);
    lKoff[i] = id * 8;
    gK[i] = kb + (size_t)row * QKVS + h * HD + ch * 8;
  }
  const short* gV[2]; short* lV[2];
#pragma unroll
  for (int i = 0; i < 2; ++i) {
    int id = i * 512 + tid;
    int row = id >> 3, cX = id & 7;
    int ch = cX ^ (row & 7);
    lV[i] = &Vt[id * 8];
    gV[i] = vtb + (size_t)h * VDIM * SEQ + (size_t)row * SEQ + ch * 8;
  }

  f32x4 oacc[8];
#pragma unroll
  for (int i = 0; i < 8; ++i) oacc[i] = (f32x4)(0.f);
  float lsum[4] = {0.f, 0.f, 0.f, 0.f};

  short* pw = &Ps[wave * 16 * PSTR];

  for (int kt = kt_beg; kt < kt_end; ++kt) {
    const int t0 = kt * BT;
    __syncthreads();
#pragma unroll
    for (int i = 0; i < 3; ++i) gload16(gK[i] + (size_t)t0 * QKVS, &Ks[lKoff[i]]);
#pragma unroll
    for (int i = 0; i < 2; ++i) gload16(gV[i] + t0, lV[i]);
    __syncthreads();

    // S = Q K^T
    f32x4 sacc[4];
    __builtin_amdgcn_s_setprio(1);
#pragma unroll
    for (int c = 0; c < 4; ++c) {
      sacc[c] = (f32x4)(0.f);
      const int row = c * 16 + lane15;
#pragma unroll
      for (int kc = 0; kc < 6; ++kc) {
        int cX = (4 * kc + quad) ^ (lane15 & 7);
        short8 kf = *(const short8*)&Ks[row * 192 + cX * 8];
        sacc[c] = __builtin_amdgcn_mfma_f32_16x16x32_bf16(qf[kc], kf, sacc[c], 0, 0, 0);
      }
    }
    __builtin_amdgcn_s_setprio(0);

    if (kt >= 2 * qtb) {  // tiles possibly crossing the diagonal
#pragma unroll
      for (int c = 0; c < 4; ++c)
#pragma unroll
        for (int r = 0; r < 4; ++r) {
          int tg = t0 + c * 16 + lane15;
          int qg = R0 + wave * 16 + quad * 4 + r;
          if (tg > qg) sacc[c][r] = -1e30f;
        }
    }

    // P = exp(S*scale - MFIX); partial row sums; stage P bf16 (wave-local)
#pragma unroll
    for (int c = 0; c < 4; ++c)
#pragma unroll
      for (int r = 0; r < 4; ++r) {
        float p = __expf(sacc[c][r] * scale - MFIX);
        lsum[r] += p;
        pw[(quad * 4 + r) * PSTR + c * 16 + lane15] = f2bf(p);
      }

    short8 pf0 = *(const short8*)&pw[lane15 * PSTR + quad * 8];
    short8 pf1 = *(const short8*)&pw[lane15 * PSTR + 32 + quad * 8];
    __builtin_amdgcn_s_setprio(1);
#pragma unroll
    for (int ch = 0; ch < 8; ++ch) {
      const int row = ch * 16 + lane15;
      int cX0 = quad ^ (lane15 & 7);
      int cX1 = (4 + quad) ^ (lane15 & 7);
      short8 vf0 = *(const short8*)&Vt[row * 64 + cX0 * 8];
      short8 vf1 = *(const short8*)&Vt[row * 64 + cX1 * 8];
      oacc[ch] = __builtin_amdgcn_mfma_f32_16x16x32_bf16(pf0, vf0, oacc[ch], 0, 0, 0);
      oacc[ch] = __builtin_amdgcn_mfma_f32_16x16x32_bf16(pf1, vf1, oacc[ch], 0, 0, 0);
    }
    __builtin_amdgcn_s_setprio(0);
  }

  // epilogue: write unnormalized partials ([128][128] per slot)
  short* op = Opart + (size_t)slot * (128 * 128);
#pragma unroll
  for (int ch = 0; ch < 8; ++ch)
#pragma unroll
    for (int r = 0; r < 4; ++r)
      op[(wave * 16 + quad * 4 + r) * 128 + ch * 16 + lane15] = f2bf(oacc[ch][r]);

  float red[4];
#pragma unroll
  for (int r = 0; r < 4; ++r) {
    float s = lsum[r];
    s += __shfl_xor(s, 1, 64);
    s += __shfl_xor(s, 2, 64);
    s += __shfl_xor(s, 4, 64);
    s += __shfl_xor(s, 8, 64);
    red[r] = s;
  }
  if (lane15 == 0) {
#pragma unroll
    for (int r = 0; r < 4; ++r)
      lpart[(size_t)slot * 128 + wave * 16 + quad * 4 + r] = red[r];
  }
}

// ---------------------------------------------------------------------------
// Phase B: sum chunk partials, normalize, write aob (into v-cols of qkv).
// blockIdx.x = qt64 (0..31, 64-row half of a 128-row qt-block), .y = head.
// ---------------------------------------------------------------------------
__global__ __launch_bounds__(256) void attn_combine(
    const short* __restrict__ Opart, const float* __restrict__ lpart,
    short* __restrict__ aob) {   // aob = qkv + 6144, row stride QKVS
  const int qt64 = blockIdx.x, h = blockIdx.y;
  const int qtb = qt64 >> 1;
  const int half = qt64 & 1;
  const int g = qtb >> 2;
  const int nact = g + 1;
  const int base = h * 40 + (g + 1) * (2 * g + (qtb & 3));
  const int tid = threadIdx.x;
  const int row = tid >> 2;            // 0..63
  const int cg = (tid & 3) * 32;

  float acc[32];
#pragma unroll
  for (int e = 0; e < 32; ++e) acc[e] = 0.f;
  float lsum = 0.f;

  for (int c = 0; c < nact; ++c) {
    const short* sp = Opart + (size_t)(base + c) * (128 * 128) +
                      (half * 64 + row) * 128 + cg;
    lsum += lpart[(size_t)(base + c) * 128 + half * 64 + row];
#pragma unroll
    for (int gg = 0; gg < 4; ++gg) {
      short8 vv = *(const short8*)(sp + gg * 8);
#pragma unroll
      for (int e = 0; e < 8; ++e) acc[gg * 8 + e] += bf2f((unsigned short)vv[e]);
    }
  }

  float inv = 1.f / lsum;
#pragma unroll
  for (int gg = 0; gg < 4; ++gg) {
    short8 ov;
#pragma unroll
    for (int e = 0; e < 8; ++e) ov[e] = f2bf(acc[gg * 8 + e] * inv);
    *(short8*)(aob + (size_t)(qt64 * 64 + row) * QKVS + h * 128 + cg + gg * 8) = ov;
  }
}

// ---------------------------------------------------------------------------
// Workspace (bytes), peak 75,497,472 (< proven 79,691,776):
//   [0,        8388608)  xb  -> wo_b (after qkv gemm)
//   [8388608, 41943040)  wqkv -> {vtb@8388608, Opart@16777216 (640x128x128x2
//                        = 20,971,520), lpart@37748736 (640x128x4 = 327,680)}
//   [41943040,75497472)  qkv bf16 [2048][8192]; aob lives in v-cols (6144+)
// ---------------------------------------------------------------------------
extern "C" void kernel_launch(void* const* d_in, const int* in_sizes, int n_in,
                              void* d_out, int out_size, void* d_ws, size_t ws_size,
                              hipStream_t stream) {
  const float* x  = (const float*)d_in[0];
  const float* wq = (const float*)d_in[1];
  const float* wk = (const float*)d_in[2];
  const float* wv = (const float*)d_in[3];
  const float* wo = (const float*)d_in[4];
  const float* fc = (const float*)d_in[5];
  const float* fs = (const float*)d_in[6];

  char* ws8 = (char*)d_ws;
  short* xb    = (short*)(ws8 + 0);
  short* wo_b  = (short*)(ws8 + 0);
  short* wqkv  = (short*)(ws8 + 8388608);
  short* vtb   = (short*)(ws8 + 8388608);
  short* Opart = (short*)(ws8 + 16777216);
  float* lpart = (float*)(ws8 + 37748736);
  short* qkv   = (short*)(ws8 + 41943040);
  float* out   = (float*)d_out;

  const int NX4 = DIM * DIM / 4;
  const int NQKV4 = QKVS * DIM / 4;
  const int ROPE_GRID = (SEQ * NH * 32) / 256;

  bf16_convert<<<(NX4 + 255) / 256, 256, 0, stream>>>(x, xb, NX4);
  conv_wqkv<<<(NQKV4 + 255) / 256, 256, 0, stream>>>(wq, wk, wv, wqkv, NQKV4);

  // fused QKV projection: qkv [2048][8192] via 256^2 kernel (m201-layout).
  gemm256_bt<<<dim3((QKVS / 256) * (SEQ / 256)), 512, 0, stream>>>(
      xb, wqkv, qkv, DIM, DIM, DIM, QKVS);
  rope_qk<<<ROPE_GRID, 256, 0, stream>>>(qkv, fc, fs);
  vt_bf16<<<dim3(SEQ / 64, VD / 64), 256, 0, stream>>>(qkv + 2 * QKD, vtb);

  // wo convert (xb dead after qkv gemm)
  bf16_convert<<<(NX4 + 255) / 256, 256, 0, stream>>>(wo, wo_b, NX4);

  // split-T attention: grid (8 xcd, 80 chunks) = 640 blocks, 512 threads
  attn_part<<<dim3(8, 80), 512, 0, stream>>>(qkv, vtb, Opart, lpart);
  attn_combine<<<dim3(SEQ / 64, NH), 256, 0, stream>>>(Opart, lpart, qkv + 2 * QKD);

  // output projection (A = aob in v-cols, lda = QKVS)
  gemm_bt<false><<<dim3(DIM / 128, SEQ / 128), 256, 0, stream>>>(
      qkv + 2 * QKD, wo_b, out, DIM, QKVS, DIM, DIM, 1.0f);
}

// Round 9
// 312.696 us; speedup vs baseline: 1.0454x; 1.0059x over previous
//
#include <hip/hip_runtime.h>
#include <hip/hip_bf16.h>
#include <math.h>

#define NH 16
#define NOPE 128
#define ROPE 64
#define VDIM 128
#define HD 192          // HEAD_DIM
#define SEQ 2048
#define DIM 2048
#define QKD (NH * HD)   // 3072
#define VD  (NH * VDIM) // 2048
#define QKVS 8192       // fused q|k|v row stride (shorts): [q 3072][k 3072][v 2048]

typedef __attribute__((ext_vector_type(8))) short short8;   // 8 bf16 = 4 VGPRs
typedef __attribute__((ext_vector_type(4))) short short4v;
typedef __attribute__((ext_vector_type(4))) float f32x4;
typedef unsigned int u32;

// s_waitcnt immediates (gfx9 encoding: vmcnt[3:0]@0, expcnt@4, lgkmcnt@8, vmcnt[5:4]@14)
#define WAIT_VM8  0x0F78   // vmcnt(8)
#define WAIT_VM6  0x0F76   // vmcnt(6)
#define WAIT_VM4  0x0F74   // vmcnt(4)
#define WAIT_VM0  0x0F70   // vmcnt(0)
#define WAIT_LGKM 0xC07F   // lgkmcnt(0), vmcnt/exp no-wait

static __device__ inline short f2bf(float f) {
  union { float f; unsigned u; } v; v.f = f;
  unsigned r = (v.u + 0x7fffu + ((v.u >> 16) & 1u)) >> 16;
  return (short)r;
}
static __device__ inline float bf2f(unsigned short u) {
  union { unsigned u; float f; } v; v.u = ((unsigned)u) << 16;
  return v.f;
}

// async global->LDS, 16B/lane. LDS dest = wave-uniform base + lane*16.
static __device__ __forceinline__ void gload16(const short* g, short* l) {
  __builtin_amdgcn_global_load_lds(
      (const __attribute__((address_space(1))) u32*)g,
      (__attribute__((address_space(3))) u32*)l, 16, 0, 0);
}

// ---------------------------------------------------------------------------
// 256x256 bf16 GEMM, C = A * B^T.  Unchanged from R8 (m201 layout+staging).
// ---------------------------------------------------------------------------

#define LSA(pp) (Lsm + (pp) * 65536)
#define LSB(pp) (Lsm + (pp) * 65536 + 32768)

#define RDA(pp, kh, mh) do { \
  const char* p_ = LSA(pp) + abase + (mh) * 8192 + ((kh) ? cx1 : cx0); \
  afr[(mh) * 4 + 0] = *(const short8*)(p_ + 0); \
  afr[(mh) * 4 + 1] = *(const short8*)(p_ + 2048); \
  afr[(mh) * 4 + 2] = *(const short8*)(p_ + 4096); \
  afr[(mh) * 4 + 3] = *(const short8*)(p_ + 6144); \
} while (0)

#define RDB(pp, kh) do { \
  const char* p_ = LSB(pp) + bbase + ((kh) ? cx1 : cx0); \
  bfr[0] = *(const short8*)(p_ + 0); \
  bfr[1] = *(const short8*)(p_ + 2048); \
  bfr[2] = *(const short8*)(p_ + 4096); \
  bfr[3] = *(const short8*)(p_ + 6144); \
} while (0)

#define SGA(kt, c) gload16(srcA[c] + (kt) * 64, (short*)(LSA((kt) & 1) + ((c) * 512 + tid) * 16))
#define SGB(kt, c) gload16(srcB[c] + (kt) * 64, (short*)(LSB((kt) & 1) + ((c) * 512 + tid) * 16))
#define G1S(kt) do { SGA(kt, 0); SGA(kt, 2); SGB(kt, 0); SGB(kt, 1); } while (0)
#define G2S(kt) do { SGA(kt, 1); SGA(kt, 3); SGB(kt, 2); SGB(kt, 3); } while (0)

#define MFMA1(mi, ni) \
  acc[mi][ni] = __builtin_amdgcn_mfma_f32_16x16x32_bf16(afr[mi], bfr[ni], acc[mi][ni], 0, 0, 0)

#define MM(mh) do { \
  MFMA1((mh)*4+0, 0); MFMA1((mh)*4+1, 0); MFMA1((mh)*4+2, 0); MFMA1((mh)*4+3, 0); \
  MFMA1((mh)*4+0, 1); MFMA1((mh)*4+1, 1); MFMA1((mh)*4+2, 1); MFMA1((mh)*4+3, 1); \
  MFMA1((mh)*4+0, 2); MFMA1((mh)*4+1, 2); MFMA1((mh)*4+2, 2); MFMA1((mh)*4+3, 2); \
  MFMA1((mh)*4+0, 3); MFMA1((mh)*4+1, 3); MFMA1((mh)*4+2, 3); MFMA1((mh)*4+3, 3); \
} while (0)

#define GBAR() __builtin_amdgcn_s_barrier()
#define GLGKM0() __builtin_amdgcn_s_waitcnt(WAIT_LGKM)
#define GPRIO1() __builtin_amdgcn_s_setprio(1)
#define GPRIO0() __builtin_amdgcn_s_setprio(0)
#define GNOP ((void)0)

// One K-tile = 4 phases; SP1 staged in P1, SP4 + counted wait in P4.
#define TILE(pp, SP1, SP4, VMW) do { \
  RDA(pp, 0, 0); RDB(pp, 0); SP1; \
  GBAR(); GLGKM0(); GPRIO1(); MM(0); GPRIO0(); GBAR(); \
  RDA(pp, 0, 1); \
  GBAR(); GLGKM0(); GPRIO1(); MM(1); GPRIO0(); GBAR(); \
  RDA(pp, 1, 0); RDB(pp, 1); \
  GBAR(); GLGKM0(); GPRIO1(); MM(0); GPRIO0(); GBAR(); \
  RDA(pp, 1, 1); SP4; \
  GBAR(); GLGKM0(); GPRIO1(); MM(1); GPRIO0(); VMW; GBAR(); \
} while (0)

__global__ __launch_bounds__(512, 2) void gemm256_bt(
    const short* __restrict__ A, const short* __restrict__ B,
    short* __restrict__ C, int K, int lda, int ldb, int ldc) {
  __shared__ __align__(16) char Lsm[131072];

  const int tid = threadIdx.x;
  const int lane = tid & 63;
  const int l15 = lane & 15;
  const int quad = lane >> 4;      // 0..3
  const int wv = tid >> 6;         // 0..7
  const int wr = wv >> 2, wc = wv & 3;

  // 8Mx4N per-XCD partition (R6).
  const int bid = blockIdx.x;
  const int xcd = bid & 7;
  const int idx = bid >> 3;              // 0..31 within XCD
  const int m0 = (idx & 7) * 256;        // 8 M panels
  const int n0 = (xcd * 4 + (idx >> 3)) * 256;  // 4 N panels per XCD

  // staging sources: linear LDS dest + inverse-swizzled global source (R8).
  const int trow = tid >> 3;                               // 0..63
  const int scol = ((tid & 7) * 8) ^ ((trow & 7) * 8);     // shorts
  const short* srcA[4]; const short* srcB[4];
#pragma unroll
  for (int c = 0; c < 4; ++c) {
    srcA[c] = A + (size_t)(m0 + c * 64 + trow) * lda + scol;
    srcB[c] = B + (size_t)(n0 + c * 64 + trow) * ldb + scol;
  }

  // ds_read bases (bytes): row = {wr*128|wc*64} + sub + l15; swizzled col.
  const int abase = (wr * 128 + l15) * 128;
  const int bbase = (wc * 64 + l15) * 128;
  const int cx0 = (quad * 16) ^ ((l15 & 7) * 16);          // kh = 0
  const int cx1 = (64 + quad * 16) ^ ((l15 & 7) * 16);     // kh = 1

  f32x4 acc[8][4];
#pragma unroll
  for (int i = 0; i < 8; ++i)
#pragma unroll
    for (int j = 0; j < 4; ++j) acc[i][j] = (f32x4)(0.f);
  short8 afr[8], bfr[4];

  const int NT = K >> 6;   // even, >= 4

  // prologue: tile0 fully (8) + G1(tile1) (4); vmcnt(4) proves tile0.
  G1S(0); G2S(0); G1S(1);
  __builtin_amdgcn_s_waitcnt(WAIT_VM4);
  GBAR();

  int kt = 0;
  for (; kt + 4 <= NT; kt += 2) {
    TILE(0, G2S(kt + 1), G1S(kt + 2), __builtin_amdgcn_s_waitcnt(WAIT_VM4));
    TILE(1, G2S(kt + 2), G1S(kt + 3), __builtin_amdgcn_s_waitcnt(WAIT_VM4));
  }
  // tail: kt == NT-2. P1 stages G2(NT-1); vmcnt(0) proves NT-1; last tile bare.
  TILE(0, G2S(kt + 1), GNOP, __builtin_amdgcn_s_waitcnt(WAIT_VM0));
  TILE(1, GNOP, GNOP, GNOP);

#pragma unroll
  for (int m = 0; m < 8; ++m) {
    const size_t rb = (size_t)(m0 + wr * 128 + m * 16 + quad * 4) * ldc +
                      n0 + wc * 64 + l15;
#pragma unroll
    for (int n = 0; n < 4; ++n)
#pragma unroll
      for (int r = 0; r < 4; ++r)
        C[rb + (size_t)r * ldc + n * 16] = f2bf(acc[m][n][r]);
  }
}

// ---------------------------------------------------------------------------
// bf16 MFMA GEMM v2 (128^2): kept for the output projection (now with
// compact-lda A so staging is full-cache-line).
// ---------------------------------------------------------------------------
template <bool BF16OUT>
__global__ __launch_bounds__(256) void gemm_bt(
    const short* __restrict__ A, const short* __restrict__ B,
    void* __restrict__ Cv, int K, int lda, int ldb, int ldc, float oscale) {
  __shared__ __align__(16) short Ls[4][2][4096];

  const int tid = threadIdx.x;
  const int lane = tid & 63;
  const int wave = tid >> 6;
  const int wr = wave >> 1, wc = wave & 1;
  const int lane15 = lane & 15, quad = lane >> 4;
  const int m0 = blockIdx.y * 128, n0 = blockIdx.x * 128;

  const short* gA[4]; const short* gB[4];
#pragma unroll
  for (int i = 0; i < 4; ++i) {
    int gidx = i * 64 + lane;
    int r = gidx >> 2, p = gidx & 3;
    int g = (p ^ ((r >> 1) & 3)) * 8;
    gA[i] = A + (size_t)(m0 + wr * 64 + r) * lda + g;
    gB[i] = B + (size_t)(n0 + wc * 64 + r) * ldb + g;
  }

  f32x4 acc[4][4];
#pragma unroll
  for (int i = 0; i < 4; ++i)
#pragma unroll
    for (int j = 0; j < 4; ++j) acc[i][j] = (f32x4)(0.f);

#pragma unroll
  for (int i = 0; i < 4; ++i) gload16(gA[i], &Ls[wave][0][i * 512]);
#pragma unroll
  for (int i = 0; i < 4; ++i) gload16(gB[i], &Ls[wave][0][2048 + i * 512]);

  const int rsw = (lane15 >> 1) & 3;
  for (int k0 = 0; k0 < K; k0 += 32) {
    const int cur = (k0 >> 5) & 1;
    __builtin_amdgcn_s_waitcnt(WAIT_LGKM);
    if (k0 + 32 < K) {
      const int nxt = cur ^ 1;
#pragma unroll
      for (int i = 0; i < 4; ++i) gload16(gA[i] + k0 + 32, &Ls[wave][nxt][i * 512]);
#pragma unroll
      for (int i = 0; i < 4; ++i) gload16(gB[i] + k0 + 32, &Ls[wave][nxt][2048 + i * 512]);
      __builtin_amdgcn_s_waitcnt(WAIT_VM8);
    } else {
      __builtin_amdgcn_s_waitcnt(WAIT_VM0);
    }
    const short* bufp = &Ls[wave][cur][0];
    short8 af[4], bfv[4];
#pragma unroll
    for (int i = 0; i < 4; ++i)
      af[i] = *(const short8*)&bufp[(i * 16 + lane15) * 32 + (quad ^ rsw) * 8];
#pragma unroll
    for (int j = 0; j < 4; ++j)
      bfv[j] = *(const short8*)&bufp[2048 + (j * 16 + lane15) * 32 + (quad ^ rsw) * 8];
#pragma unroll
    for (int i = 0; i < 4; ++i)
#pragma unroll
      for (int j = 0; j < 4; ++j)
        acc[i][j] = __builtin_amdgcn_mfma_f32_16x16x32_bf16(af[i], bfv[j], acc[i][j], 0, 0, 0);
  }

#pragma unroll
  for (int i = 0; i < 4; ++i)
#pragma unroll
    for (int j = 0; j < 4; ++j)
#pragma unroll
      for (int r = 0; r < 4; ++r) {
        size_t idx = (size_t)(m0 + wr * 64 + i * 16 + quad * 4 + r) * ldc +
                     n0 + wc * 64 + j * 16 + lane15;
        if (BF16OUT)
          ((short*)Cv)[idx] = f2bf(acc[i][j][r] * oscale);
        else
          ((float*)Cv)[idx] = acc[i][j][r];
      }
}

// ---------------------------------------------------------------------------
// RoPE in-place on fused qkv bf16 [SEQ][QKVS].
// ---------------------------------------------------------------------------
__global__ __launch_bounds__(256) void rope_qk(
    short* __restrict__ qk, const float* __restrict__ cosf, const float* __restrict__ sinf) {
  int idx = blockIdx.x * blockDim.x + threadIdx.x;
  int j = idx & 31;
  int h = (idx >> 5) & (NH - 1);
  int s = idx >> 9;
  if (s >= SEQ) return;

  float c = cosf[s * 32 + j];
  float sn = sinf[s * 32 + j];
  size_t rowb = (size_t)s * QKVS + h * HD + NOPE + 2 * j;

  u32* pq = (u32*)(qk + rowb);
  u32 w = *pq;
  float a = bf2f((unsigned short)(w & 0xffff));
  float b = bf2f((unsigned short)(w >> 16));
  *pq = (u32)(unsigned short)f2bf(a * c - b * sn) |
        ((u32)(unsigned short)f2bf(a * sn + b * c) << 16);

  u32* pk = (u32*)(qk + rowb + QKD);
  w = *pk;
  a = bf2f((unsigned short)(w & 0xffff));
  b = bf2f((unsigned short)(w >> 16));
  *pk = (u32)(unsigned short)f2bf(a * c - b * sn) |
        ((u32)(unsigned short)f2bf(a * sn + b * c) << 16);
}

// ---------------------------------------------------------------------------
// Converts.
// ---------------------------------------------------------------------------
__global__ __launch_bounds__(256) void bf16_convert(
    const float* __restrict__ in, short* __restrict__ out, int n4) {
  int i = blockIdx.x * 256 + threadIdx.x;
  if (i >= n4) return;
  float4 f = ((const float4*)in)[i];
  short4v o;
  o.x = f2bf(f.x); o.y = f2bf(f.y); o.z = f2bf(f.z); o.w = f2bf(f.w);
  ((short4v*)out)[i] = o;
}

__global__ __launch_bounds__(256) void conv_wqkv(
    const float* __restrict__ wq, const float* __restrict__ wk,
    const float* __restrict__ wv, short* __restrict__ wqkv, int n4) {
  int i = blockIdx.x * 256 + threadIdx.x;
  if (i >= n4) return;
  int row = i >> 9;
  float4 f;
  if (row < QKD) f = ((const float4*)wq)[i];
  else if (row < 2 * QKD) f = ((const float4*)wk)[i - QKD * (DIM / 4)];
  else f = ((const float4*)wv)[i - 2 * QKD * (DIM / 4)];
  short4v o;
  o.x = f2bf(f.x); o.y = f2bf(f.y); o.z = f2bf(f.z); o.w = f2bf(f.w);
  ((short4v*)wqkv)[i] = o;
}

// ---------------------------------------------------------------------------
// v bf16 -> vtb bf16 [h][d][t] transpose.
// ---------------------------------------------------------------------------
__global__ __launch_bounds__(256) void vt_bf16(
    const short* __restrict__ vb, short* __restrict__ vtb) {
  __shared__ short tile[64][74];
  const int t0 = blockIdx.x * 64;
  const int c0 = blockIdx.y * 64;
  const int tid = threadIdx.x;
#pragma unroll
  for (int i = 0; i < 16; ++i) {
    int idx = i * 256 + tid;
    int r = idx >> 6, c = idx & 63;
    tile[r][c] = vb[(size_t)(t0 + r) * QKVS + c0 + c];
  }
  __syncthreads();
  const int h = c0 >> 7;
  const int dbase = c0 & 127;
#pragma unroll
  for (int i = 0; i < 16; ++i) {
    int idx = i * 256 + tid;
    int d = idx >> 6, t = idx & 63;
    vtb[(size_t)h * VDIM * SEQ + (size_t)(dbase + d) * SEQ + t0 + t] = tile[t][d];
  }
}

// ---------------------------------------------------------------------------
// Split-T flash attention v4 (unchanged from R5): BQ=128 via 8 waves.
// LDS: 24576 (K) + 16384 (V) + 19456 (Ps) = 60416 -> 2 blocks/CU.
// ---------------------------------------------------------------------------
#define BQ 128
#define BT 64
#define CHT 8
#define PSTR 76
#define MFIX 8.0f

__global__ __launch_bounds__(512, 4) void attn_part(
    const short* __restrict__ qk,   // [SEQ][QKVS] bf16
    const short* __restrict__ vtb,  // [NH][VDIM][SEQ] bf16
    short* __restrict__ Opart,      // [640][128][128] bf16
    float* __restrict__ lpart)      // [640][128] fp32
{
  __shared__ __align__(16) short Ks[BT * 192];      // 24576 B
  __shared__ __align__(16) short Vt[VDIM * BT];     // 16384 B
  __shared__ __align__(16) short Ps[8 * 16 * PSTR]; // 19456 B

  // decode: xcd owns heads {xcd, xcd+8}; heavy qt-blocks first.
  const int xcd = blockIdx.x;          // 0..7
  const int i0 = blockIdx.y;           // 0..79
  const int h = xcd + ((i0 >= 40) ? 8 : 0);
  int jj = (i0 >= 40) ? (i0 - 40) : i0;  // 0..39
  int qtb = 15;
  while (jj >= (qtb >> 2) + 1) { jj -= (qtb >> 2) + 1; --qtb; }
  const int chk = jj;                   // 0..(qtb>>2)

  const int tid = threadIdx.x;
  const int wave = tid >> 6;            // 0..7
  const int lane = tid & 63;
  const int lane15 = lane & 15;
  const int quad = lane >> 4;
  const int g = qtb >> 2;
  const int slot = h * 40 + (g + 1) * (2 * g + (qtb & 3)) + chk;
  const int R0 = qtb * BQ;
  const int NT = 2 * qtb + 2;
  const int kt_beg = chk * CHT;
  const int kt_end = min(kt_beg + CHT, NT);
  const float scale = 0.072168784f;  // 1/sqrt(192)

  // Q A-frags: wave's 16 rows
  const int qrow = R0 + wave * 16 + lane15;
  short8 qf[6];
  const short* qbase = qk + (size_t)qrow * QKVS + h * HD + quad * 8;
#pragma unroll
  for (int kc = 0; kc < 6; ++kc) qf[kc] = *(const short8*)(qbase + kc * 32);

  // staging descriptors (XOR-swizzled), 512 threads: K 3/thread, V 2/thread
  const short* kb = qk + QKD;
  int lKoff[3]; const short* gK[3];
#pragma unroll
  for (int i = 0; i < 3; ++i) {
    int id = i * 512 + tid;
    int row = id / 24, cX = id - row * 24;
    int ch = cX ^ (row & 7);
    lKoff[i] = id * 8;
    gK[i] = kb + (size_t)row * QKVS + h * HD + ch * 8;
  }
  const short* gV[2]; short* lV[2];
#pragma unroll
  for (int i = 0; i < 2; ++i) {
    int id = i * 512 + tid;
    int row = id >> 3, cX = id & 7;
    int ch = cX ^ (row & 7);
    lV[i] = &Vt[id * 8];
    gV[i] = vtb + (size_t)h * VDIM * SEQ + (size_t)row * SEQ + ch * 8;
  }

  f32x4 oacc[8];
#pragma unroll
  for (int i = 0; i < 8; ++i) oacc[i] = (f32x4)(0.f);
  float lsum[4] = {0.f, 0.f, 0.f, 0.f};

  short* pw = &Ps[wave * 16 * PSTR];

  for (int kt = kt_beg; kt < kt_end; ++kt) {
    const int t0 = kt * BT;
    __syncthreads();
#pragma unroll
    for (int i = 0; i < 3; ++i) gload16(gK[i] + (size_t)t0 * QKVS, &Ks[lKoff[i]]);
#pragma unroll
    for (int i = 0; i < 2; ++i) gload16(gV[i] + t0, lV[i]);
    __syncthreads();

    // S = Q K^T
    f32x4 sacc[4];
    __builtin_amdgcn_s_setprio(1);
#pragma unroll
    for (int c = 0; c < 4; ++c) {
      sacc[c] = (f32x4)(0.f);
      const int row = c * 16 + lane15;
#pragma unroll
      for (int kc = 0; kc < 6; ++kc) {
        int cX = (4 * kc + quad) ^ (lane15 & 7);
        short8 kf = *(const short8*)&Ks[row * 192 + cX * 8];
        sacc[c] = __builtin_amdgcn_mfma_f32_16x16x32_bf16(qf[kc], kf, sacc[c], 0, 0, 0);
      }
    }
    __builtin_amdgcn_s_setprio(0);

    if (kt >= 2 * qtb) {  // tiles possibly crossing the diagonal
#pragma unroll
      for (int c = 0; c < 4; ++c)
#pragma unroll
        for (int r = 0; r < 4; ++r) {
          int tg = t0 + c * 16 + lane15;
          int qg = R0 + wave * 16 + quad * 4 + r;
          if (tg > qg) sacc[c][r] = -1e30f;
        }
    }

    // P = exp(S*scale - MFIX); partial row sums; stage P bf16 (wave-local)
#pragma unroll
    for (int c = 0; c < 4; ++c)
#pragma unroll
      for (int r = 0; r < 4; ++r) {
        float p = __expf(sacc[c][r] * scale - MFIX);
        lsum[r] += p;
        pw[(quad * 4 + r) * PSTR + c * 16 + lane15] = f2bf(p);
      }

    short8 pf0 = *(const short8*)&pw[lane15 * PSTR + quad * 8];
    short8 pf1 = *(const short8*)&pw[lane15 * PSTR + 32 + quad * 8];
    __builtin_amdgcn_s_setprio(1);
#pragma unroll
    for (int ch = 0; ch < 8; ++ch) {
      const int row = ch * 16 + lane15;
      int cX0 = quad ^ (lane15 & 7);
      int cX1 = (4 + quad) ^ (lane15 & 7);
      short8 vf0 = *(const short8*)&Vt[row * 64 + cX0 * 8];
      short8 vf1 = *(const short8*)&Vt[row * 64 + cX1 * 8];
      oacc[ch] = __builtin_amdgcn_mfma_f32_16x16x32_bf16(pf0, vf0, oacc[ch], 0, 0, 0);
      oacc[ch] = __builtin_amdgcn_mfma_f32_16x16x32_bf16(pf1, vf1, oacc[ch], 0, 0, 0);
    }
    __builtin_amdgcn_s_setprio(0);
  }

  // epilogue: write unnormalized partials ([128][128] per slot)
  short* op = Opart + (size_t)slot * (128 * 128);
#pragma unroll
  for (int ch = 0; ch < 8; ++ch)
#pragma unroll
    for (int r = 0; r < 4; ++r)
      op[(wave * 16 + quad * 4 + r) * 128 + ch * 16 + lane15] = f2bf(oacc[ch][r]);

  float red[4];
#pragma unroll
  for (int r = 0; r < 4; ++r) {
    float s = lsum[r];
    s += __shfl_xor(s, 1, 64);
    s += __shfl_xor(s, 2, 64);
    s += __shfl_xor(s, 4, 64);
    s += __shfl_xor(s, 8, 64);
    red[r] = s;
  }
  if (lane15 == 0) {
#pragma unroll
    for (int r = 0; r < 4; ++r)
      lpart[(size_t)slot * 128 + wave * 16 + quad * 4 + r] = red[r];
  }
}

// ---------------------------------------------------------------------------
// Phase B: sum chunk partials, normalize, write COMPACT aob [2048][2048] bf16
// (row stride DIM, placed at qkv base -- qkv is dead after this kernel).
// blockIdx.x = qt64 (0..31), .y = head.
// ---------------------------------------------------------------------------
__global__ __launch_bounds__(256) void attn_combine(
    const short* __restrict__ Opart, const float* __restrict__ lpart,
    short* __restrict__ aob) {   // compact [SEQ][VD], row stride VD=2048
  const int qt64 = blockIdx.x, h = blockIdx.y;
  const int qtb = qt64 >> 1;
  const int half = qt64 & 1;
  const int g = qtb >> 2;
  const int nact = g + 1;
  const int base = h * 40 + (g + 1) * (2 * g + (qtb & 3));
  const int tid = threadIdx.x;
  const int row = tid >> 2;            // 0..63
  const int cg = (tid & 3) * 32;

  float acc[32];
#pragma unroll
  for (int e = 0; e < 32; ++e) acc[e] = 0.f;
  float lsum = 0.f;

  for (int c = 0; c < nact; ++c) {
    const short* sp = Opart + (size_t)(base + c) * (128 * 128) +
                      (half * 64 + row) * 128 + cg;
    lsum += lpart[(size_t)(base + c) * 128 + half * 64 + row];
#pragma unroll
    for (int gg = 0; gg < 4; ++gg) {
      short8 vv = *(const short8*)(sp + gg * 8);
#pragma unroll
      for (int e = 0; e < 8; ++e) acc[gg * 8 + e] += bf2f((unsigned short)vv[e]);
    }
  }

  float inv = 1.f / lsum;
#pragma unroll
  for (int gg = 0; gg < 4; ++gg) {
    short8 ov;
#pragma unroll
    for (int e = 0; e < 8; ++e) ov[e] = f2bf(acc[gg * 8 + e] * inv);
    *(short8*)(aob + (size_t)(qt64 * 64 + row) * VD + h * 128 + cg + gg * 8) = ov;
  }
}

// ---------------------------------------------------------------------------
// Workspace (bytes), peak 75,497,472 (< proven 79,691,776):
//   [0,        8388608)  xb  -> wo_b (after qkv gemm)
//   [8388608, 41943040)  wqkv -> {vtb@8388608, Opart@16777216 (20,971,520),
//                        lpart@37748736 (327,680)}
//   [41943040,75497472)  qkv bf16 [2048][8192]; AFTER attn_combine, qkv is
//                        dead and compact aob [2048][2048] bf16 (8 MB) lives
//                        at the qkv base.
// ---------------------------------------------------------------------------
extern "C" void kernel_launch(void* const* d_in, const int* in_sizes, int n_in,
                              void* d_out, int out_size, void* d_ws, size_t ws_size,
                              hipStream_t stream) {
  const float* x  = (const float*)d_in[0];
  const float* wq = (const float*)d_in[1];
  const float* wk = (const float*)d_in[2];
  const float* wv = (const float*)d_in[3];
  const float* wo = (const float*)d_in[4];
  const float* fc = (const float*)d_in[5];
  const float* fs = (const float*)d_in[6];

  char* ws8 = (char*)d_ws;
  short* xb    = (short*)(ws8 + 0);
  short* wo_b  = (short*)(ws8 + 0);
  short* wqkv  = (short*)(ws8 + 8388608);
  short* vtb   = (short*)(ws8 + 8388608);
  short* Opart = (short*)(ws8 + 16777216);
  float* lpart = (float*)(ws8 + 37748736);
  short* qkv   = (short*)(ws8 + 41943040);
  short* aob   = qkv;   // compact aob overwrites dead qkv after attn_combine
  float* out   = (float*)d_out;

  const int NX4 = DIM * DIM / 4;
  const int NQKV4 = QKVS * DIM / 4;
  const int ROPE_GRID = (SEQ * NH * 32) / 256;

  bf16_convert<<<(NX4 + 255) / 256, 256, 0, stream>>>(x, xb, NX4);
  conv_wqkv<<<(NQKV4 + 255) / 256, 256, 0, stream>>>(wq, wk, wv, wqkv, NQKV4);

  // fused QKV projection: qkv [2048][8192] via 256^2 kernel (m201-layout).
  gemm256_bt<<<dim3((QKVS / 256) * (SEQ / 256)), 512, 0, stream>>>(
      xb, wqkv, qkv, DIM, DIM, DIM, QKVS);
  rope_qk<<<ROPE_GRID, 256, 0, stream>>>(qkv, fc, fs);
  vt_bf16<<<dim3(SEQ / 64, VD / 64), 256, 0, stream>>>(qkv + 2 * QKD, vtb);

  // wo convert (xb dead after qkv gemm)
  bf16_convert<<<(NX4 + 255) / 256, 256, 0, stream>>>(wo, wo_b, NX4);

  // split-T attention: grid (8 xcd, 80 chunks) = 640 blocks, 512 threads
  attn_part<<<dim3(8, 80), 512, 0, stream>>>(qkv, vtb, Opart, lpart);
  attn_combine<<<dim3(SEQ / 64, NH), 256, 0, stream>>>(Opart, lpart, aob);

  // output projection: A = compact aob, lda = VD (contiguous rows)
  gemm_bt<false><<<dim3(DIM / 128, SEQ / 128), 256, 0, stream>>>(
      aob, wo_b, out, DIM, VD, DIM, DIM, 1.0f);
}

// Round 10
// 312.233 us; speedup vs baseline: 1.0469x; 1.0015x over previous
//
#include <hip/hip_runtime.h>
#include <hip/hip_bf16.h>
#include <math.h>

#define NH 16
#define NOPE 128
#define ROPE 64
#define VDIM 128
#define HD 192          // HEAD_DIM
#define SEQ 2048
#define DIM 2048
#define QKD (NH * HD)   // 3072
#define VD  (NH * VDIM) // 2048
#define QKVS 8192       // fused q|k|v row stride (shorts): [q 3072][k 3072][v 2048]

typedef __attribute__((ext_vector_type(8))) short short8;   // 8 bf16 = 4 VGPRs
typedef __attribute__((ext_vector_type(4))) short short4v;
typedef __attribute__((ext_vector_type(4))) float f32x4;
typedef unsigned int u32;

// s_waitcnt immediates (gfx9 encoding: vmcnt[3:0]@0, expcnt@4, lgkmcnt@8, vmcnt[5:4]@14)
#define WAIT_VM8  0x0F78   // vmcnt(8)
#define WAIT_VM6  0x0F76   // vmcnt(6)
#define WAIT_VM4  0x0F74   // vmcnt(4)
#define WAIT_VM3  0x0F73   // vmcnt(3)
#define WAIT_VM2  0x0F72   // vmcnt(2)
#define WAIT_VM0  0x0F70   // vmcnt(0)
#define WAIT_LGKM 0xC07F   // lgkmcnt(0), vmcnt/exp no-wait

static __device__ inline short f2bf(float f) {
  union { float f; unsigned u; } v; v.f = f;
  unsigned r = (v.u + 0x7fffu + ((v.u >> 16) & 1u)) >> 16;
  return (short)r;
}
static __device__ inline float bf2f(unsigned short u) {
  union { unsigned u; float f; } v; v.u = ((unsigned)u) << 16;
  return v.f;
}

// async global->LDS, 16B/lane. LDS dest = wave-uniform base + lane*16.
static __device__ __forceinline__ void gload16(const short* g, short* l) {
  __builtin_amdgcn_global_load_lds(
      (const __attribute__((address_space(1))) u32*)g,
      (__attribute__((address_space(3))) u32*)l, 16, 0, 0);
}

// ---------------------------------------------------------------------------
// 256x256 bf16 GEMM, C = A * B^T.  Unchanged from R8 (m201 layout+staging).
// ---------------------------------------------------------------------------

#define LSA(pp) (Lsm + (pp) * 65536)
#define LSB(pp) (Lsm + (pp) * 65536 + 32768)

#define RDA(pp, kh, mh) do { \
  const char* p_ = LSA(pp) + abase + (mh) * 8192 + ((kh) ? cx1 : cx0); \
  afr[(mh) * 4 + 0] = *(const short8*)(p_ + 0); \
  afr[(mh) * 4 + 1] = *(const short8*)(p_ + 2048); \
  afr[(mh) * 4 + 2] = *(const short8*)(p_ + 4096); \
  afr[(mh) * 4 + 3] = *(const short8*)(p_ + 6144); \
} while (0)

#define RDB(pp, kh) do { \
  const char* p_ = LSB(pp) + bbase + ((kh) ? cx1 : cx0); \
  bfr[0] = *(const short8*)(p_ + 0); \
  bfr[1] = *(const short8*)(p_ + 2048); \
  bfr[2] = *(const short8*)(p_ + 4096); \
  bfr[3] = *(const short8*)(p_ + 6144); \
} while (0)

#define SGA(kt, c) gload16(srcA[c] + (kt) * 64, (short*)(LSA((kt) & 1) + ((c) * 512 + tid) * 16))
#define SGB(kt, c) gload16(srcB[c] + (kt) * 64, (short*)(LSB((kt) & 1) + ((c) * 512 + tid) * 16))
#define G1S(kt) do { SGA(kt, 0); SGA(kt, 2); SGB(kt, 0); SGB(kt, 1); } while (0)
#define G2S(kt) do { SGA(kt, 1); SGA(kt, 3); SGB(kt, 2); SGB(kt, 3); } while (0)

#define MFMA1(mi, ni) \
  acc[mi][ni] = __builtin_amdgcn_mfma_f32_16x16x32_bf16(afr[mi], bfr[ni], acc[mi][ni], 0, 0, 0)

#define MM(mh) do { \
  MFMA1((mh)*4+0, 0); MFMA1((mh)*4+1, 0); MFMA1((mh)*4+2, 0); MFMA1((mh)*4+3, 0); \
  MFMA1((mh)*4+0, 1); MFMA1((mh)*4+1, 1); MFMA1((mh)*4+2, 1); MFMA1((mh)*4+3, 1); \
  MFMA1((mh)*4+0, 2); MFMA1((mh)*4+1, 2); MFMA1((mh)*4+2, 2); MFMA1((mh)*4+3, 2); \
  MFMA1((mh)*4+0, 3); MFMA1((mh)*4+1, 3); MFMA1((mh)*4+2, 3); MFMA1((mh)*4+3, 3); \
} while (0)

#define GBAR() __builtin_amdgcn_s_barrier()
#define GLGKM0() __builtin_amdgcn_s_waitcnt(WAIT_LGKM)
#define GPRIO1() __builtin_amdgcn_s_setprio(1)
#define GPRIO0() __builtin_amdgcn_s_setprio(0)
#define GNOP ((void)0)

// One K-tile = 4 phases; SP1 staged in P1, SP4 + counted wait in P4.
#define TILE(pp, SP1, SP4, VMW) do { \
  RDA(pp, 0, 0); RDB(pp, 0); SP1; \
  GBAR(); GLGKM0(); GPRIO1(); MM(0); GPRIO0(); GBAR(); \
  RDA(pp, 0, 1); \
  GBAR(); GLGKM0(); GPRIO1(); MM(1); GPRIO0(); GBAR(); \
  RDA(pp, 1, 0); RDB(pp, 1); \
  GBAR(); GLGKM0(); GPRIO1(); MM(0); GPRIO0(); GBAR(); \
  RDA(pp, 1, 1); SP4; \
  GBAR(); GLGKM0(); GPRIO1(); MM(1); GPRIO0(); VMW; GBAR(); \
} while (0)

__global__ __launch_bounds__(512, 2) void gemm256_bt(
    const short* __restrict__ A, const short* __restrict__ B,
    short* __restrict__ C, int K, int lda, int ldb, int ldc) {
  __shared__ __align__(16) char Lsm[131072];

  const int tid = threadIdx.x;
  const int lane = tid & 63;
  const int l15 = lane & 15;
  const int quad = lane >> 4;      // 0..3
  const int wv = tid >> 6;         // 0..7
  const int wr = wv >> 2, wc = wv & 3;

  // 8Mx4N per-XCD partition (R6).
  const int bid = blockIdx.x;
  const int xcd = bid & 7;
  const int idx = bid >> 3;              // 0..31 within XCD
  const int m0 = (idx & 7) * 256;        // 8 M panels
  const int n0 = (xcd * 4 + (idx >> 3)) * 256;  // 4 N panels per XCD

  // staging sources: linear LDS dest + inverse-swizzled global source (R8).
  const int trow = tid >> 3;                               // 0..63
  const int scol = ((tid & 7) * 8) ^ ((trow & 7) * 8);     // shorts
  const short* srcA[4]; const short* srcB[4];
#pragma unroll
  for (int c = 0; c < 4; ++c) {
    srcA[c] = A + (size_t)(m0 + c * 64 + trow) * lda + scol;
    srcB[c] = B + (size_t)(n0 + c * 64 + trow) * ldb + scol;
  }

  // ds_read bases (bytes): row = {wr*128|wc*64} + sub + l15; swizzled col.
  const int abase = (wr * 128 + l15) * 128;
  const int bbase = (wc * 64 + l15) * 128;
  const int cx0 = (quad * 16) ^ ((l15 & 7) * 16);          // kh = 0
  const int cx1 = (64 + quad * 16) ^ ((l15 & 7) * 16);     // kh = 1

  f32x4 acc[8][4];
#pragma unroll
  for (int i = 0; i < 8; ++i)
#pragma unroll
    for (int j = 0; j < 4; ++j) acc[i][j] = (f32x4)(0.f);
  short8 afr[8], bfr[4];

  const int NT = K >> 6;   // even, >= 4

  // prologue: tile0 fully (8) + G1(tile1) (4); vmcnt(4) proves tile0.
  G1S(0); G2S(0); G1S(1);
  __builtin_amdgcn_s_waitcnt(WAIT_VM4);
  GBAR();

  int kt = 0;
  for (; kt + 4 <= NT; kt += 2) {
    TILE(0, G2S(kt + 1), G1S(kt + 2), __builtin_amdgcn_s_waitcnt(WAIT_VM4));
    TILE(1, G2S(kt + 2), G1S(kt + 3), __builtin_amdgcn_s_waitcnt(WAIT_VM4));
  }
  // tail: kt == NT-2. P1 stages G2(NT-1); vmcnt(0) proves NT-1; last tile bare.
  TILE(0, G2S(kt + 1), GNOP, __builtin_amdgcn_s_waitcnt(WAIT_VM0));
  TILE(1, GNOP, GNOP, GNOP);

#pragma unroll
  for (int m = 0; m < 8; ++m) {
    const size_t rb = (size_t)(m0 + wr * 128 + m * 16 + quad * 4) * ldc +
                      n0 + wc * 64 + l15;
#pragma unroll
    for (int n = 0; n < 4; ++n)
#pragma unroll
      for (int r = 0; r < 4; ++r)
        C[rb + (size_t)r * ldc + n * 16] = f2bf(acc[m][n][r]);
  }
}

// ---------------------------------------------------------------------------
// bf16 MFMA GEMM v2 (128^2): output projection (compact-lda A).
// ---------------------------------------------------------------------------
template <bool BF16OUT>
__global__ __launch_bounds__(256) void gemm_bt(
    const short* __restrict__ A, const short* __restrict__ B,
    void* __restrict__ Cv, int K, int lda, int ldb, int ldc, float oscale) {
  __shared__ __align__(16) short Ls[4][2][4096];

  const int tid = threadIdx.x;
  const int lane = tid & 63;
  const int wave = tid >> 6;
  const int wr = wave >> 1, wc = wave & 1;
  const int lane15 = lane & 15, quad = lane >> 4;
  const int m0 = blockIdx.y * 128, n0 = blockIdx.x * 128;

  const short* gA[4]; const short* gB[4];
#pragma unroll
  for (int i = 0; i < 4; ++i) {
    int gidx = i * 64 + lane;
    int r = gidx >> 2, p = gidx & 3;
    int g = (p ^ ((r >> 1) & 3)) * 8;
    gA[i] = A + (size_t)(m0 + wr * 64 + r) * lda + g;
    gB[i] = B + (size_t)(n0 + wc * 64 + r) * ldb + g;
  }

  f32x4 acc[4][4];
#pragma unroll
  for (int i = 0; i < 4; ++i)
#pragma unroll
    for (int j = 0; j < 4; ++j) acc[i][j] = (f32x4)(0.f);

#pragma unroll
  for (int i = 0; i < 4; ++i) gload16(gA[i], &Ls[wave][0][i * 512]);
#pragma unroll
  for (int i = 0; i < 4; ++i) gload16(gB[i], &Ls[wave][0][2048 + i * 512]);

  const int rsw = (lane15 >> 1) & 3;
  for (int k0 = 0; k0 < K; k0 += 32) {
    const int cur = (k0 >> 5) & 1;
    __builtin_amdgcn_s_waitcnt(WAIT_LGKM);
    if (k0 + 32 < K) {
      const int nxt = cur ^ 1;
#pragma unroll
      for (int i = 0; i < 4; ++i) gload16(gA[i] + k0 + 32, &Ls[wave][nxt][i * 512]);
#pragma unroll
      for (int i = 0; i < 4; ++i) gload16(gB[i] + k0 + 32, &Ls[wave][nxt][2048 + i * 512]);
      __builtin_amdgcn_s_waitcnt(WAIT_VM8);
    } else {
      __builtin_amdgcn_s_waitcnt(WAIT_VM0);
    }
    const short* bufp = &Ls[wave][cur][0];
    short8 af[4], bfv[4];
#pragma unroll
    for (int i = 0; i < 4; ++i)
      af[i] = *(const short8*)&bufp[(i * 16 + lane15) * 32 + (quad ^ rsw) * 8];
#pragma unroll
    for (int j = 0; j < 4; ++j)
      bfv[j] = *(const short8*)&bufp[2048 + (j * 16 + lane15) * 32 + (quad ^ rsw) * 8];
#pragma unroll
    for (int i = 0; i < 4; ++i)
#pragma unroll
      for (int j = 0; j < 4; ++j)
        acc[i][j] = __builtin_amdgcn_mfma_f32_16x16x32_bf16(af[i], bfv[j], acc[i][j], 0, 0, 0);
  }

#pragma unroll
  for (int i = 0; i < 4; ++i)
#pragma unroll
    for (int j = 0; j < 4; ++j)
#pragma unroll
      for (int r = 0; r < 4; ++r) {
        size_t idx = (size_t)(m0 + wr * 64 + i * 16 + quad * 4 + r) * ldc +
                     n0 + wc * 64 + j * 16 + lane15;
        if (BF16OUT)
          ((short*)Cv)[idx] = f2bf(acc[i][j][r] * oscale);
        else
          ((float*)Cv)[idx] = acc[i][j][r];
      }
}

// ---------------------------------------------------------------------------
// RoPE in-place on fused qkv bf16 [SEQ][QKVS].
// ---------------------------------------------------------------------------
__global__ __launch_bounds__(256) void rope_qk(
    short* __restrict__ qk, const float* __restrict__ cosf, const float* __restrict__ sinf) {
  int idx = blockIdx.x * blockDim.x + threadIdx.x;
  int j = idx & 31;
  int h = (idx >> 5) & (NH - 1);
  int s = idx >> 9;
  if (s >= SEQ) return;

  float c = cosf[s * 32 + j];
  float sn = sinf[s * 32 + j];
  size_t rowb = (size_t)s * QKVS + h * HD + NOPE + 2 * j;

  u32* pq = (u32*)(qk + rowb);
  u32 w = *pq;
  float a = bf2f((unsigned short)(w & 0xffff));
  float b = bf2f((unsigned short)(w >> 16));
  *pq = (u32)(unsigned short)f2bf(a * c - b * sn) |
        ((u32)(unsigned short)f2bf(a * sn + b * c) << 16);

  u32* pk = (u32*)(qk + rowb + QKD);
  w = *pk;
  a = bf2f((unsigned short)(w & 0xffff));
  b = bf2f((unsigned short)(w >> 16));
  *pk = (u32)(unsigned short)f2bf(a * c - b * sn) |
        ((u32)(unsigned short)f2bf(a * sn + b * c) << 16);
}

// ---------------------------------------------------------------------------
// Fused input converts: x -> xb and wq|wk|wv -> wqkv (one launch).
// ---------------------------------------------------------------------------
__global__ __launch_bounds__(256) void conv_in(
    const float* __restrict__ x, const float* __restrict__ wq,
    const float* __restrict__ wk, const float* __restrict__ wv,
    short* __restrict__ xb, short* __restrict__ wqkv) {
  const int NX4v = DIM * DIM / 4;
  int i = blockIdx.x * 256 + threadIdx.x;
  float4 f; short* dst; int di;
  if (i < NX4v) {
    f = ((const float4*)x)[i]; dst = xb; di = i;
  } else {
    int j = i - NX4v;
    int row = j >> 9;
    if (row < QKD) f = ((const float4*)wq)[j];
    else if (row < 2 * QKD) f = ((const float4*)wk)[j - QKD * (DIM / 4)];
    else f = ((const float4*)wv)[j - 2 * QKD * (DIM / 4)];
    dst = wqkv; di = j;
  }
  short4v o;
  o.x = f2bf(f.x); o.y = f2bf(f.y); o.z = f2bf(f.z); o.w = f2bf(f.w);
  ((short4v*)dst)[di] = o;
}

__global__ __launch_bounds__(256) void bf16_convert(
    const float* __restrict__ in, short* __restrict__ out, int n4) {
  int i = blockIdx.x * 256 + threadIdx.x;
  if (i >= n4) return;
  float4 f = ((const float4*)in)[i];
  short4v o;
  o.x = f2bf(f.x); o.y = f2bf(f.y); o.z = f2bf(f.z); o.w = f2bf(f.w);
  ((short4v*)out)[i] = o;
}

// ---------------------------------------------------------------------------
// v bf16 -> vtb bf16 [h][d][t] transpose.
// ---------------------------------------------------------------------------
__global__ __launch_bounds__(256) void vt_bf16(
    const short* __restrict__ vb, short* __restrict__ vtb) {
  __shared__ short tile[64][74];
  const int t0 = blockIdx.x * 64;
  const int c0 = blockIdx.y * 64;
  const int tid = threadIdx.x;
#pragma unroll
  for (int i = 0; i < 16; ++i) {
    int idx = i * 256 + tid;
    int r = idx >> 6, c = idx & 63;
    tile[r][c] = vb[(size_t)(t0 + r) * QKVS + c0 + c];
  }
  __syncthreads();
  const int h = c0 >> 7;
  const int dbase = c0 & 127;
#pragma unroll
  for (int i = 0; i < 16; ++i) {
    int idx = i * 256 + tid;
    int d = idx >> 6, t = idx & 63;
    vtb[(size_t)h * VDIM * SEQ + (size_t)(dbase + d) * SEQ + t0 + t] = tile[t][d];
  }
}

// ---------------------------------------------------------------------------
// Split-T flash attention v5: BQ=128, 8 waves, PIPELINED 3-barrier schedule.
//  - Ks double-buffered; V single-buffered; Ps halved (two-pass PV through a
//    32-col buffer) so LDS = 49152 + 16384 + 9216 = 74752 B -> 2 blocks/CU.
//  - Per tile: [issue K(t+1)] QK(t) softmax | vmcnt(3)+bar (V(t) proven,
//    issued last tile -> fully covered) | PV0, PV1 | lgkm+bar (Vt free) |
//    issue V(t+1) | vmcnt(2)+bar (K(t+1) proven, covered by QK+softmax).
//    vmcnt never drains to 0 mid-loop; every load has >=500cy cover.
//  - All barriers block-uniform (have/kt_end uniform); cooperative-write
//    safety via per-wave vmcnt + barrier at each prove point.
// ---------------------------------------------------------------------------
#define BQ 128
#define BT 64
#define CHT 8
#define PSTR2 36
#define MFIX 8.0f

__global__ __launch_bounds__(512, 4) void attn_part(
    const short* __restrict__ qk,   // [SEQ][QKVS] bf16
    const short* __restrict__ vtb,  // [NH][VDIM][SEQ] bf16
    short* __restrict__ Opart,      // [640][128][128] bf16
    float* __restrict__ lpart)      // [640][128] fp32
{
  __shared__ __align__(16) short Ks[2][BT * 192];    // 49152 B
  __shared__ __align__(16) short Vt[VDIM * BT];      // 16384 B
  __shared__ __align__(16) short Ps[8 * 16 * PSTR2]; // 9216 B

  // decode: xcd owns heads {xcd, xcd+8}; heavy qt-blocks first.
  const int xcd = blockIdx.x;          // 0..7
  const int i0 = blockIdx.y;           // 0..79
  const int h = xcd + ((i0 >= 40) ? 8 : 0);
  int jj = (i0 >= 40) ? (i0 - 40) : i0;  // 0..39
  int qtb = 15;
  while (jj >= (qtb >> 2) + 1) { jj -= (qtb >> 2) + 1; --qtb; }
  const int chk = jj;                   // 0..(qtb>>2)

  const int tid = threadIdx.x;
  const int wave = tid >> 6;            // 0..7
  const int lane = tid & 63;
  const int lane15 = lane & 15;
  const int quad = lane >> 4;
  const int g = qtb >> 2;
  const int slot = h * 40 + (g + 1) * (2 * g + (qtb & 3)) + chk;
  const int R0 = qtb * BQ;
  const int NT = 2 * qtb + 2;
  const int kt_beg = chk * CHT;
  const int kt_end = min(kt_beg + CHT, NT);
  const float scale = 0.072168784f;  // 1/sqrt(192)

  // Q A-frags: wave's 16 rows. Drain fully so the in-loop vmcnt ledger is
  // exact (only gload16s outstanding afterwards).
  const int qrow = R0 + wave * 16 + lane15;
  short8 qf[6];
  const short* qbase = qk + (size_t)qrow * QKVS + h * HD + quad * 8;
#pragma unroll
  for (int kc = 0; kc < 6; ++kc) qf[kc] = *(const short8*)(qbase + kc * 32);
  __builtin_amdgcn_s_waitcnt(WAIT_VM0);
  __builtin_amdgcn_sched_barrier(0);

  // staging descriptors (XOR-swizzled), 512 threads: K 3/thread, V 2/thread
  const short* kb = qk + QKD;
  int lKoff[3]; const short* gK[3];
#pragma unroll
  for (int i = 0; i < 3; ++i) {
    int id = i * 512 + tid;
    int row = id / 24, cX = id - row * 24;
    int ch = cX ^ (row & 7);
    lKoff[i] = id * 8;
    gK[i] = kb + (size_t)row * QKVS + h * HD + ch * 8;
  }
  const short* gV[2]; short* lV[2];
#pragma unroll
  for (int i = 0; i < 2; ++i) {
    int id = i * 512 + tid;
    int row = id >> 3, cX = id & 7;
    int ch = cX ^ (row & 7);
    lV[i] = &Vt[id * 8];
    gV[i] = vtb + (size_t)h * VDIM * SEQ + (size_t)row * SEQ + ch * 8;
  }

  f32x4 oacc[8];
#pragma unroll
  for (int i = 0; i < 8; ++i) oacc[i] = (f32x4)(0.f);
  float lsum[4] = {0.f, 0.f, 0.f, 0.f};

  short* pw = &Ps[wave * 16 * PSTR2];

  // prologue: stage K(t0)->Ks[0] (3) + V(t0)->Vt (2); vmcnt(2) proves K,
  // V stays in flight (proven at first tile's bar before PV).
  {
    const size_t t0 = (size_t)kt_beg * BT;
#pragma unroll
    for (int i = 0; i < 3; ++i) gload16(gK[i] + t0 * QKVS, &Ks[0][lKoff[i]]);
#pragma unroll
    for (int i = 0; i < 2; ++i) gload16(gV[i] + t0, lV[i]);
  }
  __builtin_amdgcn_s_waitcnt(WAIT_VM2);
  __builtin_amdgcn_s_barrier();
  __builtin_amdgcn_sched_barrier(0);

  for (int kt = kt_beg; kt < kt_end; ++kt) {
    const int cur = (kt - kt_beg) & 1;
    const bool have = (kt + 1 < kt_end);

    // issue K(t+1) -> Ks[nxt] (region safe: last read QK(t-1), two barriers ago)
    if (have) {
      const size_t tn = (size_t)(kt + 1) * BT;
#pragma unroll
      for (int i = 0; i < 3; ++i) gload16(gK[i] + tn * QKVS, &Ks[cur ^ 1][lKoff[i]]);
    }

    // S = Q K^T on Ks[cur] (proven by previous tile's final barrier)
    const short* kcur = &Ks[cur][0];
    f32x4 sacc[4];
    __builtin_amdgcn_s_setprio(1);
#pragma unroll
    for (int c = 0; c < 4; ++c) {
      sacc[c] = (f32x4)(0.f);
      const int row = c * 16 + lane15;
#pragma unroll
      for (int kc = 0; kc < 6; ++kc) {
        int cX = (4 * kc + quad) ^ (lane15 & 7);
        short8 kf = *(const short8*)&kcur[row * 192 + cX * 8];
        sacc[c] = __builtin_amdgcn_mfma_f32_16x16x32_bf16(qf[kc], kf, sacc[c], 0, 0, 0);
      }
    }
    __builtin_amdgcn_s_setprio(0);

    if (kt >= 2 * qtb) {  // tiles possibly crossing the diagonal
#pragma unroll
      for (int c = 0; c < 4; ++c)
#pragma unroll
        for (int r = 0; r < 4; ++r) {
          int tg = kt * BT + c * 16 + lane15;
          int qg = R0 + wave * 16 + quad * 4 + r;
          if (tg > qg) sacc[c][r] = -1e30f;
        }
    }

    // softmax: exp all 64, lsum; p kept in sacc
#pragma unroll
    for (int c = 0; c < 4; ++c)
#pragma unroll
      for (int r = 0; r < 4; ++r) {
        float p = __expf(sacc[c][r] * scale - MFIX);
        lsum[r] += p;
        sacc[c][r] = p;
      }

    // P half0 (t cols 0..31) -> Ps (wave-private), read pf0
#pragma unroll
    for (int c = 0; c < 2; ++c)
#pragma unroll
      for (int r = 0; r < 4; ++r)
        pw[(quad * 4 + r) * PSTR2 + c * 16 + lane15] = f2bf(sacc[c][r]);
    short8 pf0 = *(const short8*)&pw[lane15 * PSTR2 + quad * 8];

    // prove V(t): per-wave count (queue [V2,K3] -> vmcnt(3)) + barrier
    // (Vt is written cooperatively -> every wave's count must clear)
    if (have) __builtin_amdgcn_s_waitcnt(WAIT_VM3);
    else      __builtin_amdgcn_s_waitcnt(WAIT_VM0);
    __builtin_amdgcn_s_barrier();
    __builtin_amdgcn_sched_barrier(0);

    // PV half0 (t 0..31)
    __builtin_amdgcn_s_setprio(1);
#pragma unroll
    for (int ch = 0; ch < 8; ++ch) {
      const int row = ch * 16 + lane15;
      int cX0 = quad ^ (lane15 & 7);
      short8 vf0 = *(const short8*)&Vt[row * 64 + cX0 * 8];
      oacc[ch] = __builtin_amdgcn_mfma_f32_16x16x32_bf16(pf0, vf0, oacc[ch], 0, 0, 0);
    }
    __builtin_amdgcn_s_setprio(0);

    // P half1 (t cols 32..63) -> same Ps region (same-wave DS in-order), PV half1
#pragma unroll
    for (int c = 0; c < 2; ++c)
#pragma unroll
      for (int r = 0; r < 4; ++r)
        pw[(quad * 4 + r) * PSTR2 + c * 16 + lane15] = f2bf(sacc[2 + c][r]);
    short8 pf1 = *(const short8*)&pw[lane15 * PSTR2 + quad * 8];
    __builtin_amdgcn_s_setprio(1);
#pragma unroll
    for (int ch = 0; ch < 8; ++ch) {
      const int row = ch * 16 + lane15;
      int cX1 = (4 + quad) ^ (lane15 & 7);
      short8 vf1 = *(const short8*)&Vt[row * 64 + cX1 * 8];
      oacc[ch] = __builtin_amdgcn_mfma_f32_16x16x32_bf16(pf1, vf1, oacc[ch], 0, 0, 0);
    }
    __builtin_amdgcn_s_setprio(0);

    if (have) {
      // all waves done reading Vt (and Ks[cur]) -> Vt free
      __builtin_amdgcn_s_waitcnt(WAIT_LGKM);
      __builtin_amdgcn_s_barrier();
      const size_t tn = (size_t)(kt + 1) * BT;
#pragma unroll
      for (int i = 0; i < 2; ++i) gload16(gV[i] + tn, lV[i]);
      // prove K(t+1): queue [K3,V2] -> vmcnt(2); barrier collects all waves
      __builtin_amdgcn_s_waitcnt(WAIT_VM2);
      __builtin_amdgcn_s_barrier();
      __builtin_amdgcn_sched_barrier(0);
    }
  }

  // epilogue: write unnormalized partials ([128][128] per slot)
  short* op = Opart + (size_t)slot * (128 * 128);
#pragma unroll
  for (int ch = 0; ch < 8; ++ch)
#pragma unroll
    for (int r = 0; r < 4; ++r)
      op[(wave * 16 + quad * 4 + r) * 128 + ch * 16 + lane15] = f2bf(oacc[ch][r]);

  float red[4];
#pragma unroll
  for (int r = 0; r < 4; ++r) {
    float s = lsum[r];
    s += __shfl_xor(s, 1, 64);
    s += __shfl_xor(s, 2, 64);
    s += __shfl_xor(s, 4, 64);
    s += __shfl_xor(s, 8, 64);
    red[r] = s;
  }
  if (lane15 == 0) {
#pragma unroll
    for (int r = 0; r < 4; ++r)
      lpart[(size_t)slot * 128 + wave * 16 + quad * 4 + r] = red[r];
  }
}

// ---------------------------------------------------------------------------
// Phase B: sum chunk partials, normalize, write COMPACT aob [2048][2048] bf16.
// ---------------------------------------------------------------------------
__global__ __launch_bounds__(256) void attn_combine(
    const short* __restrict__ Opart, const float* __restrict__ lpart,
    short* __restrict__ aob) {   // compact [SEQ][VD], row stride VD=2048
  const int qt64 = blockIdx.x, h = blockIdx.y;
  const int qtb = qt64 >> 1;
  const int half = qt64 & 1;
  const int g = qtb >> 2;
  const int nact = g + 1;
  const int base = h * 40 + (g + 1) * (2 * g + (qtb & 3));
  const int tid = threadIdx.x;
  const int row = tid >> 2;            // 0..63
  const int cg = (tid & 3) * 32;

  float acc[32];
#pragma unroll
  for (int e = 0; e < 32; ++e) acc[e] = 0.f;
  float lsum = 0.f;

  for (int c = 0; c < nact; ++c) {
    const short* sp = Opart + (size_t)(base + c) * (128 * 128) +
                      (half * 64 + row) * 128 + cg;
    lsum += lpart[(size_t)(base + c) * 128 + half * 64 + row];
#pragma unroll
    for (int gg = 0; gg < 4; ++gg) {
      short8 vv = *(const short8*)(sp + gg * 8);
#pragma unroll
      for (int e = 0; e < 8; ++e) acc[gg * 8 + e] += bf2f((unsigned short)vv[e]);
    }
  }

  float inv = 1.f / lsum;
#pragma unroll
  for (int gg = 0; gg < 4; ++gg) {
    short8 ov;
#pragma unroll
    for (int e = 0; e < 8; ++e) ov[e] = f2bf(acc[gg * 8 + e] * inv);
    *(short8*)(aob + (size_t)(qt64 * 64 + row) * VD + h * 128 + cg + gg * 8) = ov;
  }
}

// ---------------------------------------------------------------------------
// Workspace (bytes), peak 75,497,472 (< proven 79,691,776):
//   [0,        8388608)  xb  -> wo_b (after qkv gemm)
//   [8388608, 41943040)  wqkv -> {vtb@8388608, Opart@16777216 (20,971,520),
//                        lpart@37748736 (327,680)}
//   [41943040,75497472)  qkv bf16 [2048][8192]; AFTER attn_combine, qkv is
//                        dead and compact aob [2048][2048] bf16 (8 MB) lives
//                        at the qkv base.
// ---------------------------------------------------------------------------
extern "C" void kernel_launch(void* const* d_in, const int* in_sizes, int n_in,
                              void* d_out, int out_size, void* d_ws, size_t ws_size,
                              hipStream_t stream) {
  const float* x  = (const float*)d_in[0];
  const float* wq = (const float*)d_in[1];
  const float* wk = (const float*)d_in[2];
  const float* wv = (const float*)d_in[3];
  const float* wo = (const float*)d_in[4];
  const float* fc = (const float*)d_in[5];
  const float* fs = (const float*)d_in[6];

  char* ws8 = (char*)d_ws;
  short* xb    = (short*)(ws8 + 0);
  short* wo_b  = (short*)(ws8 + 0);
  short* wqkv  = (short*)(ws8 + 8388608);
  short* vtb   = (short*)(ws8 + 8388608);
  short* Opart = (short*)(ws8 + 16777216);
  float* lpart = (float*)(ws8 + 37748736);
  short* qkv   = (short*)(ws8 + 41943040);
  short* aob   = qkv;   // compact aob overwrites dead qkv after attn_combine
  float* out   = (float*)d_out;

  const int NX4 = DIM * DIM / 4;
  const int NQKV4 = QKVS * DIM / 4;
  const int ROPE_GRID = (SEQ * NH * 32) / 256;

  // fused input converts (x + wq|wk|wv), one launch
  conv_in<<<(NX4 + NQKV4) / 256, 256, 0, stream>>>(x, wq, wk, wv, xb, wqkv);

  // fused QKV projection: qkv [2048][8192] via 256^2 kernel (m201-layout).
  gemm256_bt<<<dim3((QKVS / 256) * (SEQ / 256)), 512, 0, stream>>>(
      xb, wqkv, qkv, DIM, DIM, DIM, QKVS);
  rope_qk<<<ROPE_GRID, 256, 0, stream>>>(qkv, fc, fs);
  vt_bf16<<<dim3(SEQ / 64, VD / 64), 256, 0, stream>>>(qkv + 2 * QKD, vtb);

  // wo convert (xb dead after qkv gemm)
  bf16_convert<<<(NX4 + 255) / 256, 256, 0, stream>>>(wo, wo_b, NX4);

  // split-T attention: grid (8 xcd, 80 chunks) = 640 blocks, 512 threads
  attn_part<<<dim3(8, 80), 512, 0, stream>>>(qkv, vtb, Opart, lpart);
  attn_combine<<<dim3(SEQ / 64, NH), 256, 0, stream>>>(Opart, lpart, aob);

  // output projection: A = compact aob, lda = VD (contiguous rows)
  gemm_bt<false><<<dim3(DIM / 128, SEQ / 128), 256, 0, stream>>>(
      aob, wo_b, out, DIM, VD, DIM, DIM, 1.0f);
}

// Round 11
// 311.710 us; speedup vs baseline: 1.0487x; 1.0017x over previous
//
#include <hip/hip_runtime.h>
#include <hip/hip_bf16.h>
#include <math.h>

#define NH 16
#define NOPE 128
#define ROPE 64
#define VDIM 128
#define HD 192          // HEAD_DIM
#define SEQ 2048
#define DIM 2048
#define QKD (NH * HD)   // 3072
#define VD  (NH * VDIM) // 2048
#define QKVS 8192       // fused q|k|v row stride (shorts): [q 3072][k 3072][v 2048]

typedef __attribute__((ext_vector_type(8))) short short8;   // 8 bf16 = 4 VGPRs
typedef __attribute__((ext_vector_type(4))) short short4v;
typedef __attribute__((ext_vector_type(4))) float f32x4;
typedef unsigned int u32;

// s_waitcnt immediates (gfx9 encoding: vmcnt[3:0]@0, expcnt@4, lgkmcnt@8, vmcnt[5:4]@14)
#define WAIT_VM8  0x0F78   // vmcnt(8)
#define WAIT_VM6  0x0F76   // vmcnt(6)
#define WAIT_VM4  0x0F74   // vmcnt(4)
#define WAIT_VM3  0x0F73   // vmcnt(3)
#define WAIT_VM2  0x0F72   // vmcnt(2)
#define WAIT_VM0  0x0F70   // vmcnt(0)
#define WAIT_LGKM 0xC07F   // lgkmcnt(0), vmcnt/exp no-wait

static __device__ inline short f2bf(float f) {
  union { float f; unsigned u; } v; v.f = f;
  unsigned r = (v.u + 0x7fffu + ((v.u >> 16) & 1u)) >> 16;
  return (short)r;
}
static __device__ inline u32 packbf(float lo, float hi) {
  return (u32)(unsigned short)f2bf(lo) | ((u32)(unsigned short)f2bf(hi) << 16);
}
static __device__ inline float bf2f(unsigned short u) {
  union { unsigned u; float f; } v; v.u = ((unsigned)u) << 16;
  return v.f;
}

// async global->LDS, 16B/lane. LDS dest = wave-uniform base + lane*16.
static __device__ __forceinline__ void gload16(const short* g, short* l) {
  __builtin_amdgcn_global_load_lds(
      (const __attribute__((address_space(1))) u32*)g,
      (__attribute__((address_space(3))) u32*)l, 16, 0, 0);
}

// ---------------------------------------------------------------------------
// 256x256 bf16 GEMM, C = A * B^T.  Unchanged from R8 (m201 layout+staging).
// ---------------------------------------------------------------------------

#define LSA(pp) (Lsm + (pp) * 65536)
#define LSB(pp) (Lsm + (pp) * 65536 + 32768)

#define RDA(pp, kh, mh) do { \
  const char* p_ = LSA(pp) + abase + (mh) * 8192 + ((kh) ? cx1 : cx0); \
  afr[(mh) * 4 + 0] = *(const short8*)(p_ + 0); \
  afr[(mh) * 4 + 1] = *(const short8*)(p_ + 2048); \
  afr[(mh) * 4 + 2] = *(const short8*)(p_ + 4096); \
  afr[(mh) * 4 + 3] = *(const short8*)(p_ + 6144); \
} while (0)

#define RDB(pp, kh) do { \
  const char* p_ = LSB(pp) + bbase + ((kh) ? cx1 : cx0); \
  bfr[0] = *(const short8*)(p_ + 0); \
  bfr[1] = *(const short8*)(p_ + 2048); \
  bfr[2] = *(const short8*)(p_ + 4096); \
  bfr[3] = *(const short8*)(p_ + 6144); \
} while (0)

#define SGA(kt, c) gload16(srcA[c] + (kt) * 64, (short*)(LSA((kt) & 1) + ((c) * 512 + tid) * 16))
#define SGB(kt, c) gload16(srcB[c] + (kt) * 64, (short*)(LSB((kt) & 1) + ((c) * 512 + tid) * 16))
#define G1S(kt) do { SGA(kt, 0); SGA(kt, 2); SGB(kt, 0); SGB(kt, 1); } while (0)
#define G2S(kt) do { SGA(kt, 1); SGA(kt, 3); SGB(kt, 2); SGB(kt, 3); } while (0)

#define MFMA1(mi, ni) \
  acc[mi][ni] = __builtin_amdgcn_mfma_f32_16x16x32_bf16(afr[mi], bfr[ni], acc[mi][ni], 0, 0, 0)

#define MM(mh) do { \
  MFMA1((mh)*4+0, 0); MFMA1((mh)*4+1, 0); MFMA1((mh)*4+2, 0); MFMA1((mh)*4+3, 0); \
  MFMA1((mh)*4+0, 1); MFMA1((mh)*4+1, 1); MFMA1((mh)*4+2, 1); MFMA1((mh)*4+3, 1); \
  MFMA1((mh)*4+0, 2); MFMA1((mh)*4+1, 2); MFMA1((mh)*4+2, 2); MFMA1((mh)*4+3, 2); \
  MFMA1((mh)*4+0, 3); MFMA1((mh)*4+1, 3); MFMA1((mh)*4+2, 3); MFMA1((mh)*4+3, 3); \
} while (0)

#define GBAR() __builtin_amdgcn_s_barrier()
#define GLGKM0() __builtin_amdgcn_s_waitcnt(WAIT_LGKM)
#define GPRIO1() __builtin_amdgcn_s_setprio(1)
#define GPRIO0() __builtin_amdgcn_s_setprio(0)
#define GNOP ((void)0)

// One K-tile = 4 phases; SP1 staged in P1, SP4 + counted wait in P4.
#define TILE(pp, SP1, SP4, VMW) do { \
  RDA(pp, 0, 0); RDB(pp, 0); SP1; \
  GBAR(); GLGKM0(); GPRIO1(); MM(0); GPRIO0(); GBAR(); \
  RDA(pp, 0, 1); \
  GBAR(); GLGKM0(); GPRIO1(); MM(1); GPRIO0(); GBAR(); \
  RDA(pp, 1, 0); RDB(pp, 1); \
  GBAR(); GLGKM0(); GPRIO1(); MM(0); GPRIO0(); GBAR(); \
  RDA(pp, 1, 1); SP4; \
  GBAR(); GLGKM0(); GPRIO1(); MM(1); GPRIO0(); VMW; GBAR(); \
} while (0)

__global__ __launch_bounds__(512, 2) void gemm256_bt(
    const short* __restrict__ A, const short* __restrict__ B,
    short* __restrict__ C, int K, int lda, int ldb, int ldc) {
  __shared__ __align__(16) char Lsm[131072];

  const int tid = threadIdx.x;
  const int lane = tid & 63;
  const int l15 = lane & 15;
  const int quad = lane >> 4;      // 0..3
  const int wv = tid >> 6;         // 0..7
  const int wr = wv >> 2, wc = wv & 3;

  // 8Mx4N per-XCD partition (R6).
  const int bid = blockIdx.x;
  const int xcd = bid & 7;
  const int idx = bid >> 3;              // 0..31 within XCD
  const int m0 = (idx & 7) * 256;        // 8 M panels
  const int n0 = (xcd * 4 + (idx >> 3)) * 256;  // 4 N panels per XCD

  // staging sources: linear LDS dest + inverse-swizzled global source (R8).
  const int trow = tid >> 3;                               // 0..63
  const int scol = ((tid & 7) * 8) ^ ((trow & 7) * 8);     // shorts
  const short* srcA[4]; const short* srcB[4];
#pragma unroll
  for (int c = 0; c < 4; ++c) {
    srcA[c] = A + (size_t)(m0 + c * 64 + trow) * lda + scol;
    srcB[c] = B + (size_t)(n0 + c * 64 + trow) * ldb + scol;
  }

  // ds_read bases (bytes): row = {wr*128|wc*64} + sub + l15; swizzled col.
  const int abase = (wr * 128 + l15) * 128;
  const int bbase = (wc * 64 + l15) * 128;
  const int cx0 = (quad * 16) ^ ((l15 & 7) * 16);          // kh = 0
  const int cx1 = (64 + quad * 16) ^ ((l15 & 7) * 16);     // kh = 1

  f32x4 acc[8][4];
#pragma unroll
  for (int i = 0; i < 8; ++i)
#pragma unroll
    for (int j = 0; j < 4; ++j) acc[i][j] = (f32x4)(0.f);
  short8 afr[8], bfr[4];

  const int NT = K >> 6;   // even, >= 4

  // prologue: tile0 fully (8) + G1(tile1) (4); vmcnt(4) proves tile0.
  G1S(0); G2S(0); G1S(1);
  __builtin_amdgcn_s_waitcnt(WAIT_VM4);
  GBAR();

  int kt = 0;
  for (; kt + 4 <= NT; kt += 2) {
    TILE(0, G2S(kt + 1), G1S(kt + 2), __builtin_amdgcn_s_waitcnt(WAIT_VM4));
    TILE(1, G2S(kt + 2), G1S(kt + 3), __builtin_amdgcn_s_waitcnt(WAIT_VM4));
  }
  // tail: kt == NT-2. P1 stages G2(NT-1); vmcnt(0) proves NT-1; last tile bare.
  TILE(0, G2S(kt + 1), GNOP, __builtin_amdgcn_s_waitcnt(WAIT_VM0));
  TILE(1, GNOP, GNOP, GNOP);

#pragma unroll
  for (int m = 0; m < 8; ++m) {
    const size_t rb = (size_t)(m0 + wr * 128 + m * 16 + quad * 4) * ldc +
                      n0 + wc * 64 + l15;
#pragma unroll
    for (int n = 0; n < 4; ++n)
#pragma unroll
      for (int r = 0; r < 4; ++r)
        C[rb + (size_t)r * ldc + n * 16] = f2bf(acc[m][n][r]);
  }
}

// ---------------------------------------------------------------------------
// bf16 MFMA GEMM v2 (128^2): output projection (compact-lda A).
// ---------------------------------------------------------------------------
template <bool BF16OUT>
__global__ __launch_bounds__(256) void gemm_bt(
    const short* __restrict__ A, const short* __restrict__ B,
    void* __restrict__ Cv, int K, int lda, int ldb, int ldc, float oscale) {
  __shared__ __align__(16) short Ls[4][2][4096];

  const int tid = threadIdx.x;
  const int lane = tid & 63;
  const int wave = tid >> 6;
  const int wr = wave >> 1, wc = wave & 1;
  const int lane15 = lane & 15, quad = lane >> 4;
  const int m0 = blockIdx.y * 128, n0 = blockIdx.x * 128;

  const short* gA[4]; const short* gB[4];
#pragma unroll
  for (int i = 0; i < 4; ++i) {
    int gidx = i * 64 + lane;
    int r = gidx >> 2, p = gidx & 3;
    int g = (p ^ ((r >> 1) & 3)) * 8;
    gA[i] = A + (size_t)(m0 + wr * 64 + r) * lda + g;
    gB[i] = B + (size_t)(n0 + wc * 64 + r) * ldb + g;
  }

  f32x4 acc[4][4];
#pragma unroll
  for (int i = 0; i < 4; ++i)
#pragma unroll
    for (int j = 0; j < 4; ++j) acc[i][j] = (f32x4)(0.f);

#pragma unroll
  for (int i = 0; i < 4; ++i) gload16(gA[i], &Ls[wave][0][i * 512]);
#pragma unroll
  for (int i = 0; i < 4; ++i) gload16(gB[i], &Ls[wave][0][2048 + i * 512]);

  const int rsw = (lane15 >> 1) & 3;
  for (int k0 = 0; k0 < K; k0 += 32) {
    const int cur = (k0 >> 5) & 1;
    __builtin_amdgcn_s_waitcnt(WAIT_LGKM);
    if (k0 + 32 < K) {
      const int nxt = cur ^ 1;
#pragma unroll
      for (int i = 0; i < 4; ++i) gload16(gA[i] + k0 + 32, &Ls[wave][nxt][i * 512]);
#pragma unroll
      for (int i = 0; i < 4; ++i) gload16(gB[i] + k0 + 32, &Ls[wave][nxt][2048 + i * 512]);
      __builtin_amdgcn_s_waitcnt(WAIT_VM8);
    } else {
      __builtin_amdgcn_s_waitcnt(WAIT_VM0);
    }
    const short* bufp = &Ls[wave][cur][0];
    short8 af[4], bfv[4];
#pragma unroll
    for (int i = 0; i < 4; ++i)
      af[i] = *(const short8*)&bufp[(i * 16 + lane15) * 32 + (quad ^ rsw) * 8];
#pragma unroll
    for (int j = 0; j < 4; ++j)
      bfv[j] = *(const short8*)&bufp[2048 + (j * 16 + lane15) * 32 + (quad ^ rsw) * 8];
#pragma unroll
    for (int i = 0; i < 4; ++i)
#pragma unroll
      for (int j = 0; j < 4; ++j)
        acc[i][j] = __builtin_amdgcn_mfma_f32_16x16x32_bf16(af[i], bfv[j], acc[i][j], 0, 0, 0);
  }

#pragma unroll
  for (int i = 0; i < 4; ++i)
#pragma unroll
    for (int j = 0; j < 4; ++j)
#pragma unroll
      for (int r = 0; r < 4; ++r) {
        size_t idx = (size_t)(m0 + wr * 64 + i * 16 + quad * 4 + r) * ldc +
                     n0 + wc * 64 + j * 16 + lane15;
        if (BF16OUT)
          ((short*)Cv)[idx] = f2bf(acc[i][j][r] * oscale);
        else
          ((float*)Cv)[idx] = acc[i][j][r];
      }
}

// ---------------------------------------------------------------------------
// RoPE in-place on fused qkv bf16 [SEQ][QKVS].
// ---------------------------------------------------------------------------
__global__ __launch_bounds__(256) void rope_qk(
    short* __restrict__ qk, const float* __restrict__ cosf, const float* __restrict__ sinf) {
  int idx = blockIdx.x * blockDim.x + threadIdx.x;
  int j = idx & 31;
  int h = (idx >> 5) & (NH - 1);
  int s = idx >> 9;
  if (s >= SEQ) return;

  float c = cosf[s * 32 + j];
  float sn = sinf[s * 32 + j];
  size_t rowb = (size_t)s * QKVS + h * HD + NOPE + 2 * j;

  u32* pq = (u32*)(qk + rowb);
  u32 w = *pq;
  float a = bf2f((unsigned short)(w & 0xffff));
  float b = bf2f((unsigned short)(w >> 16));
  *pq = (u32)(unsigned short)f2bf(a * c - b * sn) |
        ((u32)(unsigned short)f2bf(a * sn + b * c) << 16);

  u32* pk = (u32*)(qk + rowb + QKD);
  w = *pk;
  a = bf2f((unsigned short)(w & 0xffff));
  b = bf2f((unsigned short)(w >> 16));
  *pk = (u32)(unsigned short)f2bf(a * c - b * sn) |
        ((u32)(unsigned short)f2bf(a * sn + b * c) << 16);
}

// ---------------------------------------------------------------------------
// Fused input converts: x -> xb and wq|wk|wv -> wqkv (one launch).
// ---------------------------------------------------------------------------
__global__ __launch_bounds__(256) void conv_in(
    const float* __restrict__ x, const float* __restrict__ wq,
    const float* __restrict__ wk, const float* __restrict__ wv,
    short* __restrict__ xb, short* __restrict__ wqkv) {
  const int NX4v = DIM * DIM / 4;
  int i = blockIdx.x * 256 + threadIdx.x;
  float4 f; short* dst; int di;
  if (i < NX4v) {
    f = ((const float4*)x)[i]; dst = xb; di = i;
  } else {
    int j = i - NX4v;
    int row = j >> 9;
    if (row < QKD) f = ((const float4*)wq)[j];
    else if (row < 2 * QKD) f = ((const float4*)wk)[j - QKD * (DIM / 4)];
    else f = ((const float4*)wv)[j - 2 * QKD * (DIM / 4)];
    dst = wqkv; di = j;
  }
  short4v o;
  o.x = f2bf(f.x); o.y = f2bf(f.y); o.z = f2bf(f.z); o.w = f2bf(f.w);
  ((short4v*)dst)[di] = o;
}

__global__ __launch_bounds__(256) void bf16_convert(
    const float* __restrict__ in, short* __restrict__ out, int n4) {
  int i = blockIdx.x * 256 + threadIdx.x;
  if (i >= n4) return;
  float4 f = ((const float4*)in)[i];
  short4v o;
  o.x = f2bf(f.x); o.y = f2bf(f.y); o.z = f2bf(f.z); o.w = f2bf(f.w);
  ((short4v*)out)[i] = o;
}

// ---------------------------------------------------------------------------
// v bf16 -> vtb bf16 [h][d][t] transpose.
// ---------------------------------------------------------------------------
__global__ __launch_bounds__(256) void vt_bf16(
    const short* __restrict__ vb, short* __restrict__ vtb) {
  __shared__ short tile[64][74];
  const int t0 = blockIdx.x * 64;
  const int c0 = blockIdx.y * 64;
  const int tid = threadIdx.x;
#pragma unroll
  for (int i = 0; i < 16; ++i) {
    int idx = i * 256 + tid;
    int r = idx >> 6, c = idx & 63;
    tile[r][c] = vb[(size_t)(t0 + r) * QKVS + c0 + c];
  }
  __syncthreads();
  const int h = c0 >> 7;
  const int dbase = c0 & 127;
#pragma unroll
  for (int i = 0; i < 16; ++i) {
    int idx = i * 256 + tid;
    int d = idx >> 6, t = idx & 63;
    vtb[(size_t)h * VDIM * SEQ + (size_t)(dbase + d) * SEQ + t0 + t] = tile[t][d];
  }
}

// ---------------------------------------------------------------------------
// Split-T flash attention v6: swapped-QK^T IN-REGISTER softmax (T12 pattern).
//  - QK^T computed as mfma(K,Q) -> lane holds S[t=c*16+quad*4+r][q=lane15]:
//    each lane owns 16 P-values of ONE q-row -> lsum is a per-lane scalar
//    (block-end shfl_xor(16,32) reduce), and the PV A-fragment is built with
//    16 __shfl + selects per tile -- the entire Ps LDS roundtrip is deleted.
//  - Pipeline identical to v5 (K dbuf, V single, 3 barriers/tile, counted
//    vmcnt never 0 mid-loop). LDS = 49152 + 16384 = 65536 -> 2 blocks/CU.
// ---------------------------------------------------------------------------
#define BQ 128
#define BT 64
#define CHT 8
#define MFIX 8.0f

__global__ __launch_bounds__(512, 4) void attn_part(
    const short* __restrict__ qk,   // [SEQ][QKVS] bf16
    const short* __restrict__ vtb,  // [NH][VDIM][SEQ] bf16
    short* __restrict__ Opart,      // [640][128][128] bf16
    float* __restrict__ lpart)      // [640][128] fp32
{
  __shared__ __align__(16) short Ks[2][BT * 192];    // 49152 B
  __shared__ __align__(16) short Vt[VDIM * BT];      // 16384 B

  // decode: xcd owns heads {xcd, xcd+8}; heavy qt-blocks first.
  const int xcd = blockIdx.x;          // 0..7
  const int i0 = blockIdx.y;           // 0..79
  const int h = xcd + ((i0 >= 40) ? 8 : 0);
  int jj = (i0 >= 40) ? (i0 - 40) : i0;  // 0..39
  int qtb = 15;
  while (jj >= (qtb >> 2) + 1) { jj -= (qtb >> 2) + 1; --qtb; }
  const int chk = jj;                   // 0..(qtb>>2)

  const int tid = threadIdx.x;
  const int wave = tid >> 6;            // 0..7
  const int lane = tid & 63;
  const int lane15 = lane & 15;
  const int quad = lane >> 4;
  const int g = qtb >> 2;
  const int slot = h * 40 + (g + 1) * (2 * g + (qtb & 3)) + chk;
  const int R0 = qtb * BQ;
  const int NT = 2 * qtb + 2;
  const int kt_beg = chk * CHT;
  const int kt_end = min(kt_beg + CHT, NT);
  const float scale = 0.072168784f;  // 1/sqrt(192)

  // Q A/B-frags: wave's 16 rows (identical layout either operand side).
  const int qrow = R0 + wave * 16 + lane15;
  short8 qf[6];
  const short* qbase = qk + (size_t)qrow * QKVS + h * HD + quad * 8;
#pragma unroll
  for (int kc = 0; kc < 6; ++kc) qf[kc] = *(const short8*)(qbase + kc * 32);
  __builtin_amdgcn_s_waitcnt(WAIT_VM0);
  __builtin_amdgcn_sched_barrier(0);

  // staging descriptors (XOR-swizzled), 512 threads: K 3/thread, V 2/thread
  const short* kb = qk + QKD;
  int lKoff[3]; const short* gK[3];
#pragma unroll
  for (int i = 0; i < 3; ++i) {
    int id = i * 512 + tid;
    int row = id / 24, cX = id - row * 24;
    int ch = cX ^ (row & 7);
    lKoff[i] = id * 8;
    gK[i] = kb + (size_t)row * QKVS + h * HD + ch * 8;
  }
  const short* gV[2]; short* lV[2];
#pragma unroll
  for (int i = 0; i < 2; ++i) {
    int id = i * 512 + tid;
    int row = id >> 3, cX = id & 7;
    int ch = cX ^ (row & 7);
    lV[i] = &Vt[id * 8];
    gV[i] = vtb + (size_t)h * VDIM * SEQ + (size_t)row * SEQ + ch * 8;
  }

  f32x4 oacc[8];
#pragma unroll
  for (int i = 0; i < 8; ++i) oacc[i] = (f32x4)(0.f);
  float lsum_l = 0.f;   // per-lane: partial row sum of q-row (wave*16+lane15)

  // shuffle source lanes for PV A-frag assembly
  const int sA = ((lane >> 4) & 1) * 32 + lane15;
  const int sB = sA + 16;
  const bool hiC = (quad >> 1) != 0;   // this lane's frag uses odd c-block src

  // prologue: stage K(t0)->Ks[0] (3) + V(t0)->Vt (2); vmcnt(2) proves K.
  {
    const size_t t0 = (size_t)kt_beg * BT;
#pragma unroll
    for (int i = 0; i < 3; ++i) gload16(gK[i] + t0 * QKVS, &Ks[0][lKoff[i]]);
#pragma unroll
    for (int i = 0; i < 2; ++i) gload16(gV[i] + t0, lV[i]);
  }
  __builtin_amdgcn_s_waitcnt(WAIT_VM2);
  __builtin_amdgcn_s_barrier();
  __builtin_amdgcn_sched_barrier(0);

  for (int kt = kt_beg; kt < kt_end; ++kt) {
    const int cur = (kt - kt_beg) & 1;
    const bool have = (kt + 1 < kt_end);

    // issue K(t+1) -> Ks[nxt]
    if (have) {
      const size_t tn = (size_t)(kt + 1) * BT;
#pragma unroll
      for (int i = 0; i < 3; ++i) gload16(gK[i] + tn * QKVS, &Ks[cur ^ 1][lKoff[i]]);
    }

    // S = (K Q^T) swapped: sacc[c][r] = S[t = c*16+quad*4+r][q = lane15]
    const short* kcur = &Ks[cur][0];
    f32x4 sacc[4];
    __builtin_amdgcn_s_setprio(1);
#pragma unroll
    for (int c = 0; c < 4; ++c) {
      sacc[c] = (f32x4)(0.f);
      const int row = c * 16 + lane15;
#pragma unroll
      for (int kc = 0; kc < 6; ++kc) {
        int cX = (4 * kc + quad) ^ (lane15 & 7);
        short8 kf = *(const short8*)&kcur[row * 192 + cX * 8];
        sacc[c] = __builtin_amdgcn_mfma_f32_16x16x32_bf16(kf, qf[kc], sacc[c], 0, 0, 0);
      }
    }
    __builtin_amdgcn_s_setprio(0);

    if (kt >= 2 * qtb) {  // diagonal-crossing tiles: mask t > q
#pragma unroll
      for (int c = 0; c < 4; ++c)
#pragma unroll
        for (int r = 0; r < 4; ++r) {
          int tg = kt * BT + c * 16 + quad * 4 + r;
          int qg = R0 + wave * 16 + lane15;
          if (tg > qg) sacc[c][r] = -1e30f;
        }
    }

    // softmax: p = exp(s*scale - MFIX); per-lane scalar row-sum
#pragma unroll
    for (int c = 0; c < 4; ++c)
#pragma unroll
      for (int r = 0; r < 4; ++r) {
        float p = __expf(sacc[c][r] * scale - MFIX);
        lsum_l += p;
        sacc[c][r] = p;
      }

    // pack p -> bf16 pairs per c-block: w[c][0] = (p0,p1), w[c][1] = (p2,p3)
    u32 w[4][2];
#pragma unroll
    for (int c = 0; c < 4; ++c) {
      w[c][0] = packbf(sacc[c][0], sacc[c][1]);
      w[c][1] = packbf(sacc[c][2], sacc[c][3]);
    }

    // assemble PV A-frags: pf0 (t 0..31 : c-src 0/1), pf1 (t 32..63 : c 2/3)
    union { short8 s; u32 u[4]; } pf0, pf1;
    {
      u32 a0 = __shfl((int)w[0][0], sA), b0 = __shfl((int)w[1][0], sA);
      u32 a1 = __shfl((int)w[0][1], sA), b1 = __shfl((int)w[1][1], sA);
      u32 a2 = __shfl((int)w[0][0], sB), b2 = __shfl((int)w[1][0], sB);
      u32 a3 = __shfl((int)w[0][1], sB), b3 = __shfl((int)w[1][1], sB);
      pf0.u[0] = hiC ? b0 : a0; pf0.u[1] = hiC ? b1 : a1;
      pf0.u[2] = hiC ? b2 : a2; pf0.u[3] = hiC ? b3 : a3;
      u32 c0 = __shfl((int)w[2][0], sA), d0 = __shfl((int)w[3][0], sA);
      u32 c1 = __shfl((int)w[2][1], sA), d1 = __shfl((int)w[3][1], sA);
      u32 c2 = __shfl((int)w[2][0], sB), d2 = __shfl((int)w[3][0], sB);
      u32 c3 = __shfl((int)w[2][1], sB), d3 = __shfl((int)w[3][1], sB);
      pf1.u[0] = hiC ? d0 : c0; pf1.u[1] = hiC ? d1 : c1;
      pf1.u[2] = hiC ? d2 : c2; pf1.u[3] = hiC ? d3 : c3;
    }

    // prove V(t): queue [V2,K3] -> vmcnt(3); last iter [V2] -> vmcnt(0)
    if (have) __builtin_amdgcn_s_waitcnt(WAIT_VM3);
    else      __builtin_amdgcn_s_waitcnt(WAIT_VM0);
    __builtin_amdgcn_s_barrier();
    __builtin_amdgcn_sched_barrier(0);

    // PV (single pass, 16 MFMA)
    __builtin_amdgcn_s_setprio(1);
#pragma unroll
    for (int ch = 0; ch < 8; ++ch) {
      const int row = ch * 16 + lane15;
      int cX0 = quad ^ (lane15 & 7);
      int cX1 = (4 + quad) ^ (lane15 & 7);
      short8 vf0 = *(const short8*)&Vt[row * 64 + cX0 * 8];
      short8 vf1 = *(const short8*)&Vt[row * 64 + cX1 * 8];
      oacc[ch] = __builtin_amdgcn_mfma_f32_16x16x32_bf16(pf0.s, vf0, oacc[ch], 0, 0, 0);
      oacc[ch] = __builtin_amdgcn_mfma_f32_16x16x32_bf16(pf1.s, vf1, oacc[ch], 0, 0, 0);
    }
    __builtin_amdgcn_s_setprio(0);

    if (have) {
      // all waves done reading Vt (and Ks[cur]) -> Vt free
      __builtin_amdgcn_s_waitcnt(WAIT_LGKM);
      __builtin_amdgcn_s_barrier();
      const size_t tn = (size_t)(kt + 1) * BT;
#pragma unroll
      for (int i = 0; i < 2; ++i) gload16(gV[i] + tn, lV[i]);
      // prove K(t+1): queue [K3,V2] -> vmcnt(2)
      __builtin_amdgcn_s_waitcnt(WAIT_VM2);
      __builtin_amdgcn_s_barrier();
      __builtin_amdgcn_sched_barrier(0);
    }
  }

  // epilogue: write unnormalized partials ([128][128] per slot)
  short* op = Opart + (size_t)slot * (128 * 128);
#pragma unroll
  for (int ch = 0; ch < 8; ++ch)
#pragma unroll
    for (int r = 0; r < 4; ++r)
      op[(wave * 16 + quad * 4 + r) * 128 + ch * 16 + lane15] = f2bf(oacc[ch][r]);

  // row sums: reduce per-lane partials across quads (same lane15)
  float s = lsum_l;
  s += __shfl_xor(s, 16, 64);
  s += __shfl_xor(s, 32, 64);
  if (quad == 0)
    lpart[(size_t)slot * 128 + wave * 16 + lane15] = s;
}

// ---------------------------------------------------------------------------
// Phase B: sum chunk partials, normalize, write COMPACT aob [2048][2048] bf16.
// ---------------------------------------------------------------------------
__global__ __launch_bounds__(256) void attn_combine(
    const short* __restrict__ Opart, const float* __restrict__ lpart,
    short* __restrict__ aob) {   // compact [SEQ][VD], row stride VD=2048
  const int qt64 = blockIdx.x, h = blockIdx.y;
  const int qtb = qt64 >> 1;
  const int half = qt64 & 1;
  const int g = qtb >> 2;
  const int nact = g + 1;
  const int base = h * 40 + (g + 1) * (2 * g + (qtb & 3));
  const int tid = threadIdx.x;
  const int row = tid >> 2;            // 0..63
  const int cg = (tid & 3) * 32;

  float acc[32];
#pragma unroll
  for (int e = 0; e < 32; ++e) acc[e] = 0.f;
  float lsum = 0.f;

  for (int c = 0; c < nact; ++c) {
    const short* sp = Opart + (size_t)(base + c) * (128 * 128) +
                      (half * 64 + row) * 128 + cg;
    lsum += lpart[(size_t)(base + c) * 128 + half * 64 + row];
#pragma unroll
    for (int gg = 0; gg < 4; ++gg) {
      short8 vv = *(const short8*)(sp + gg * 8);
#pragma unroll
      for (int e = 0; e < 8; ++e) acc[gg * 8 + e] += bf2f((unsigned short)vv[e]);
    }
  }

  float inv = 1.f / lsum;
#pragma unroll
  for (int gg = 0; gg < 4; ++gg) {
    short8 ov;
#pragma unroll
    for (int e = 0; e < 8; ++e) ov[e] = f2bf(acc[gg * 8 + e] * inv);
    *(short8*)(aob + (size_t)(qt64 * 64 + row) * VD + h * 128 + cg + gg * 8) = ov;
  }
}

// ---------------------------------------------------------------------------
// Workspace (bytes), peak 75,497,472 (< proven 79,691,776):
//   [0,        8388608)  xb  -> wo_b (after qkv gemm)
//   [8388608, 41943040)  wqkv -> {vtb@8388608, Opart@16777216 (20,971,520),
//                        lpart@37748736 (327,680)}
//   [41943040,75497472)  qkv bf16 [2048][8192]; AFTER attn_combine, qkv is
//                        dead and compact aob [2048][2048] bf16 (8 MB) lives
//                        at the qkv base.
// ---------------------------------------------------------------------------
extern "C" void kernel_launch(void* const* d_in, const int* in_sizes, int n_in,
                              void* d_out, int out_size, void* d_ws, size_t ws_size,
                              hipStream_t stream) {
  const float* x  = (const float*)d_in[0];
  const float* wq = (const float*)d_in[1];
  const float* wk = (const float*)d_in[2];
  const float* wv = (const float*)d_in[3];
  const float* wo = (const float*)d_in[4];
  const float* fc = (const float*)d_in[5];
  const float* fs = (const float*)d_in[6];

  char* ws8 = (char*)d_ws;
  short* xb    = (short*)(ws8 + 0);
  short* wo_b  = (short*)(ws8 + 0);
  short* wqkv  = (short*)(ws8 + 8388608);
  short* vtb   = (short*)(ws8 + 8388608);
  short* Opart = (short*)(ws8 + 16777216);
  float* lpart = (float*)(ws8 + 37748736);
  short* qkv   = (short*)(ws8 + 41943040);
  short* aob   = qkv;   // compact aob overwrites dead qkv after attn_combine
  float* out   = (float*)d_out;

  const int NX4 = DIM * DIM / 4;
  const int NQKV4 = QKVS * DIM / 4;
  const int ROPE_GRID = (SEQ * NH * 32) / 256;

  // fused input converts (x + wq|wk|wv), one launch
  conv_in<<<(NX4 + NQKV4) / 256, 256, 0, stream>>>(x, wq, wk, wv, xb, wqkv);

  // fused QKV projection: qkv [2048][8192] via 256^2 kernel (m201-layout).
  gemm256_bt<<<dim3((QKVS / 256) * (SEQ / 256)), 512, 0, stream>>>(
      xb, wqkv, qkv, DIM, DIM, DIM, QKVS);
  rope_qk<<<ROPE_GRID, 256, 0, stream>>>(qkv, fc, fs);
  vt_bf16<<<dim3(SEQ / 64, VD / 64), 256, 0, stream>>>(qkv + 2 * QKD, vtb);

  // wo convert (xb dead after qkv gemm)
  bf16_convert<<<(NX4 + 255) / 256, 256, 0, stream>>>(wo, wo_b, NX4);

  // split-T attention: grid (8 xcd, 80 chunks) = 640 blocks, 512 threads
  attn_part<<<dim3(8, 80), 512, 0, stream>>>(qkv, vtb, Opart, lpart);
  attn_combine<<<dim3(SEQ / 64, NH), 256, 0, stream>>>(Opart, lpart, aob);

  // output projection: A = compact aob, lda = VD (contiguous rows)
  gemm_bt<false><<<dim3(DIM / 128, SEQ / 128), 256, 0, stream>>>(
      aob, wo_b, out, DIM, VD, DIM, DIM, 1.0f);
}

// Round 12
// 300.756 us; speedup vs baseline: 1.0869x; 1.0364x over previous
//
#include <hip/hip_runtime.h>
#include <hip/hip_bf16.h>
#include <math.h>

#define NH 16
#define NOPE 128
#define ROPE 64
#define VDIM 128
#define HD 192          // HEAD_DIM
#define SEQ 2048
#define DIM 2048
#define QKD (NH * HD)   // 3072
#define VD  (NH * VDIM) // 2048
#define QKVS 8192       // fused q|k|v row stride (shorts): [q 3072][k 3072][v 2048]

typedef __attribute__((ext_vector_type(8))) short short8;   // 8 bf16 = 4 VGPRs
typedef __attribute__((ext_vector_type(4))) short short4v;
typedef __attribute__((ext_vector_type(4))) float f32x4;
typedef unsigned int u32;

// s_waitcnt immediates (gfx9 encoding: vmcnt[3:0]@0, expcnt@4, lgkmcnt@8, vmcnt[5:4]@14)
#define WAIT_VM8  0x0F78   // vmcnt(8)
#define WAIT_VM6  0x0F76   // vmcnt(6)
#define WAIT_VM4  0x0F74   // vmcnt(4)
#define WAIT_VM3  0x0F73   // vmcnt(3)
#define WAIT_VM2  0x0F72   // vmcnt(2)
#define WAIT_VM0  0x0F70   // vmcnt(0)
#define WAIT_LGKM 0xC07F   // lgkmcnt(0), vmcnt/exp no-wait

static __device__ inline short f2bf(float f) {
  union { float f; unsigned u; } v; v.f = f;
  unsigned r = (v.u + 0x7fffu + ((v.u >> 16) & 1u)) >> 16;
  return (short)r;
}
static __device__ inline u32 packbf(float lo, float hi) {
  return (u32)(unsigned short)f2bf(lo) | ((u32)(unsigned short)f2bf(hi) << 16);
}
static __device__ inline float bf2f(unsigned short u) {
  union { unsigned u; float f; } v; v.u = ((unsigned)u) << 16;
  return v.f;
}

// async global->LDS, 16B/lane. LDS dest = wave-uniform base + lane*16.
static __device__ __forceinline__ void gload16(const short* g, short* l) {
  __builtin_amdgcn_global_load_lds(
      (const __attribute__((address_space(1))) u32*)g,
      (__attribute__((address_space(3))) u32*)l, 16, 0, 0);
}

// ---------------------------------------------------------------------------
// 256x256 bf16 GEMM, C = A * B^T.  Unchanged from R8 (m201 layout+staging).
// ---------------------------------------------------------------------------

#define LSA(pp) (Lsm + (pp) * 65536)
#define LSB(pp) (Lsm + (pp) * 65536 + 32768)

#define RDA(pp, kh, mh) do { \
  const char* p_ = LSA(pp) + abase + (mh) * 8192 + ((kh) ? cx1 : cx0); \
  afr[(mh) * 4 + 0] = *(const short8*)(p_ + 0); \
  afr[(mh) * 4 + 1] = *(const short8*)(p_ + 2048); \
  afr[(mh) * 4 + 2] = *(const short8*)(p_ + 4096); \
  afr[(mh) * 4 + 3] = *(const short8*)(p_ + 6144); \
} while (0)

#define RDB(pp, kh) do { \
  const char* p_ = LSB(pp) + bbase + ((kh) ? cx1 : cx0); \
  bfr[0] = *(const short8*)(p_ + 0); \
  bfr[1] = *(const short8*)(p_ + 2048); \
  bfr[2] = *(const short8*)(p_ + 4096); \
  bfr[3] = *(const short8*)(p_ + 6144); \
} while (0)

#define SGA(kt, c) gload16(srcA[c] + (kt) * 64, (short*)(LSA((kt) & 1) + ((c) * 512 + tid) * 16))
#define SGB(kt, c) gload16(srcB[c] + (kt) * 64, (short*)(LSB((kt) & 1) + ((c) * 512 + tid) * 16))
#define G1S(kt) do { SGA(kt, 0); SGA(kt, 2); SGB(kt, 0); SGB(kt, 1); } while (0)
#define G2S(kt) do { SGA(kt, 1); SGA(kt, 3); SGB(kt, 2); SGB(kt, 3); } while (0)

#define MFMA1(mi, ni) \
  acc[mi][ni] = __builtin_amdgcn_mfma_f32_16x16x32_bf16(afr[mi], bfr[ni], acc[mi][ni], 0, 0, 0)

#define MM(mh) do { \
  MFMA1((mh)*4+0, 0); MFMA1((mh)*4+1, 0); MFMA1((mh)*4+2, 0); MFMA1((mh)*4+3, 0); \
  MFMA1((mh)*4+0, 1); MFMA1((mh)*4+1, 1); MFMA1((mh)*4+2, 1); MFMA1((mh)*4+3, 1); \
  MFMA1((mh)*4+0, 2); MFMA1((mh)*4+1, 2); MFMA1((mh)*4+2, 2); MFMA1((mh)*4+3, 2); \
  MFMA1((mh)*4+0, 3); MFMA1((mh)*4+1, 3); MFMA1((mh)*4+2, 3); MFMA1((mh)*4+3, 3); \
} while (0)

#define GBAR() __builtin_amdgcn_s_barrier()
#define GLGKM0() __builtin_amdgcn_s_waitcnt(WAIT_LGKM)
#define GPRIO1() __builtin_amdgcn_s_setprio(1)
#define GPRIO0() __builtin_amdgcn_s_setprio(0)
#define GNOP ((void)0)

// One K-tile = 4 phases; SP1 staged in P1, SP4 + counted wait in P4.
#define TILE(pp, SP1, SP4, VMW) do { \
  RDA(pp, 0, 0); RDB(pp, 0); SP1; \
  GBAR(); GLGKM0(); GPRIO1(); MM(0); GPRIO0(); GBAR(); \
  RDA(pp, 0, 1); \
  GBAR(); GLGKM0(); GPRIO1(); MM(1); GPRIO0(); GBAR(); \
  RDA(pp, 1, 0); RDB(pp, 1); \
  GBAR(); GLGKM0(); GPRIO1(); MM(0); GPRIO0(); GBAR(); \
  RDA(pp, 1, 1); SP4; \
  GBAR(); GLGKM0(); GPRIO1(); MM(1); GPRIO0(); VMW; GBAR(); \
} while (0)

__global__ __launch_bounds__(512, 2) void gemm256_bt(
    const short* __restrict__ A, const short* __restrict__ B,
    short* __restrict__ C, int K, int lda, int ldb, int ldc) {
  __shared__ __align__(16) char Lsm[131072];

  const int tid = threadIdx.x;
  const int lane = tid & 63;
  const int l15 = lane & 15;
  const int quad = lane >> 4;      // 0..3
  const int wv = tid >> 6;         // 0..7
  const int wr = wv >> 2, wc = wv & 3;

  // 8Mx4N per-XCD partition (R6).
  const int bid = blockIdx.x;
  const int xcd = bid & 7;
  const int idx = bid >> 3;              // 0..31 within XCD
  const int m0 = (idx & 7) * 256;        // 8 M panels
  const int n0 = (xcd * 4 + (idx >> 3)) * 256;  // 4 N panels per XCD

  // staging sources: linear LDS dest + inverse-swizzled global source (R8).
  const int trow = tid >> 3;                               // 0..63
  const int scol = ((tid & 7) * 8) ^ ((trow & 7) * 8);     // shorts
  const short* srcA[4]; const short* srcB[4];
#pragma unroll
  for (int c = 0; c < 4; ++c) {
    srcA[c] = A + (size_t)(m0 + c * 64 + trow) * lda + scol;
    srcB[c] = B + (size_t)(n0 + c * 64 + trow) * ldb + scol;
  }

  // ds_read bases (bytes): row = {wr*128|wc*64} + sub + l15; swizzled col.
  const int abase = (wr * 128 + l15) * 128;
  const int bbase = (wc * 64 + l15) * 128;
  const int cx0 = (quad * 16) ^ ((l15 & 7) * 16);          // kh = 0
  const int cx1 = (64 + quad * 16) ^ ((l15 & 7) * 16);     // kh = 1

  f32x4 acc[8][4];
#pragma unroll
  for (int i = 0; i < 8; ++i)
#pragma unroll
    for (int j = 0; j < 4; ++j) acc[i][j] = (f32x4)(0.f);
  short8 afr[8], bfr[4];

  const int NT = K >> 6;   // even, >= 4

  // prologue: tile0 fully (8) + G1(tile1) (4); vmcnt(4) proves tile0.
  G1S(0); G2S(0); G1S(1);
  __builtin_amdgcn_s_waitcnt(WAIT_VM4);
  GBAR();

  int kt = 0;
  for (; kt + 4 <= NT; kt += 2) {
    TILE(0, G2S(kt + 1), G1S(kt + 2), __builtin_amdgcn_s_waitcnt(WAIT_VM4));
    TILE(1, G2S(kt + 2), G1S(kt + 3), __builtin_amdgcn_s_waitcnt(WAIT_VM4));
  }
  // tail: kt == NT-2. P1 stages G2(NT-1); vmcnt(0) proves NT-1; last tile bare.
  TILE(0, G2S(kt + 1), GNOP, __builtin_amdgcn_s_waitcnt(WAIT_VM0));
  TILE(1, GNOP, GNOP, GNOP);

#pragma unroll
  for (int m = 0; m < 8; ++m) {
    const size_t rb = (size_t)(m0 + wr * 128 + m * 16 + quad * 4) * ldc +
                      n0 + wc * 64 + l15;
#pragma unroll
    for (int n = 0; n < 4; ++n)
#pragma unroll
      for (int r = 0; r < 4; ++r)
        C[rb + (size_t)r * ldc + n * 16] = f2bf(acc[m][n][r]);
  }
}

// ---------------------------------------------------------------------------
// bf16 MFMA GEMM v2 (128^2): output projection (compact-lda A).
// ---------------------------------------------------------------------------
template <bool BF16OUT>
__global__ __launch_bounds__(256) void gemm_bt(
    const short* __restrict__ A, const short* __restrict__ B,
    void* __restrict__ Cv, int K, int lda, int ldb, int ldc, float oscale) {
  __shared__ __align__(16) short Ls[4][2][4096];

  const int tid = threadIdx.x;
  const int lane = tid & 63;
  const int wave = tid >> 6;
  const int wr = wave >> 1, wc = wave & 1;
  const int lane15 = lane & 15, quad = lane >> 4;
  const int m0 = blockIdx.y * 128, n0 = blockIdx.x * 128;

  const short* gA[4]; const short* gB[4];
#pragma unroll
  for (int i = 0; i < 4; ++i) {
    int gidx = i * 64 + lane;
    int r = gidx >> 2, p = gidx & 3;
    int g = (p ^ ((r >> 1) & 3)) * 8;
    gA[i] = A + (size_t)(m0 + wr * 64 + r) * lda + g;
    gB[i] = B + (size_t)(n0 + wc * 64 + r) * ldb + g;
  }

  f32x4 acc[4][4];
#pragma unroll
  for (int i = 0; i < 4; ++i)
#pragma unroll
    for (int j = 0; j < 4; ++j) acc[i][j] = (f32x4)(0.f);

#pragma unroll
  for (int i = 0; i < 4; ++i) gload16(gA[i], &Ls[wave][0][i * 512]);
#pragma unroll
  for (int i = 0; i < 4; ++i) gload16(gB[i], &Ls[wave][0][2048 + i * 512]);

  const int rsw = (lane15 >> 1) & 3;
  for (int k0 = 0; k0 < K; k0 += 32) {
    const int cur = (k0 >> 5) & 1;
    __builtin_amdgcn_s_waitcnt(WAIT_LGKM);
    if (k0 + 32 < K) {
      const int nxt = cur ^ 1;
#pragma unroll
      for (int i = 0; i < 4; ++i) gload16(gA[i] + k0 + 32, &Ls[wave][nxt][i * 512]);
#pragma unroll
      for (int i = 0; i < 4; ++i) gload16(gB[i] + k0 + 32, &Ls[wave][nxt][2048 + i * 512]);
      __builtin_amdgcn_s_waitcnt(WAIT_VM8);
    } else {
      __builtin_amdgcn_s_waitcnt(WAIT_VM0);
    }
    const short* bufp = &Ls[wave][cur][0];
    short8 af[4], bfv[4];
#pragma unroll
    for (int i = 0; i < 4; ++i)
      af[i] = *(const short8*)&bufp[(i * 16 + lane15) * 32 + (quad ^ rsw) * 8];
#pragma unroll
    for (int j = 0; j < 4; ++j)
      bfv[j] = *(const short8*)&bufp[2048 + (j * 16 + lane15) * 32 + (quad ^ rsw) * 8];
#pragma unroll
    for (int i = 0; i < 4; ++i)
#pragma unroll
      for (int j = 0; j < 4; ++j)
        acc[i][j] = __builtin_amdgcn_mfma_f32_16x16x32_bf16(af[i], bfv[j], acc[i][j], 0, 0, 0);
  }

#pragma unroll
  for (int i = 0; i < 4; ++i)
#pragma unroll
    for (int j = 0; j < 4; ++j)
#pragma unroll
      for (int r = 0; r < 4; ++r) {
        size_t idx = (size_t)(m0 + wr * 64 + i * 16 + quad * 4 + r) * ldc +
                     n0 + wc * 64 + j * 16 + lane15;
        if (BF16OUT)
          ((short*)Cv)[idx] = f2bf(acc[i][j][r] * oscale);
        else
          ((float*)Cv)[idx] = acc[i][j][r];
      }
}

// ---------------------------------------------------------------------------
// Fused input converts: x -> xb and wq|wk|wv -> wqkv (one launch).
// ---------------------------------------------------------------------------
__global__ __launch_bounds__(256) void conv_in(
    const float* __restrict__ x, const float* __restrict__ wq,
    const float* __restrict__ wk, const float* __restrict__ wv,
    short* __restrict__ xb, short* __restrict__ wqkv) {
  const int NX4v = DIM * DIM / 4;
  int i = blockIdx.x * 256 + threadIdx.x;
  float4 f; short* dst; int di;
  if (i < NX4v) {
    f = ((const float4*)x)[i]; dst = xb; di = i;
  } else {
    int j = i - NX4v;
    int row = j >> 9;
    if (row < QKD) f = ((const float4*)wq)[j];
    else if (row < 2 * QKD) f = ((const float4*)wk)[j - QKD * (DIM / 4)];
    else f = ((const float4*)wv)[j - 2 * QKD * (DIM / 4)];
    dst = wqkv; di = j;
  }
  short4v o;
  o.x = f2bf(f.x); o.y = f2bf(f.y); o.z = f2bf(f.z); o.w = f2bf(f.w);
  ((short4v*)dst)[di] = o;
}

// ---------------------------------------------------------------------------
// Fused post-QKV kernel: 3 independent tasks, all gated only on gemm256_bt,
// fused into one launch with a block-uniform 3-way branch:
//   blocks [0, 4096):        RoPE in-place on qkv (q+k rope cols)
//   blocks [4096, 5120):     v -> vtb [h][d][t] transpose
//   blocks [5120, 9216):     wo f32 -> wo_b bf16 (xb region, dead after gemm)
// ---------------------------------------------------------------------------
#define ROPE_BLKS 4096
#define VT_BLKS   1024
#define WO_BLKS   4096

__global__ __launch_bounds__(256) void post_qkv(
    short* __restrict__ qkv, const float* __restrict__ cosf,
    const float* __restrict__ sinf, short* __restrict__ vtb,
    const float* __restrict__ wo, short* __restrict__ wo_b) {
  __shared__ short tile[64][74];
  const int b = blockIdx.x;
  const int tid = threadIdx.x;

  if (b < ROPE_BLKS) {
    // ---- RoPE ----
    int idx = b * 256 + tid;
    int j = idx & 31;
    int h = (idx >> 5) & (NH - 1);
    int s = idx >> 9;

    float c = cosf[s * 32 + j];
    float sn = sinf[s * 32 + j];
    size_t rowb = (size_t)s * QKVS + h * HD + NOPE + 2 * j;

    u32* pq = (u32*)(qkv + rowb);
    u32 w = *pq;
    float a = bf2f((unsigned short)(w & 0xffff));
    float bb = bf2f((unsigned short)(w >> 16));
    *pq = packbf(a * c - bb * sn, a * sn + bb * c);

    u32* pk = (u32*)(qkv + rowb + QKD);
    w = *pk;
    a = bf2f((unsigned short)(w & 0xffff));
    bb = bf2f((unsigned short)(w >> 16));
    *pk = packbf(a * c - bb * sn, a * sn + bb * c);
  } else if (b < ROPE_BLKS + VT_BLKS) {
    // ---- v transpose ----
    const int bb = b - ROPE_BLKS;
    const int t0 = (bb & 31) * 64;
    const int c0 = (bb >> 5) * 64;
    const short* vb = qkv + 2 * QKD;
#pragma unroll
    for (int i = 0; i < 16; ++i) {
      int idx = i * 256 + tid;
      int r = idx >> 6, c = idx & 63;
      tile[r][c] = vb[(size_t)(t0 + r) * QKVS + c0 + c];
    }
    __syncthreads();
    const int h = c0 >> 7;
    const int dbase = c0 & 127;
#pragma unroll
    for (int i = 0; i < 16; ++i) {
      int idx = i * 256 + tid;
      int d = idx >> 6, t = idx & 63;
      vtb[(size_t)h * VDIM * SEQ + (size_t)(dbase + d) * SEQ + t0 + t] = tile[t][d];
    }
  } else {
    // ---- wo convert ----
    int i = (b - ROPE_BLKS - VT_BLKS) * 256 + tid;
    float4 f = ((const float4*)wo)[i];
    short4v o;
    o.x = f2bf(f.x); o.y = f2bf(f.y); o.z = f2bf(f.z); o.w = f2bf(f.w);
    ((short4v*)wo_b)[i] = o;
  }
}

// ---------------------------------------------------------------------------
// Split-T flash attention v6 (unchanged from R11): swapped-QK^T in-register
// softmax; K dbuf, V single, 3 barriers/tile, counted vmcnt never 0 mid-loop.
// LDS = 49152 + 16384 = 65536 -> 2 blocks/CU.
// ---------------------------------------------------------------------------
#define BQ 128
#define BT 64
#define CHT 8
#define MFIX 8.0f

__global__ __launch_bounds__(512, 4) void attn_part(
    const short* __restrict__ qk,   // [SEQ][QKVS] bf16
    const short* __restrict__ vtb,  // [NH][VDIM][SEQ] bf16
    short* __restrict__ Opart,      // [640][128][128] bf16
    float* __restrict__ lpart)      // [640][128] fp32
{
  __shared__ __align__(16) short Ks[2][BT * 192];    // 49152 B
  __shared__ __align__(16) short Vt[VDIM * BT];      // 16384 B

  // decode: xcd owns heads {xcd, xcd+8}; heavy qt-blocks first.
  const int xcd = blockIdx.x;          // 0..7
  const int i0 = blockIdx.y;           // 0..79
  const int h = xcd + ((i0 >= 40) ? 8 : 0);
  int jj = (i0 >= 40) ? (i0 - 40) : i0;  // 0..39
  int qtb = 15;
  while (jj >= (qtb >> 2) + 1) { jj -= (qtb >> 2) + 1; --qtb; }
  const int chk = jj;                   // 0..(qtb>>2)

  const int tid = threadIdx.x;
  const int wave = tid >> 6;            // 0..7
  const int lane = tid & 63;
  const int lane15 = lane & 15;
  const int quad = lane >> 4;
  const int g = qtb >> 2;
  const int slot = h * 40 + (g + 1) * (2 * g + (qtb & 3)) + chk;
  const int R0 = qtb * BQ;
  const int NT = 2 * qtb + 2;
  const int kt_beg = chk * CHT;
  const int kt_end = min(kt_beg + CHT, NT);
  const float scale = 0.072168784f;  // 1/sqrt(192)

  // Q frags: wave's 16 rows (identical layout either operand side).
  const int qrow = R0 + wave * 16 + lane15;
  short8 qf[6];
  const short* qbase = qk + (size_t)qrow * QKVS + h * HD + quad * 8;
#pragma unroll
  for (int kc = 0; kc < 6; ++kc) qf[kc] = *(const short8*)(qbase + kc * 32);
  __builtin_amdgcn_s_waitcnt(WAIT_VM0);
  __builtin_amdgcn_sched_barrier(0);

  // staging descriptors (XOR-swizzled), 512 threads: K 3/thread, V 2/thread
  const short* kb = qk + QKD;
  int lKoff[3]; const short* gK[3];
#pragma unroll
  for (int i = 0; i < 3; ++i) {
    int id = i * 512 + tid;
    int row = id / 24, cX = id - row * 24;
    int ch = cX ^ (row & 7);
    lKoff[i] = id * 8;
    gK[i] = kb + (size_t)row * QKVS + h * HD + ch * 8;
  }
  const short* gV[2]; short* lV[2];
#pragma unroll
  for (int i = 0; i < 2; ++i) {
    int id = i * 512 + tid;
    int row = id >> 3, cX = id & 7;
    int ch = cX ^ (row & 7);
    lV[i] = &Vt[id * 8];
    gV[i] = vtb + (size_t)h * VDIM * SEQ + (size_t)row * SEQ + ch * 8;
  }

  f32x4 oacc[8];
#pragma unroll
  for (int i = 0; i < 8; ++i) oacc[i] = (f32x4)(0.f);
  float lsum_l = 0.f;   // per-lane: partial row sum of q-row (wave*16+lane15)

  // shuffle source lanes for PV A-frag assembly
  const int sA = ((lane >> 4) & 1) * 32 + lane15;
  const int sB = sA + 16;
  const bool hiC = (quad >> 1) != 0;   // this lane's frag uses odd c-block src

  // prologue: stage K(t0)->Ks[0] (3) + V(t0)->Vt (2); vmcnt(2) proves K.
  {
    const size_t t0 = (size_t)kt_beg * BT;
#pragma unroll
    for (int i = 0; i < 3; ++i) gload16(gK[i] + t0 * QKVS, &Ks[0][lKoff[i]]);
#pragma unroll
    for (int i = 0; i < 2; ++i) gload16(gV[i] + t0, lV[i]);
  }
  __builtin_amdgcn_s_waitcnt(WAIT_VM2);
  __builtin_amdgcn_s_barrier();
  __builtin_amdgcn_sched_barrier(0);

  for (int kt = kt_beg; kt < kt_end; ++kt) {
    const int cur = (kt - kt_beg) & 1;
    const bool have = (kt + 1 < kt_end);

    // issue K(t+1) -> Ks[nxt]
    if (have) {
      const size_t tn = (size_t)(kt + 1) * BT;
#pragma unroll
      for (int i = 0; i < 3; ++i) gload16(gK[i] + tn * QKVS, &Ks[cur ^ 1][lKoff[i]]);
    }

    // S = (K Q^T) swapped: sacc[c][r] = S[t = c*16+quad*4+r][q = lane15]
    const short* kcur = &Ks[cur][0];
    f32x4 sacc[4];
    __builtin_amdgcn_s_setprio(1);
#pragma unroll
    for (int c = 0; c < 4; ++c) {
      sacc[c] = (f32x4)(0.f);
      const int row = c * 16 + lane15;
#pragma unroll
      for (int kc = 0; kc < 6; ++kc) {
        int cX = (4 * kc + quad) ^ (lane15 & 7);
        short8 kf = *(const short8*)&kcur[row * 192 + cX * 8];
        sacc[c] = __builtin_amdgcn_mfma_f32_16x16x32_bf16(kf, qf[kc], sacc[c], 0, 0, 0);
      }
    }
    __builtin_amdgcn_s_setprio(0);

    if (kt >= 2 * qtb) {  // diagonal-crossing tiles: mask t > q
#pragma unroll
      for (int c = 0; c < 4; ++c)
#pragma unroll
        for (int r = 0; r < 4; ++r) {
          int tg = kt * BT + c * 16 + quad * 4 + r;
          int qg = R0 + wave * 16 + lane15;
          if (tg > qg) sacc[c][r] = -1e30f;
        }
    }

    // softmax: p = exp(s*scale - MFIX); per-lane scalar row-sum
#pragma unroll
    for (int c = 0; c < 4; ++c)
#pragma unroll
      for (int r = 0; r < 4; ++r) {
        float p = __expf(sacc[c][r] * scale - MFIX);
        lsum_l += p;
        sacc[c][r] = p;
      }

    // pack p -> bf16 pairs per c-block: w[c][0] = (p0,p1), w[c][1] = (p2,p3)
    u32 w[4][2];
#pragma unroll
    for (int c = 0; c < 4; ++c) {
      w[c][0] = packbf(sacc[c][0], sacc[c][1]);
      w[c][1] = packbf(sacc[c][2], sacc[c][3]);
    }

    // assemble PV A-frags: pf0 (t 0..31 : c-src 0/1), pf1 (t 32..63 : c 2/3)
    union { short8 s; u32 u[4]; } pf0, pf1;
    {
      u32 a0 = __shfl((int)w[0][0], sA), b0 = __shfl((int)w[1][0], sA);
      u32 a1 = __shfl((int)w[0][1], sA), b1 = __shfl((int)w[1][1], sA);
      u32 a2 = __shfl((int)w[0][0], sB), b2 = __shfl((int)w[1][0], sB);
      u32 a3 = __shfl((int)w[0][1], sB), b3 = __shfl((int)w[1][1], sB);
      pf0.u[0] = hiC ? b0 : a0; pf0.u[1] = hiC ? b1 : a1;
      pf0.u[2] = hiC ? b2 : a2; pf0.u[3] = hiC ? b3 : a3;
      u32 c0 = __shfl((int)w[2][0], sA), d0 = __shfl((int)w[3][0], sA);
      u32 c1 = __shfl((int)w[2][1], sA), d1 = __shfl((int)w[3][1], sA);
      u32 c2 = __shfl((int)w[2][0], sB), d2 = __shfl((int)w[3][0], sB);
      u32 c3 = __shfl((int)w[2][1], sB), d3 = __shfl((int)w[3][1], sB);
      pf1.u[0] = hiC ? d0 : c0; pf1.u[1] = hiC ? d1 : c1;
      pf1.u[2] = hiC ? d2 : c2; pf1.u[3] = hiC ? d3 : c3;
    }

    // prove V(t): queue [V2,K3] -> vmcnt(3); last iter [V2] -> vmcnt(0)
    if (have) __builtin_amdgcn_s_waitcnt(WAIT_VM3);
    else      __builtin_amdgcn_s_waitcnt(WAIT_VM0);
    __builtin_amdgcn_s_barrier();
    __builtin_amdgcn_sched_barrier(0);

    // PV (single pass, 16 MFMA)
    __builtin_amdgcn_s_setprio(1);
#pragma unroll
    for (int ch = 0; ch < 8; ++ch) {
      const int row = ch * 16 + lane15;
      int cX0 = quad ^ (lane15 & 7);
      int cX1 = (4 + quad) ^ (lane15 & 7);
      short8 vf0 = *(const short8*)&Vt[row * 64 + cX0 * 8];
      short8 vf1 = *(const short8*)&Vt[row * 64 + cX1 * 8];
      oacc[ch] = __builtin_amdgcn_mfma_f32_16x16x32_bf16(pf0.s, vf0, oacc[ch], 0, 0, 0);
      oacc[ch] = __builtin_amdgcn_mfma_f32_16x16x32_bf16(pf1.s, vf1, oacc[ch], 0, 0, 0);
    }
    __builtin_amdgcn_s_setprio(0);

    if (have) {
      // all waves done reading Vt (and Ks[cur]) -> Vt free
      __builtin_amdgcn_s_waitcnt(WAIT_LGKM);
      __builtin_amdgcn_s_barrier();
      const size_t tn = (size_t)(kt + 1) * BT;
#pragma unroll
      for (int i = 0; i < 2; ++i) gload16(gV[i] + tn, lV[i]);
      // prove K(t+1): queue [K3,V2] -> vmcnt(2)
      __builtin_amdgcn_s_waitcnt(WAIT_VM2);
      __builtin_amdgcn_s_barrier();
      __builtin_amdgcn_sched_barrier(0);
    }
  }

  // epilogue: write unnormalized partials ([128][128] per slot)
  short* op = Opart + (size_t)slot * (128 * 128);
#pragma unroll
  for (int ch = 0; ch < 8; ++ch)
#pragma unroll
    for (int r = 0; r < 4; ++r)
      op[(wave * 16 + quad * 4 + r) * 128 + ch * 16 + lane15] = f2bf(oacc[ch][r]);

  // row sums: reduce per-lane partials across quads (same lane15)
  float s = lsum_l;
  s += __shfl_xor(s, 16, 64);
  s += __shfl_xor(s, 32, 64);
  if (quad == 0)
    lpart[(size_t)slot * 128 + wave * 16 + lane15] = s;
}

// ---------------------------------------------------------------------------
// Phase B: sum chunk partials, normalize, write COMPACT aob [2048][2048] bf16.
// ---------------------------------------------------------------------------
__global__ __launch_bounds__(256) void attn_combine(
    const short* __restrict__ Opart, const float* __restrict__ lpart,
    short* __restrict__ aob) {   // compact [SEQ][VD], row stride VD=2048
  const int qt64 = blockIdx.x, h = blockIdx.y;
  const int qtb = qt64 >> 1;
  const int half = qt64 & 1;
  const int g = qtb >> 2;
  const int nact = g + 1;
  const int base = h * 40 + (g + 1) * (2 * g + (qtb & 3));
  const int tid = threadIdx.x;
  const int row = tid >> 2;            // 0..63
  const int cg = (tid & 3) * 32;

  float acc[32];
#pragma unroll
  for (int e = 0; e < 32; ++e) acc[e] = 0.f;
  float lsum = 0.f;

  for (int c = 0; c < nact; ++c) {
    const short* sp = Opart + (size_t)(base + c) * (128 * 128) +
                      (half * 64 + row) * 128 + cg;
    lsum += lpart[(size_t)(base + c) * 128 + half * 64 + row];
#pragma unroll
    for (int gg = 0; gg < 4; ++gg) {
      short8 vv = *(const short8*)(sp + gg * 8);
#pragma unroll
      for (int e = 0; e < 8; ++e) acc[gg * 8 + e] += bf2f((unsigned short)vv[e]);
    }
  }

  float inv = 1.f / lsum;
#pragma unroll
  for (int gg = 0; gg < 4; ++gg) {
    short8 ov;
#pragma unroll
    for (int e = 0; e < 8; ++e) ov[e] = f2bf(acc[gg * 8 + e] * inv);
    *(short8*)(aob + (size_t)(qt64 * 64 + row) * VD + h * 128 + cg + gg * 8) = ov;
  }
}

// ---------------------------------------------------------------------------
// Workspace (bytes), peak 75,497,472 (< proven 79,691,776):
//   [0,        8388608)  xb  -> wo_b (after qkv gemm)
//   [8388608, 41943040)  wqkv -> {vtb@8388608, Opart@16777216 (20,971,520),
//                        lpart@37748736 (327,680)}
//   [41943040,75497472)  qkv bf16 [2048][8192]; AFTER attn_combine, qkv is
//                        dead and compact aob [2048][2048] bf16 (8 MB) lives
//                        at the qkv base.
// ---------------------------------------------------------------------------
extern "C" void kernel_launch(void* const* d_in, const int* in_sizes, int n_in,
                              void* d_out, int out_size, void* d_ws, size_t ws_size,
                              hipStream_t stream) {
  const float* x  = (const float*)d_in[0];
  const float* wq = (const float*)d_in[1];
  const float* wk = (const float*)d_in[2];
  const float* wv = (const float*)d_in[3];
  const float* wo = (const float*)d_in[4];
  const float* fc = (const float*)d_in[5];
  const float* fs = (const float*)d_in[6];

  char* ws8 = (char*)d_ws;
  short* xb    = (short*)(ws8 + 0);
  short* wo_b  = (short*)(ws8 + 0);
  short* wqkv  = (short*)(ws8 + 8388608);
  short* vtb   = (short*)(ws8 + 8388608);
  short* Opart = (short*)(ws8 + 16777216);
  float* lpart = (float*)(ws8 + 37748736);
  short* qkv   = (short*)(ws8 + 41943040);
  short* aob   = qkv;   // compact aob overwrites dead qkv after attn_combine
  float* out   = (float*)d_out;

  const int NX4 = DIM * DIM / 4;
  const int NQKV4 = QKVS * DIM / 4;

  // fused input converts (x + wq|wk|wv), one launch
  conv_in<<<(NX4 + NQKV4) / 256, 256, 0, stream>>>(x, wq, wk, wv, xb, wqkv);

  // fused QKV projection: qkv [2048][8192] via 256^2 kernel (m201-layout).
  gemm256_bt<<<dim3((QKVS / 256) * (SEQ / 256)), 512, 0, stream>>>(
      xb, wqkv, qkv, DIM, DIM, DIM, QKVS);

  // fused post-QKV: RoPE + v-transpose + wo convert (one launch, 3 branches)
  post_qkv<<<ROPE_BLKS + VT_BLKS + WO_BLKS, 256, 0, stream>>>(
      qkv, fc, fs, vtb, wo, wo_b);

  // split-T attention: grid (8 xcd, 80 chunks) = 640 blocks, 512 threads
  attn_part<<<dim3(8, 80), 512, 0, stream>>>(qkv, vtb, Opart, lpart);
  attn_combine<<<dim3(SEQ / 64, NH), 256, 0, stream>>>(Opart, lpart, aob);

  // output projection: A = compact aob, lda = VD (contiguous rows)
  gemm_bt<false><<<dim3(DIM / 128, SEQ / 128), 256, 0, stream>>>(
      aob, wo_b, out, DIM, VD, DIM, DIM, 1.0f);
}

// Round 13
// 296.555 us; speedup vs baseline: 1.1023x; 1.0142x over previous
//
#include <hip/hip_runtime.h>
#include <hip/hip_bf16.h>
#include <math.h>

#define NH 16
#define NOPE 128
#define ROPE 64
#define VDIM 128
#define HD 192          // HEAD_DIM
#define SEQ 2048
#define DIM 2048
#define QKD (NH * HD)   // 3072
#define VD  (NH * VDIM) // 2048
#define QKVS 8192       // fused q|k|v row stride (shorts): [q 3072][k 3072][v 2048]

typedef __attribute__((ext_vector_type(8))) short short8;   // 8 bf16 = 4 VGPRs
typedef __attribute__((ext_vector_type(4))) short short4v;
typedef __attribute__((ext_vector_type(4))) float f32x4;
typedef unsigned int u32;

// s_waitcnt immediates (gfx9 encoding: vmcnt[3:0]@0, expcnt@4, lgkmcnt@8, vmcnt[5:4]@14)
#define WAIT_VM8  0x0F78   // vmcnt(8)
#define WAIT_VM6  0x0F76   // vmcnt(6)
#define WAIT_VM4  0x0F74   // vmcnt(4)
#define WAIT_VM3  0x0F73   // vmcnt(3)
#define WAIT_VM2  0x0F72   // vmcnt(2)
#define WAIT_VM0  0x0F70   // vmcnt(0)
#define WAIT_LGKM 0xC07F   // lgkmcnt(0), vmcnt/exp no-wait

static __device__ inline short f2bf(float f) {
  union { float f; unsigned u; } v; v.f = f;
  unsigned r = (v.u + 0x7fffu + ((v.u >> 16) & 1u)) >> 16;
  return (short)r;
}
static __device__ inline u32 packbf(float lo, float hi) {
  return (u32)(unsigned short)f2bf(lo) | ((u32)(unsigned short)f2bf(hi) << 16);
}
static __device__ inline float bf2f(unsigned short u) {
  union { unsigned u; float f; } v; v.u = ((unsigned)u) << 16;
  return v.f;
}

// async global->LDS, 16B/lane. LDS dest = wave-uniform base + lane*16.
static __device__ __forceinline__ void gload16(const short* g, short* l) {
  __builtin_amdgcn_global_load_lds(
      (const __attribute__((address_space(1))) u32*)g,
      (__attribute__((address_space(3))) u32*)l, 16, 0, 0);
}

// ---------------------------------------------------------------------------
// 256x256 bf16 GEMM, C = A * B^T.  Unchanged from R8 (m201 layout+staging).
// ---------------------------------------------------------------------------

#define LSA(pp) (Lsm + (pp) * 65536)
#define LSB(pp) (Lsm + (pp) * 65536 + 32768)

#define RDA(pp, kh, mh) do { \
  const char* p_ = LSA(pp) + abase + (mh) * 8192 + ((kh) ? cx1 : cx0); \
  afr[(mh) * 4 + 0] = *(const short8*)(p_ + 0); \
  afr[(mh) * 4 + 1] = *(const short8*)(p_ + 2048); \
  afr[(mh) * 4 + 2] = *(const short8*)(p_ + 4096); \
  afr[(mh) * 4 + 3] = *(const short8*)(p_ + 6144); \
} while (0)

#define RDB(pp, kh) do { \
  const char* p_ = LSB(pp) + bbase + ((kh) ? cx1 : cx0); \
  bfr[0] = *(const short8*)(p_ + 0); \
  bfr[1] = *(const short8*)(p_ + 2048); \
  bfr[2] = *(const short8*)(p_ + 4096); \
  bfr[3] = *(const short8*)(p_ + 6144); \
} while (0)

#define SGA(kt, c) gload16(srcA[c] + (kt) * 64, (short*)(LSA((kt) & 1) + ((c) * 512 + tid) * 16))
#define SGB(kt, c) gload16(srcB[c] + (kt) * 64, (short*)(LSB((kt) & 1) + ((c) * 512 + tid) * 16))
#define G1S(kt) do { SGA(kt, 0); SGA(kt, 2); SGB(kt, 0); SGB(kt, 1); } while (0)
#define G2S(kt) do { SGA(kt, 1); SGA(kt, 3); SGB(kt, 2); SGB(kt, 3); } while (0)

#define MFMA1(mi, ni) \
  acc[mi][ni] = __builtin_amdgcn_mfma_f32_16x16x32_bf16(afr[mi], bfr[ni], acc[mi][ni], 0, 0, 0)

#define MM(mh) do { \
  MFMA1((mh)*4+0, 0); MFMA1((mh)*4+1, 0); MFMA1((mh)*4+2, 0); MFMA1((mh)*4+3, 0); \
  MFMA1((mh)*4+0, 1); MFMA1((mh)*4+1, 1); MFMA1((mh)*4+2, 1); MFMA1((mh)*4+3, 1); \
  MFMA1((mh)*4+0, 2); MFMA1((mh)*4+1, 2); MFMA1((mh)*4+2, 2); MFMA1((mh)*4+3, 2); \
  MFMA1((mh)*4+0, 3); MFMA1((mh)*4+1, 3); MFMA1((mh)*4+2, 3); MFMA1((mh)*4+3, 3); \
} while (0)

#define GBAR() __builtin_amdgcn_s_barrier()
#define GLGKM0() __builtin_amdgcn_s_waitcnt(WAIT_LGKM)
#define GPRIO1() __builtin_amdgcn_s_setprio(1)
#define GPRIO0() __builtin_amdgcn_s_setprio(0)
#define GNOP ((void)0)

// One K-tile = 4 phases; SP1 staged in P1, SP4 + counted wait in P4.
#define TILE(pp, SP1, SP4, VMW) do { \
  RDA(pp, 0, 0); RDB(pp, 0); SP1; \
  GBAR(); GLGKM0(); GPRIO1(); MM(0); GPRIO0(); GBAR(); \
  RDA(pp, 0, 1); \
  GBAR(); GLGKM0(); GPRIO1(); MM(1); GPRIO0(); GBAR(); \
  RDA(pp, 1, 0); RDB(pp, 1); \
  GBAR(); GLGKM0(); GPRIO1(); MM(0); GPRIO0(); GBAR(); \
  RDA(pp, 1, 1); SP4; \
  GBAR(); GLGKM0(); GPRIO1(); MM(1); GPRIO0(); VMW; GBAR(); \
} while (0)

__global__ __launch_bounds__(512, 2) void gemm256_bt(
    const short* __restrict__ A, const short* __restrict__ B,
    short* __restrict__ C, int K, int lda, int ldb, int ldc) {
  __shared__ __align__(16) char Lsm[131072];

  const int tid = threadIdx.x;
  const int lane = tid & 63;
  const int l15 = lane & 15;
  const int quad = lane >> 4;      // 0..3
  const int wv = tid >> 6;         // 0..7
  const int wr = wv >> 2, wc = wv & 3;

  // 8Mx4N per-XCD partition (R6).
  const int bid = blockIdx.x;
  const int xcd = bid & 7;
  const int idx = bid >> 3;              // 0..31 within XCD
  const int m0 = (idx & 7) * 256;        // 8 M panels
  const int n0 = (xcd * 4 + (idx >> 3)) * 256;  // 4 N panels per XCD

  // staging sources: linear LDS dest + inverse-swizzled global source (R8).
  const int trow = tid >> 3;                               // 0..63
  const int scol = ((tid & 7) * 8) ^ ((trow & 7) * 8);     // shorts
  const short* srcA[4]; const short* srcB[4];
#pragma unroll
  for (int c = 0; c < 4; ++c) {
    srcA[c] = A + (size_t)(m0 + c * 64 + trow) * lda + scol;
    srcB[c] = B + (size_t)(n0 + c * 64 + trow) * ldb + scol;
  }

  // ds_read bases (bytes): row = {wr*128|wc*64} + sub + l15; swizzled col.
  const int abase = (wr * 128 + l15) * 128;
  const int bbase = (wc * 64 + l15) * 128;
  const int cx0 = (quad * 16) ^ ((l15 & 7) * 16);          // kh = 0
  const int cx1 = (64 + quad * 16) ^ ((l15 & 7) * 16);     // kh = 1

  f32x4 acc[8][4];
#pragma unroll
  for (int i = 0; i < 8; ++i)
#pragma unroll
    for (int j = 0; j < 4; ++j) acc[i][j] = (f32x4)(0.f);
  short8 afr[8], bfr[4];

  const int NT = K >> 6;   // even, >= 4

  // prologue: tile0 fully (8) + G1(tile1) (4); vmcnt(4) proves tile0.
  G1S(0); G2S(0); G1S(1);
  __builtin_amdgcn_s_waitcnt(WAIT_VM4);
  GBAR();

  int kt = 0;
  for (; kt + 4 <= NT; kt += 2) {
    TILE(0, G2S(kt + 1), G1S(kt + 2), __builtin_amdgcn_s_waitcnt(WAIT_VM4));
    TILE(1, G2S(kt + 2), G1S(kt + 3), __builtin_amdgcn_s_waitcnt(WAIT_VM4));
  }
  // tail: kt == NT-2. P1 stages G2(NT-1); vmcnt(0) proves NT-1; last tile bare.
  TILE(0, G2S(kt + 1), GNOP, __builtin_amdgcn_s_waitcnt(WAIT_VM0));
  TILE(1, GNOP, GNOP, GNOP);

#pragma unroll
  for (int m = 0; m < 8; ++m) {
    const size_t rb = (size_t)(m0 + wr * 128 + m * 16 + quad * 4) * ldc +
                      n0 + wc * 64 + l15;
#pragma unroll
    for (int n = 0; n < 4; ++n)
#pragma unroll
      for (int r = 0; r < 4; ++r)
        C[rb + (size_t)r * ldc + n * 16] = f2bf(acc[m][n][r]);
  }
}

// ---------------------------------------------------------------------------
// 128x128 bf16 GEMM v3 (output projection): BK=64, block-cooperative FULL-
// CACHE-LINE staging (R8 pattern: linear LDS dest + inverse-swizzled source +
// swizzled ds_read), dbuf 64 KB -> 2 blocks/CU. Per tile: stage(T+1) ->
// vmcnt(8) (proves T, cover = one full tile) -> barrier -> 32 MFMA ->
// lgkm+barrier. Counted vmcnt never 0 mid-loop; 2 barriers/tile.
// XCD partition 4Mx8N (footprint 6 MB/XCD).
// ---------------------------------------------------------------------------
template <bool BF16OUT>
__global__ __launch_bounds__(256, 2) void gemm128_bt(
    const short* __restrict__ A, const short* __restrict__ B,
    void* __restrict__ Cv, int K, int lda, int ldb, int ldc, float oscale) {
  __shared__ __align__(16) short Ls[2][2][8192];  // [buf][A|B][128 rows][64]

  const int tid = threadIdx.x;
  const int lane = tid & 63;
  const int l15 = lane & 15;
  const int quad = lane >> 4;
  const int wave = tid >> 6;            // 4 waves, 2M x 2N
  const int wr = wave >> 1, wc = wave & 1;

  // bijective XCD partition: xcd owns 4 M-panels x 8 N-panels (16x16 grid).
  const int bid = blockIdx.x;
  const int xcd = bid & 7;
  const int ii = bid >> 3;                       // 0..31
  const int m0 = (((xcd & 3) << 2) + (ii & 3)) * 128;
  const int n0 = (((xcd >> 2) << 3) + (ii >> 2)) * 128;

  // staging: chunk c covers rows c*32 + (tid>>3); source col chunk pre-XORed.
  // A wave-round = 8 consecutive rows x 8 permuted 16B chunks = full lines.
  const int trow = tid >> 3;                     // 0..31
  const int scol = (((tid & 7) ^ (trow & 7))) * 8;
  const short* srcA[4]; const short* srcB[4];
#pragma unroll
  for (int c = 0; c < 4; ++c) {
    srcA[c] = A + (size_t)(m0 + c * 32 + trow) * lda + scol;
    srcB[c] = B + (size_t)(n0 + c * 32 + trow) * ldb + scol;
  }

  f32x4 acc[4][4];
#pragma unroll
  for (int i = 0; i < 4; ++i)
#pragma unroll
    for (int j = 0; j < 4; ++j) acc[i][j] = (f32x4)(0.f);

  const int NT = K >> 6;

  // prologue: stage tile0 -> buf0 (8 gloads)
#pragma unroll
  for (int c = 0; c < 4; ++c) gload16(srcA[c], &Ls[0][0][(c * 256 + tid) * 8]);
#pragma unroll
  for (int c = 0; c < 4; ++c) gload16(srcB[c], &Ls[0][1][(c * 256 + tid) * 8]);

  for (int kt = 0; kt < NT; ++kt) {
    const int cur = kt & 1;
    if (kt + 1 < NT) {
      // stage T+1 -> other buffer (its readers finished at last iter's barrier)
      const int kc = (kt + 1) * 64;
#pragma unroll
      for (int c = 0; c < 4; ++c)
        gload16(srcA[c] + kc, &Ls[cur ^ 1][0][(c * 256 + tid) * 8]);
#pragma unroll
      for (int c = 0; c < 4; ++c)
        gload16(srcB[c] + kc, &Ls[cur ^ 1][1][(c * 256 + tid) * 8]);
      // queue = [T 8 (issued last iter), T+1 8] -> vmcnt(8) proves T
      __builtin_amdgcn_s_waitcnt(WAIT_VM8);
    } else {
      __builtin_amdgcn_s_waitcnt(WAIT_VM0);
    }
    __builtin_amdgcn_s_barrier();

    const short* la = &Ls[cur][0][0];
    const short* lb = &Ls[cur][1][0];
#pragma unroll
    for (int kh = 0; kh < 2; ++kh) {
      short8 af[4], bfv[4];
#pragma unroll
      for (int m = 0; m < 4; ++m) {
        int row = wr * 64 + m * 16 + l15;
        int ch = (kh * 4 + quad) ^ (l15 & 7);
        af[m] = *(const short8*)&la[row * 64 + ch * 8];
      }
#pragma unroll
      for (int n = 0; n < 4; ++n) {
        int row = wc * 64 + n * 16 + l15;
        int ch = (kh * 4 + quad) ^ (l15 & 7);
        bfv[n] = *(const short8*)&lb[row * 64 + ch * 8];
      }
      __builtin_amdgcn_s_setprio(1);
#pragma unroll
      for (int m = 0; m < 4; ++m)
#pragma unroll
        for (int n = 0; n < 4; ++n)
          acc[m][n] = __builtin_amdgcn_mfma_f32_16x16x32_bf16(af[m], bfv[n], acc[m][n], 0, 0, 0);
      __builtin_amdgcn_s_setprio(0);
    }
    __builtin_amdgcn_s_waitcnt(WAIT_LGKM);
    __builtin_amdgcn_s_barrier();
  }

#pragma unroll
  for (int i = 0; i < 4; ++i)
#pragma unroll
    for (int j = 0; j < 4; ++j)
#pragma unroll
      for (int r = 0; r < 4; ++r) {
        size_t idx = (size_t)(m0 + wr * 64 + i * 16 + quad * 4 + r) * ldc +
                     n0 + wc * 64 + j * 16 + l15;
        if (BF16OUT)
          ((short*)Cv)[idx] = f2bf(acc[i][j][r] * oscale);
        else
          ((float*)Cv)[idx] = acc[i][j][r];
      }
}

// ---------------------------------------------------------------------------
// Fused input converts: x -> xb and wq|wk|wv -> wqkv (one launch).
// ---------------------------------------------------------------------------
__global__ __launch_bounds__(256) void conv_in(
    const float* __restrict__ x, const float* __restrict__ wq,
    const float* __restrict__ wk, const float* __restrict__ wv,
    short* __restrict__ xb, short* __restrict__ wqkv) {
  const int NX4v = DIM * DIM / 4;
  int i = blockIdx.x * 256 + threadIdx.x;
  float4 f; short* dst; int di;
  if (i < NX4v) {
    f = ((const float4*)x)[i]; dst = xb; di = i;
  } else {
    int j = i - NX4v;
    int row = j >> 9;
    if (row < QKD) f = ((const float4*)wq)[j];
    else if (row < 2 * QKD) f = ((const float4*)wk)[j - QKD * (DIM / 4)];
    else f = ((const float4*)wv)[j - 2 * QKD * (DIM / 4)];
    dst = wqkv; di = j;
  }
  short4v o;
  o.x = f2bf(f.x); o.y = f2bf(f.y); o.z = f2bf(f.z); o.w = f2bf(f.w);
  ((short4v*)dst)[di] = o;
}

// ---------------------------------------------------------------------------
// Fused post-QKV kernel: RoPE | v-transpose | wo-convert (block-range branch).
// ---------------------------------------------------------------------------
#define ROPE_BLKS 4096
#define VT_BLKS   1024
#define WO_BLKS   4096

__global__ __launch_bounds__(256) void post_qkv(
    short* __restrict__ qkv, const float* __restrict__ cosf,
    const float* __restrict__ sinf, short* __restrict__ vtb,
    const float* __restrict__ wo, short* __restrict__ wo_b) {
  __shared__ short tile[64][74];
  const int b = blockIdx.x;
  const int tid = threadIdx.x;

  if (b < ROPE_BLKS) {
    // ---- RoPE ----
    int idx = b * 256 + tid;
    int j = idx & 31;
    int h = (idx >> 5) & (NH - 1);
    int s = idx >> 9;

    float c = cosf[s * 32 + j];
    float sn = sinf[s * 32 + j];
    size_t rowb = (size_t)s * QKVS + h * HD + NOPE + 2 * j;

    u32* pq = (u32*)(qkv + rowb);
    u32 w = *pq;
    float a = bf2f((unsigned short)(w & 0xffff));
    float bb = bf2f((unsigned short)(w >> 16));
    *pq = packbf(a * c - bb * sn, a * sn + bb * c);

    u32* pk = (u32*)(qkv + rowb + QKD);
    w = *pk;
    a = bf2f((unsigned short)(w & 0xffff));
    bb = bf2f((unsigned short)(w >> 16));
    *pk = packbf(a * c - bb * sn, a * sn + bb * c);
  } else if (b < ROPE_BLKS + VT_BLKS) {
    // ---- v transpose ----
    const int bb = b - ROPE_BLKS;
    const int t0 = (bb & 31) * 64;
    const int c0 = (bb >> 5) * 64;
    const short* vb = qkv + 2 * QKD;
#pragma unroll
    for (int i = 0; i < 16; ++i) {
      int idx = i * 256 + tid;
      int r = idx >> 6, c = idx & 63;
      tile[r][c] = vb[(size_t)(t0 + r) * QKVS + c0 + c];
    }
    __syncthreads();
    const int h = c0 >> 7;
    const int dbase = c0 & 127;
#pragma unroll
    for (int i = 0; i < 16; ++i) {
      int idx = i * 256 + tid;
      int d = idx >> 6, t = idx & 63;
      vtb[(size_t)h * VDIM * SEQ + (size_t)(dbase + d) * SEQ + t0 + t] = tile[t][d];
    }
  } else {
    // ---- wo convert ----
    int i = (b - ROPE_BLKS - VT_BLKS) * 256 + tid;
    float4 f = ((const float4*)wo)[i];
    short4v o;
    o.x = f2bf(f.x); o.y = f2bf(f.y); o.z = f2bf(f.z); o.w = f2bf(f.w);
    ((short4v*)wo_b)[i] = o;
  }
}

// ---------------------------------------------------------------------------
// Split-T flash attention v6 (unchanged from R11): swapped-QK^T in-register
// softmax; K dbuf, V single, 3 barriers/tile, counted vmcnt never 0 mid-loop.
// LDS = 49152 + 16384 = 65536 -> 2 blocks/CU.
// ---------------------------------------------------------------------------
#define BQ 128
#define BT 64
#define CHT 8
#define MFIX 8.0f

__global__ __launch_bounds__(512, 4) void attn_part(
    const short* __restrict__ qk,   // [SEQ][QKVS] bf16
    const short* __restrict__ vtb,  // [NH][VDIM][SEQ] bf16
    short* __restrict__ Opart,      // [640][128][128] bf16
    float* __restrict__ lpart)      // [640][128] fp32
{
  __shared__ __align__(16) short Ks[2][BT * 192];    // 49152 B
  __shared__ __align__(16) short Vt[VDIM * BT];      // 16384 B

  // decode: xcd owns heads {xcd, xcd+8}; heavy qt-blocks first.
  const int xcd = blockIdx.x;          // 0..7
  const int i0 = blockIdx.y;           // 0..79
  const int h = xcd + ((i0 >= 40) ? 8 : 0);
  int jj = (i0 >= 40) ? (i0 - 40) : i0;  // 0..39
  int qtb = 15;
  while (jj >= (qtb >> 2) + 1) { jj -= (qtb >> 2) + 1; --qtb; }
  const int chk = jj;                   // 0..(qtb>>2)

  const int tid = threadIdx.x;
  const int wave = tid >> 6;            // 0..7
  const int lane = tid & 63;
  const int lane15 = lane & 15;
  const int quad = lane >> 4;
  const int g = qtb >> 2;
  const int slot = h * 40 + (g + 1) * (2 * g + (qtb & 3)) + chk;
  const int R0 = qtb * BQ;
  const int NT = 2 * qtb + 2;
  const int kt_beg = chk * CHT;
  const int kt_end = min(kt_beg + CHT, NT);
  const float scale = 0.072168784f;  // 1/sqrt(192)

  // Q frags: wave's 16 rows (identical layout either operand side).
  const int qrow = R0 + wave * 16 + lane15;
  short8 qf[6];
  const short* qbase = qk + (size_t)qrow * QKVS + h * HD + quad * 8;
#pragma unroll
  for (int kc = 0; kc < 6; ++kc) qf[kc] = *(const short8*)(qbase + kc * 32);
  __builtin_amdgcn_s_waitcnt(WAIT_VM0);
  __builtin_amdgcn_sched_barrier(0);

  // staging descriptors (XOR-swizzled), 512 threads: K 3/thread, V 2/thread
  const short* kb = qk + QKD;
  int lKoff[3]; const short* gK[3];
#pragma unroll
  for (int i = 0; i < 3; ++i) {
    int id = i * 512 + tid;
    int row = id / 24, cX = id - row * 24;
    int ch = cX ^ (row & 7);
    lKoff[i] = id * 8;
    gK[i] = kb + (size_t)row * QKVS + h * HD + ch * 8;
  }
  const short* gV[2]; short* lV[2];
#pragma unroll
  for (int i = 0; i < 2; ++i) {
    int id = i * 512 + tid;
    int row = id >> 3, cX = id & 7;
    int ch = cX ^ (row & 7);
    lV[i] = &Vt[id * 8];
    gV[i] = vtb + (size_t)h * VDIM * SEQ + (size_t)row * SEQ + ch * 8;
  }

  f32x4 oacc[8];
#pragma unroll
  for (int i = 0; i < 8; ++i) oacc[i] = (f32x4)(0.f);
  float lsum_l = 0.f;   // per-lane: partial row sum of q-row (wave*16+lane15)

  // shuffle source lanes for PV A-frag assembly
  const int sA = ((lane >> 4) & 1) * 32 + lane15;
  const int sB = sA + 16;
  const bool hiC = (quad >> 1) != 0;   // this lane's frag uses odd c-block src

  // prologue: stage K(t0)->Ks[0] (3) + V(t0)->Vt (2); vmcnt(2) proves K.
  {
    const size_t t0 = (size_t)kt_beg * BT;
#pragma unroll
    for (int i = 0; i < 3; ++i) gload16(gK[i] + t0 * QKVS, &Ks[0][lKoff[i]]);
#pragma unroll
    for (int i = 0; i < 2; ++i) gload16(gV[i] + t0, lV[i]);
  }
  __builtin_amdgcn_s_waitcnt(WAIT_VM2);
  __builtin_amdgcn_s_barrier();
  __builtin_amdgcn_sched_barrier(0);

  for (int kt = kt_beg; kt < kt_end; ++kt) {
    const int cur = (kt - kt_beg) & 1;
    const bool have = (kt + 1 < kt_end);

    // issue K(t+1) -> Ks[nxt]
    if (have) {
      const size_t tn = (size_t)(kt + 1) * BT;
#pragma unroll
      for (int i = 0; i < 3; ++i) gload16(gK[i] + tn * QKVS, &Ks[cur ^ 1][lKoff[i]]);
    }

    // S = (K Q^T) swapped: sacc[c][r] = S[t = c*16+quad*4+r][q = lane15]
    const short* kcur = &Ks[cur][0];
    f32x4 sacc[4];
    __builtin_amdgcn_s_setprio(1);
#pragma unroll
    for (int c = 0; c < 4; ++c) {
      sacc[c] = (f32x4)(0.f);
      const int row = c * 16 + lane15;
#pragma unroll
      for (int kc = 0; kc < 6; ++kc) {
        int cX = (4 * kc + quad) ^ (lane15 & 7);
        short8 kf = *(const short8*)&kcur[row * 192 + cX * 8];
        sacc[c] = __builtin_amdgcn_mfma_f32_16x16x32_bf16(kf, qf[kc], sacc[c], 0, 0, 0);
      }
    }
    __builtin_amdgcn_s_setprio(0);

    if (kt >= 2 * qtb) {  // diagonal-crossing tiles: mask t > q
#pragma unroll
      for (int c = 0; c < 4; ++c)
#pragma unroll
        for (int r = 0; r < 4; ++r) {
          int tg = kt * BT + c * 16 + quad * 4 + r;
          int qg = R0 + wave * 16 + lane15;
          if (tg > qg) sacc[c][r] = -1e30f;
        }
    }

    // softmax: p = exp(s*scale - MFIX); per-lane scalar row-sum
#pragma unroll
    for (int c = 0; c < 4; ++c)
#pragma unroll
      for (int r = 0; r < 4; ++r) {
        float p = __expf(sacc[c][r] * scale - MFIX);
        lsum_l += p;
        sacc[c][r] = p;
      }

    // pack p -> bf16 pairs per c-block: w[c][0] = (p0,p1), w[c][1] = (p2,p3)
    u32 w[4][2];
#pragma unroll
    for (int c = 0; c < 4; ++c) {
      w[c][0] = packbf(sacc[c][0], sacc[c][1]);
      w[c][1] = packbf(sacc[c][2], sacc[c][3]);
    }

    // assemble PV A-frags: pf0 (t 0..31 : c-src 0/1), pf1 (t 32..63 : c 2/3)
    union { short8 s; u32 u[4]; } pf0, pf1;
    {
      u32 a0 = __shfl((int)w[0][0], sA), b0 = __shfl((int)w[1][0], sA);
      u32 a1 = __shfl((int)w[0][1], sA), b1 = __shfl((int)w[1][1], sA);
      u32 a2 = __shfl((int)w[0][0], sB), b2 = __shfl((int)w[1][0], sB);
      u32 a3 = __shfl((int)w[0][1], sB), b3 = __shfl((int)w[1][1], sB);
      pf0.u[0] = hiC ? b0 : a0; pf0.u[1] = hiC ? b1 : a1;
      pf0.u[2] = hiC ? b2 : a2; pf0.u[3] = hiC ? b3 : a3;
      u32 c0 = __shfl((int)w[2][0], sA), d0 = __shfl((int)w[3][0], sA);
      u32 c1 = __shfl((int)w[2][1], sA), d1 = __shfl((int)w[3][1], sA);
      u32 c2 = __shfl((int)w[2][0], sB), d2 = __shfl((int)w[3][0], sB);
      u32 c3 = __shfl((int)w[2][1], sB), d3 = __shfl((int)w[3][1], sB);
      pf1.u[0] = hiC ? d0 : c0; pf1.u[1] = hiC ? d1 : c1;
      pf1.u[2] = hiC ? d2 : c2; pf1.u[3] = hiC ? d3 : c3;
    }

    // prove V(t): queue [V2,K3] -> vmcnt(3); last iter [V2] -> vmcnt(0)
    if (have) __builtin_amdgcn_s_waitcnt(WAIT_VM3);
    else      __builtin_amdgcn_s_waitcnt(WAIT_VM0);
    __builtin_amdgcn_s_barrier();
    __builtin_amdgcn_sched_barrier(0);

    // PV (single pass, 16 MFMA)
    __builtin_amdgcn_s_setprio(1);
#pragma unroll
    for (int ch = 0; ch < 8; ++ch) {
      const int row = ch * 16 + lane15;
      int cX0 = quad ^ (lane15 & 7);
      int cX1 = (4 + quad) ^ (lane15 & 7);
      short8 vf0 = *(const short8*)&Vt[row * 64 + cX0 * 8];
      short8 vf1 = *(const short8*)&Vt[row * 64 + cX1 * 8];
      oacc[ch] = __builtin_amdgcn_mfma_f32_16x16x32_bf16(pf0.s, vf0, oacc[ch], 0, 0, 0);
      oacc[ch] = __builtin_amdgcn_mfma_f32_16x16x32_bf16(pf1.s, vf1, oacc[ch], 0, 0, 0);
    }
    __builtin_amdgcn_s_setprio(0);

    if (have) {
      // all waves done reading Vt (and Ks[cur]) -> Vt free
      __builtin_amdgcn_s_waitcnt(WAIT_LGKM);
      __builtin_amdgcn_s_barrier();
      const size_t tn = (size_t)(kt + 1) * BT;
#pragma unroll
      for (int i = 0; i < 2; ++i) gload16(gV[i] + tn, lV[i]);
      // prove K(t+1): queue [K3,V2] -> vmcnt(2)
      __builtin_amdgcn_s_waitcnt(WAIT_VM2);
      __builtin_amdgcn_s_barrier();
      __builtin_amdgcn_sched_barrier(0);
    }
  }

  // epilogue: write unnormalized partials ([128][128] per slot)
  short* op = Opart + (size_t)slot * (128 * 128);
#pragma unroll
  for (int ch = 0; ch < 8; ++ch)
#pragma unroll
    for (int r = 0; r < 4; ++r)
      op[(wave * 16 + quad * 4 + r) * 128 + ch * 16 + lane15] = f2bf(oacc[ch][r]);

  // row sums: reduce per-lane partials across quads (same lane15)
  float s = lsum_l;
  s += __shfl_xor(s, 16, 64);
  s += __shfl_xor(s, 32, 64);
  if (quad == 0)
    lpart[(size_t)slot * 128 + wave * 16 + lane15] = s;
}

// ---------------------------------------------------------------------------
// Phase B: sum chunk partials, normalize, write COMPACT aob [2048][2048] bf16.
// ---------------------------------------------------------------------------
__global__ __launch_bounds__(256) void attn_combine(
    const short* __restrict__ Opart, const float* __restrict__ lpart,
    short* __restrict__ aob) {   // compact [SEQ][VD], row stride VD=2048
  const int qt64 = blockIdx.x, h = blockIdx.y;
  const int qtb = qt64 >> 1;
  const int half = qt64 & 1;
  const int g = qtb >> 2;
  const int nact = g + 1;
  const int base = h * 40 + (g + 1) * (2 * g + (qtb & 3));
  const int tid = threadIdx.x;
  const int row = tid >> 2;            // 0..63
  const int cg = (tid & 3) * 32;

  float acc[32];
#pragma unroll
  for (int e = 0; e < 32; ++e) acc[e] = 0.f;
  float lsum = 0.f;

  for (int c = 0; c < nact; ++c) {
    const short* sp = Opart + (size_t)(base + c) * (128 * 128) +
                      (half * 64 + row) * 128 + cg;
    lsum += lpart[(size_t)(base + c) * 128 + half * 64 + row];
#pragma unroll
    for (int gg = 0; gg < 4; ++gg) {
      short8 vv = *(const short8*)(sp + gg * 8);
#pragma unroll
      for (int e = 0; e < 8; ++e) acc[gg * 8 + e] += bf2f((unsigned short)vv[e]);
    }
  }

  float inv = 1.f / lsum;
#pragma unroll
  for (int gg = 0; gg < 4; ++gg) {
    short8 ov;
#pragma unroll
    for (int e = 0; e < 8; ++e) ov[e] = f2bf(acc[gg * 8 + e] * inv);
    *(short8*)(aob + (size_t)(qt64 * 64 + row) * VD + h * 128 + cg + gg * 8) = ov;
  }
}

// ---------------------------------------------------------------------------
// Workspace (bytes), peak 75,497,472 (< proven 79,691,776):
//   [0,        8388608)  xb  -> wo_b (after qkv gemm)
//   [8388608, 41943040)  wqkv -> {vtb@8388608, Opart@16777216 (20,971,520),
//                        lpart@37748736 (327,680)}
//   [41943040,75497472)  qkv bf16 [2048][8192]; AFTER attn_combine, qkv is
//                        dead and compact aob [2048][2048] bf16 (8 MB) lives
//                        at the qkv base.
// ---------------------------------------------------------------------------
extern "C" void kernel_launch(void* const* d_in, const int* in_sizes, int n_in,
                              void* d_out, int out_size, void* d_ws, size_t ws_size,
                              hipStream_t stream) {
  const float* x  = (const float*)d_in[0];
  const float* wq = (const float*)d_in[1];
  const float* wk = (const float*)d_in[2];
  const float* wv = (const float*)d_in[3];
  const float* wo = (const float*)d_in[4];
  const float* fc = (const float*)d_in[5];
  const float* fs = (const float*)d_in[6];

  char* ws8 = (char*)d_ws;
  short* xb    = (short*)(ws8 + 0);
  short* wo_b  = (short*)(ws8 + 0);
  short* wqkv  = (short*)(ws8 + 8388608);
  short* vtb   = (short*)(ws8 + 8388608);
  short* Opart = (short*)(ws8 + 16777216);
  float* lpart = (float*)(ws8 + 37748736);
  short* qkv   = (short*)(ws8 + 41943040);
  short* aob   = qkv;   // compact aob overwrites dead qkv after attn_combine
  float* out   = (float*)d_out;

  const int NX4 = DIM * DIM / 4;
  const int NQKV4 = QKVS * DIM / 4;

  // fused input converts (x + wq|wk|wv), one launch
  conv_in<<<(NX4 + NQKV4) / 256, 256, 0, stream>>>(x, wq, wk, wv, xb, wqkv);

  // fused QKV projection: qkv [2048][8192] via 256^2 kernel (m201-layout).
  gemm256_bt<<<dim3((QKVS / 256) * (SEQ / 256)), 512, 0, stream>>>(
      xb, wqkv, qkv, DIM, DIM, DIM, QKVS);

  // fused post-QKV: RoPE + v-transpose + wo convert (one launch, 3 branches)
  post_qkv<<<ROPE_BLKS + VT_BLKS + WO_BLKS, 256, 0, stream>>>(
      qkv, fc, fs, vtb, wo, wo_b);

  // split-T attention: grid (8 xcd, 80 chunks) = 640 blocks, 512 threads
  attn_part<<<dim3(8, 80), 512, 0, stream>>>(qkv, vtb, Opart, lpart);
  attn_combine<<<dim3(SEQ / 64, NH), 256, 0, stream>>>(Opart, lpart, aob);

  // output projection: A = compact aob (lda = VD), coalesced-staging 128^2
  gemm128_bt<false><<<dim3(256), 256, 0, stream>>>(
      aob, wo_b, out, DIM, VD, DIM, DIM, 1.0f);
}

// Round 14
// 291.163 us; speedup vs baseline: 1.1227x; 1.0185x over previous
//
#include <hip/hip_runtime.h>
#include <hip/hip_bf16.h>
#include <math.h>

#define NH 16
#define NOPE 128
#define ROPE 64
#define VDIM 128
#define HD 192          // HEAD_DIM
#define SEQ 2048
#define DIM 2048
#define QKD (NH * HD)   // 3072
#define VD  (NH * VDIM) // 2048
#define QKVS 8192       // fused q|k|v row stride (shorts): [q 3072][k 3072][v 2048]

typedef __attribute__((ext_vector_type(8))) short short8;   // 8 bf16 = 4 VGPRs
typedef __attribute__((ext_vector_type(4))) short short4v;
typedef __attribute__((ext_vector_type(4))) float f32x4;
typedef unsigned int u32;

// s_waitcnt immediates (gfx9 encoding: vmcnt[3:0]@0, expcnt@4, lgkmcnt@8, vmcnt[5:4]@14)
#define WAIT_VM8  0x0F78   // vmcnt(8)
#define WAIT_VM6  0x0F76   // vmcnt(6)
#define WAIT_VM4  0x0F74   // vmcnt(4)
#define WAIT_VM3  0x0F73   // vmcnt(3)
#define WAIT_VM2  0x0F72   // vmcnt(2)
#define WAIT_VM0  0x0F70   // vmcnt(0)
#define WAIT_LGKM 0xC07F   // lgkmcnt(0), vmcnt/exp no-wait

static __device__ inline short f2bf(float f) {
  union { float f; unsigned u; } v; v.f = f;
  unsigned r = (v.u + 0x7fffu + ((v.u >> 16) & 1u)) >> 16;
  return (short)r;
}
static __device__ inline u32 packbf(float lo, float hi) {
  return (u32)(unsigned short)f2bf(lo) | ((u32)(unsigned short)f2bf(hi) << 16);
}
static __device__ inline float bf2f(unsigned short u) {
  union { unsigned u; float f; } v; v.u = ((unsigned)u) << 16;
  return v.f;
}

// async global->LDS, 16B/lane. LDS dest = wave-uniform base + lane*16.
static __device__ __forceinline__ void gload16(const short* g, short* l) {
  __builtin_amdgcn_global_load_lds(
      (const __attribute__((address_space(1))) u32*)g,
      (__attribute__((address_space(3))) u32*)l, 16, 0, 0);
}

// ---------------------------------------------------------------------------
// 256x256 bf16 GEMM, C = A * B^T.  R14: per-phase distributed staging
// (2 gloads EVERY phase, m201/m196 pattern) instead of 4-load bursts at
// P1/P4. Ledger: 12 outstanding at each P4-wait; vmcnt(4) proves tile t+1's
// 8 oldest; never 0 mid-loop. Chunk lifetimes:
//   t.P1 stages A-hi(t+1) [other buf], t.P2 stages B-hi(t+1) [other buf],
//   t.P3 stages B-lo(t+2) [this buf; B-lo last read t.P1, 2 barriers ago],
//   t.P4 stages A-lo(t+2) [this buf; A-lo last read t.P2].
// ---------------------------------------------------------------------------

#define LSA(pp) (Lsm + (pp) * 65536)
#define LSB(pp) (Lsm + (pp) * 65536 + 32768)

#define RDA(pp, kh, mh) do { \
  const char* p_ = LSA(pp) + abase + (mh) * 8192 + ((kh) ? cx1 : cx0); \
  afr[(mh) * 4 + 0] = *(const short8*)(p_ + 0); \
  afr[(mh) * 4 + 1] = *(const short8*)(p_ + 2048); \
  afr[(mh) * 4 + 2] = *(const short8*)(p_ + 4096); \
  afr[(mh) * 4 + 3] = *(const short8*)(p_ + 6144); \
} while (0)

#define RDB(pp, kh) do { \
  const char* p_ = LSB(pp) + bbase + ((kh) ? cx1 : cx0); \
  bfr[0] = *(const short8*)(p_ + 0); \
  bfr[1] = *(const short8*)(p_ + 2048); \
  bfr[2] = *(const short8*)(p_ + 4096); \
  bfr[3] = *(const short8*)(p_ + 6144); \
} while (0)

#define SGA(kt, c) gload16(srcA[c] + (kt) * 64, (short*)(LSA((kt) & 1) + ((c) * 512 + tid) * 16))
#define SGB(kt, c) gload16(srcB[c] + (kt) * 64, (short*)(LSB((kt) & 1) + ((c) * 512 + tid) * 16))
// lo = chunks {0,2} (A) / {0,1} (B): read at P1/P2. hi = the complements.
#define A_LO(kt) do { SGA(kt, 0); SGA(kt, 2); } while (0)
#define A_HI(kt) do { SGA(kt, 1); SGA(kt, 3); } while (0)
#define B_LO(kt) do { SGB(kt, 0); SGB(kt, 1); } while (0)
#define B_HI(kt) do { SGB(kt, 2); SGB(kt, 3); } while (0)

#define MFMA1(mi, ni) \
  acc[mi][ni] = __builtin_amdgcn_mfma_f32_16x16x32_bf16(afr[mi], bfr[ni], acc[mi][ni], 0, 0, 0)

#define MM(mh) do { \
  MFMA1((mh)*4+0, 0); MFMA1((mh)*4+1, 0); MFMA1((mh)*4+2, 0); MFMA1((mh)*4+3, 0); \
  MFMA1((mh)*4+0, 1); MFMA1((mh)*4+1, 1); MFMA1((mh)*4+2, 1); MFMA1((mh)*4+3, 1); \
  MFMA1((mh)*4+0, 2); MFMA1((mh)*4+1, 2); MFMA1((mh)*4+2, 2); MFMA1((mh)*4+3, 2); \
  MFMA1((mh)*4+0, 3); MFMA1((mh)*4+1, 3); MFMA1((mh)*4+2, 3); MFMA1((mh)*4+3, 3); \
} while (0)

#define GBAR() __builtin_amdgcn_s_barrier()
#define GLGKM0() __builtin_amdgcn_s_waitcnt(WAIT_LGKM)
#define GPRIO1() __builtin_amdgcn_s_setprio(1)
#define GPRIO0() __builtin_amdgcn_s_setprio(0)
#define GNOP ((void)0)

// One K-tile = 4 phases; one stage slot per phase; counted wait at P4.
#define TILE(pp, S1, S2, S3, S4, VMW) do { \
  RDA(pp, 0, 0); RDB(pp, 0); S1; \
  GBAR(); GLGKM0(); GPRIO1(); MM(0); GPRIO0(); GBAR(); \
  RDA(pp, 0, 1); S2; \
  GBAR(); GLGKM0(); GPRIO1(); MM(1); GPRIO0(); GBAR(); \
  RDA(pp, 1, 0); RDB(pp, 1); S3; \
  GBAR(); GLGKM0(); GPRIO1(); MM(0); GPRIO0(); GBAR(); \
  RDA(pp, 1, 1); S4; \
  GBAR(); GLGKM0(); GPRIO1(); MM(1); GPRIO0(); VMW; GBAR(); \
} while (0)

__global__ __launch_bounds__(512, 2) void gemm256_bt(
    const short* __restrict__ A, const short* __restrict__ B,
    short* __restrict__ C, int K, int lda, int ldb, int ldc) {
  __shared__ __align__(16) char Lsm[131072];

  const int tid = threadIdx.x;
  const int lane = tid & 63;
  const int l15 = lane & 15;
  const int quad = lane >> 4;      // 0..3
  const int wv = tid >> 6;         // 0..7
  const int wr = wv >> 2, wc = wv & 3;

  // 8Mx4N per-XCD partition (R6).
  const int bid = blockIdx.x;
  const int xcd = bid & 7;
  const int idx = bid >> 3;              // 0..31 within XCD
  const int m0 = (idx & 7) * 256;        // 8 M panels
  const int n0 = (xcd * 4 + (idx >> 3)) * 256;  // 4 N panels per XCD

  // staging sources: linear LDS dest + inverse-swizzled global source (R8).
  const int trow = tid >> 3;                               // 0..63
  const int scol = ((tid & 7) * 8) ^ ((trow & 7) * 8);     // shorts
  const short* srcA[4]; const short* srcB[4];
#pragma unroll
  for (int c = 0; c < 4; ++c) {
    srcA[c] = A + (size_t)(m0 + c * 64 + trow) * lda + scol;
    srcB[c] = B + (size_t)(n0 + c * 64 + trow) * ldb + scol;
  }

  // ds_read bases (bytes): row = {wr*128|wc*64} + sub + l15; swizzled col.
  const int abase = (wr * 128 + l15) * 128;
  const int bbase = (wc * 64 + l15) * 128;
  const int cx0 = (quad * 16) ^ ((l15 & 7) * 16);          // kh = 0
  const int cx1 = (64 + quad * 16) ^ ((l15 & 7) * 16);     // kh = 1

  f32x4 acc[8][4];
#pragma unroll
  for (int i = 0; i < 8; ++i)
#pragma unroll
    for (int j = 0; j < 4; ++j) acc[i][j] = (f32x4)(0.f);
  short8 afr[8], bfr[4];

  const int NT = K >> 6;   // even, >= 4

  // prologue: tile0 all 8 + {A-lo,B-lo}(1) = 12; vmcnt(4) proves tile0,
  // keeps {A-lo,B-lo}(1) in flight (steady-state entry).
  A_LO(0); B_LO(0); A_HI(0); B_HI(0);
  A_LO(1); B_LO(1);
  __builtin_amdgcn_s_waitcnt(WAIT_VM4);
  GBAR();

  int kt = 0;
  for (; kt + 4 <= NT; kt += 2) {
    TILE(0, A_HI(kt + 1), B_HI(kt + 1), B_LO(kt + 2), A_LO(kt + 2),
         __builtin_amdgcn_s_waitcnt(WAIT_VM4));
    TILE(1, A_HI(kt + 2), B_HI(kt + 2), B_LO(kt + 3), A_LO(kt + 3),
         __builtin_amdgcn_s_waitcnt(WAIT_VM4));
  }
  // tail: kt == NT-2. Finish tile NT-1's hi-chunks; vmcnt(0) proves all.
  TILE(0, A_HI(kt + 1), B_HI(kt + 1), GNOP, GNOP,
       __builtin_amdgcn_s_waitcnt(WAIT_VM0));
  TILE(1, GNOP, GNOP, GNOP, GNOP, GNOP);

#pragma unroll
  for (int m = 0; m < 8; ++m) {
    const size_t rb = (size_t)(m0 + wr * 128 + m * 16 + quad * 4) * ldc +
                      n0 + wc * 64 + l15;
#pragma unroll
    for (int n = 0; n < 4; ++n)
#pragma unroll
      for (int r = 0; r < 4; ++r)
        C[rb + (size_t)r * ldc + n * 16] = f2bf(acc[m][n][r]);
  }
}

// ---------------------------------------------------------------------------
// 128x128 bf16 GEMM v3 (output projection): unchanged from R13.
// ---------------------------------------------------------------------------
template <bool BF16OUT>
__global__ __launch_bounds__(256, 2) void gemm128_bt(
    const short* __restrict__ A, const short* __restrict__ B,
    void* __restrict__ Cv, int K, int lda, int ldb, int ldc, float oscale) {
  __shared__ __align__(16) short Ls[2][2][8192];  // [buf][A|B][128 rows][64]

  const int tid = threadIdx.x;
  const int lane = tid & 63;
  const int l15 = lane & 15;
  const int quad = lane >> 4;
  const int wave = tid >> 6;            // 4 waves, 2M x 2N
  const int wr = wave >> 1, wc = wave & 1;

  const int bid = blockIdx.x;
  const int xcd = bid & 7;
  const int ii = bid >> 3;                       // 0..31
  const int m0 = (((xcd & 3) << 2) + (ii & 3)) * 128;
  const int n0 = (((xcd >> 2) << 3) + (ii >> 2)) * 128;

  const int trow = tid >> 3;                     // 0..31
  const int scol = (((tid & 7) ^ (trow & 7))) * 8;
  const short* srcA[4]; const short* srcB[4];
#pragma unroll
  for (int c = 0; c < 4; ++c) {
    srcA[c] = A + (size_t)(m0 + c * 32 + trow) * lda + scol;
    srcB[c] = B + (size_t)(n0 + c * 32 + trow) * ldb + scol;
  }

  f32x4 acc[4][4];
#pragma unroll
  for (int i = 0; i < 4; ++i)
#pragma unroll
    for (int j = 0; j < 4; ++j) acc[i][j] = (f32x4)(0.f);

  const int NT = K >> 6;

#pragma unroll
  for (int c = 0; c < 4; ++c) gload16(srcA[c], &Ls[0][0][(c * 256 + tid) * 8]);
#pragma unroll
  for (int c = 0; c < 4; ++c) gload16(srcB[c], &Ls[0][1][(c * 256 + tid) * 8]);

  for (int kt = 0; kt < NT; ++kt) {
    const int cur = kt & 1;
    if (kt + 1 < NT) {
      const int kc = (kt + 1) * 64;
#pragma unroll
      for (int c = 0; c < 4; ++c)
        gload16(srcA[c] + kc, &Ls[cur ^ 1][0][(c * 256 + tid) * 8]);
#pragma unroll
      for (int c = 0; c < 4; ++c)
        gload16(srcB[c] + kc, &Ls[cur ^ 1][1][(c * 256 + tid) * 8]);
      __builtin_amdgcn_s_waitcnt(WAIT_VM8);
    } else {
      __builtin_amdgcn_s_waitcnt(WAIT_VM0);
    }
    __builtin_amdgcn_s_barrier();

    const short* la = &Ls[cur][0][0];
    const short* lb = &Ls[cur][1][0];
#pragma unroll
    for (int kh = 0; kh < 2; ++kh) {
      short8 af[4], bfv[4];
#pragma unroll
      for (int m = 0; m < 4; ++m) {
        int row = wr * 64 + m * 16 + l15;
        int ch = (kh * 4 + quad) ^ (l15 & 7);
        af[m] = *(const short8*)&la[row * 64 + ch * 8];
      }
#pragma unroll
      for (int n = 0; n < 4; ++n) {
        int row = wc * 64 + n * 16 + l15;
        int ch = (kh * 4 + quad) ^ (l15 & 7);
        bfv[n] = *(const short8*)&lb[row * 64 + ch * 8];
      }
      __builtin_amdgcn_s_setprio(1);
#pragma unroll
      for (int m = 0; m < 4; ++m)
#pragma unroll
        for (int n = 0; n < 4; ++n)
          acc[m][n] = __builtin_amdgcn_mfma_f32_16x16x32_bf16(af[m], bfv[n], acc[m][n], 0, 0, 0);
      __builtin_amdgcn_s_setprio(0);
    }
    __builtin_amdgcn_s_waitcnt(WAIT_LGKM);
    __builtin_amdgcn_s_barrier();
  }

#pragma unroll
  for (int i = 0; i < 4; ++i)
#pragma unroll
    for (int j = 0; j < 4; ++j)
#pragma unroll
      for (int r = 0; r < 4; ++r) {
        size_t idx = (size_t)(m0 + wr * 64 + i * 16 + quad * 4 + r) * ldc +
                     n0 + wc * 64 + j * 16 + l15;
        if (BF16OUT)
          ((short*)Cv)[idx] = f2bf(acc[i][j][r] * oscale);
        else
          ((float*)Cv)[idx] = acc[i][j][r];
      }
}

// ---------------------------------------------------------------------------
// Fused input converts: x -> xb and wq|wk|wv -> wqkv (one launch).
// ---------------------------------------------------------------------------
__global__ __launch_bounds__(256) void conv_in(
    const float* __restrict__ x, const float* __restrict__ wq,
    const float* __restrict__ wk, const float* __restrict__ wv,
    short* __restrict__ xb, short* __restrict__ wqkv) {
  const int NX4v = DIM * DIM / 4;
  int i = blockIdx.x * 256 + threadIdx.x;
  float4 f; short* dst; int di;
  if (i < NX4v) {
    f = ((const float4*)x)[i]; dst = xb; di = i;
  } else {
    int j = i - NX4v;
    int row = j >> 9;
    if (row < QKD) f = ((const float4*)wq)[j];
    else if (row < 2 * QKD) f = ((const float4*)wk)[j - QKD * (DIM / 4)];
    else f = ((const float4*)wv)[j - 2 * QKD * (DIM / 4)];
    dst = wqkv; di = j;
  }
  short4v o;
  o.x = f2bf(f.x); o.y = f2bf(f.y); o.z = f2bf(f.z); o.w = f2bf(f.w);
  ((short4v*)dst)[di] = o;
}

// ---------------------------------------------------------------------------
// Fused post-QKV kernel: RoPE | v-transpose | wo-convert (block-range branch).
// ---------------------------------------------------------------------------
#define ROPE_BLKS 4096
#define VT_BLKS   1024
#define WO_BLKS   4096

__global__ __launch_bounds__(256) void post_qkv(
    short* __restrict__ qkv, const float* __restrict__ cosf,
    const float* __restrict__ sinf, short* __restrict__ vtb,
    const float* __restrict__ wo, short* __restrict__ wo_b) {
  __shared__ short tile[64][74];
  const int b = blockIdx.x;
  const int tid = threadIdx.x;

  if (b < ROPE_BLKS) {
    // ---- RoPE ----
    int idx = b * 256 + tid;
    int j = idx & 31;
    int h = (idx >> 5) & (NH - 1);
    int s = idx >> 9;

    float c = cosf[s * 32 + j];
    float sn = sinf[s * 32 + j];
    size_t rowb = (size_t)s * QKVS + h * HD + NOPE + 2 * j;

    u32* pq = (u32*)(qkv + rowb);
    u32 w = *pq;
    float a = bf2f((unsigned short)(w & 0xffff));
    float bb = bf2f((unsigned short)(w >> 16));
    *pq = packbf(a * c - bb * sn, a * sn + bb * c);

    u32* pk = (u32*)(qkv + rowb + QKD);
    w = *pk;
    a = bf2f((unsigned short)(w & 0xffff));
    bb = bf2f((unsigned short)(w >> 16));
    *pk = packbf(a * c - bb * sn, a * sn + bb * c);
  } else if (b < ROPE_BLKS + VT_BLKS) {
    // ---- v transpose ----
    const int bb = b - ROPE_BLKS;
    const int t0 = (bb & 31) * 64;
    const int c0 = (bb >> 5) * 64;
    const short* vb = qkv + 2 * QKD;
#pragma unroll
    for (int i = 0; i < 16; ++i) {
      int idx = i * 256 + tid;
      int r = idx >> 6, c = idx & 63;
      tile[r][c] = vb[(size_t)(t0 + r) * QKVS + c0 + c];
    }
    __syncthreads();
    const int h = c0 >> 7;
    const int dbase = c0 & 127;
#pragma unroll
    for (int i = 0; i < 16; ++i) {
      int idx = i * 256 + tid;
      int d = idx >> 6, t = idx & 63;
      vtb[(size_t)h * VDIM * SEQ + (size_t)(dbase + d) * SEQ + t0 + t] = tile[t][d];
    }
  } else {
    // ---- wo convert ----
    int i = (b - ROPE_BLKS - VT_BLKS) * 256 + tid;
    float4 f = ((const float4*)wo)[i];
    short4v o;
    o.x = f2bf(f.x); o.y = f2bf(f.y); o.z = f2bf(f.z); o.w = f2bf(f.w);
    ((short4v*)wo_b)[i] = o;
  }
}

// ---------------------------------------------------------------------------
// Split-T flash attention v6 (unchanged from R11): swapped-QK^T in-register
// softmax; K dbuf, V single, 3 barriers/tile, counted vmcnt never 0 mid-loop.
// LDS = 49152 + 16384 = 65536 -> 2 blocks/CU.
// ---------------------------------------------------------------------------
#define BQ 128
#define BT 64
#define CHT 8
#define MFIX 8.0f

__global__ __launch_bounds__(512, 4) void attn_part(
    const short* __restrict__ qk,   // [SEQ][QKVS] bf16
    const short* __restrict__ vtb,  // [NH][VDIM][SEQ] bf16
    short* __restrict__ Opart,      // [640][128][128] bf16
    float* __restrict__ lpart)      // [640][128] fp32
{
  __shared__ __align__(16) short Ks[2][BT * 192];    // 49152 B
  __shared__ __align__(16) short Vt[VDIM * BT];      // 16384 B

  // decode: xcd owns heads {xcd, xcd+8}; heavy qt-blocks first.
  const int xcd = blockIdx.x;          // 0..7
  const int i0 = blockIdx.y;           // 0..79
  const int h = xcd + ((i0 >= 40) ? 8 : 0);
  int jj = (i0 >= 40) ? (i0 - 40) : i0;  // 0..39
  int qtb = 15;
  while (jj >= (qtb >> 2) + 1) { jj -= (qtb >> 2) + 1; --qtb; }
  const int chk = jj;                   // 0..(qtb>>2)

  const int tid = threadIdx.x;
  const int wave = tid >> 6;            // 0..7
  const int lane = tid & 63;
  const int lane15 = lane & 15;
  const int quad = lane >> 4;
  const int g = qtb >> 2;
  const int slot = h * 40 + (g + 1) * (2 * g + (qtb & 3)) + chk;
  const int R0 = qtb * BQ;
  const int NT = 2 * qtb + 2;
  const int kt_beg = chk * CHT;
  const int kt_end = min(kt_beg + CHT, NT);
  const float scale = 0.072168784f;  // 1/sqrt(192)

  // Q frags: wave's 16 rows (identical layout either operand side).
  const int qrow = R0 + wave * 16 + lane15;
  short8 qf[6];
  const short* qbase = qk + (size_t)qrow * QKVS + h * HD + quad * 8;
#pragma unroll
  for (int kc = 0; kc < 6; ++kc) qf[kc] = *(const short8*)(qbase + kc * 32);
  __builtin_amdgcn_s_waitcnt(WAIT_VM0);
  __builtin_amdgcn_sched_barrier(0);

  // staging descriptors (XOR-swizzled), 512 threads: K 3/thread, V 2/thread
  const short* kb = qk + QKD;
  int lKoff[3]; const short* gK[3];
#pragma unroll
  for (int i = 0; i < 3; ++i) {
    int id = i * 512 + tid;
    int row = id / 24, cX = id - row * 24;
    int ch = cX ^ (row & 7);
    lKoff[i] = id * 8;
    gK[i] = kb + (size_t)row * QKVS + h * HD + ch * 8;
  }
  const short* gV[2]; short* lV[2];
#pragma unroll
  for (int i = 0; i < 2; ++i) {
    int id = i * 512 + tid;
    int row = id >> 3, cX = id & 7;
    int ch = cX ^ (row & 7);
    lV[i] = &Vt[id * 8];
    gV[i] = vtb + (size_t)h * VDIM * SEQ + (size_t)row * SEQ + ch * 8;
  }

  f32x4 oacc[8];
#pragma unroll
  for (int i = 0; i < 8; ++i) oacc[i] = (f32x4)(0.f);
  float lsum_l = 0.f;   // per-lane: partial row sum of q-row (wave*16+lane15)

  // shuffle source lanes for PV A-frag assembly
  const int sA = ((lane >> 4) & 1) * 32 + lane15;
  const int sB = sA + 16;
  const bool hiC = (quad >> 1) != 0;   // this lane's frag uses odd c-block src

  // prologue: stage K(t0)->Ks[0] (3) + V(t0)->Vt (2); vmcnt(2) proves K.
  {
    const size_t t0 = (size_t)kt_beg * BT;
#pragma unroll
    for (int i = 0; i < 3; ++i) gload16(gK[i] + t0 * QKVS, &Ks[0][lKoff[i]]);
#pragma unroll
    for (int i = 0; i < 2; ++i) gload16(gV[i] + t0, lV[i]);
  }
  __builtin_amdgcn_s_waitcnt(WAIT_VM2);
  __builtin_amdgcn_s_barrier();
  __builtin_amdgcn_sched_barrier(0);

  for (int kt = kt_beg; kt < kt_end; ++kt) {
    const int cur = (kt - kt_beg) & 1;
    const bool have = (kt + 1 < kt_end);

    // issue K(t+1) -> Ks[nxt]
    if (have) {
      const size_t tn = (size_t)(kt + 1) * BT;
#pragma unroll
      for (int i = 0; i < 3; ++i) gload16(gK[i] + tn * QKVS, &Ks[cur ^ 1][lKoff[i]]);
    }

    // S = (K Q^T) swapped: sacc[c][r] = S[t = c*16+quad*4+r][q = lane15]
    const short* kcur = &Ks[cur][0];
    f32x4 sacc[4];
    __builtin_amdgcn_s_setprio(1);
#pragma unroll
    for (int c = 0; c < 4; ++c) {
      sacc[c] = (f32x4)(0.f);
      const int row = c * 16 + lane15;
#pragma unroll
      for (int kc = 0; kc < 6; ++kc) {
        int cX = (4 * kc + quad) ^ (lane15 & 7);
        short8 kf = *(const short8*)&kcur[row * 192 + cX * 8];
        sacc[c] = __builtin_amdgcn_mfma_f32_16x16x32_bf16(kf, qf[kc], sacc[c], 0, 0, 0);
      }
    }
    __builtin_amdgcn_s_setprio(0);

    if (kt >= 2 * qtb) {  // diagonal-crossing tiles: mask t > q
#pragma unroll
      for (int c = 0; c < 4; ++c)
#pragma unroll
        for (int r = 0; r < 4; ++r) {
          int tg = kt * BT + c * 16 + quad * 4 + r;
          int qg = R0 + wave * 16 + lane15;
          if (tg > qg) sacc[c][r] = -1e30f;
        }
    }

    // softmax: p = exp(s*scale - MFIX); per-lane scalar row-sum
#pragma unroll
    for (int c = 0; c < 4; ++c)
#pragma unroll
      for (int r = 0; r < 4; ++r) {
        float p = __expf(sacc[c][r] * scale - MFIX);
        lsum_l += p;
        sacc[c][r] = p;
      }

    // pack p -> bf16 pairs per c-block: w[c][0] = (p0,p1), w[c][1] = (p2,p3)
    u32 w[4][2];
#pragma unroll
    for (int c = 0; c < 4; ++c) {
      w[c][0] = packbf(sacc[c][0], sacc[c][1]);
      w[c][1] = packbf(sacc[c][2], sacc[c][3]);
    }

    // assemble PV A-frags: pf0 (t 0..31 : c-src 0/1), pf1 (t 32..63 : c 2/3)
    union { short8 s; u32 u[4]; } pf0, pf1;
    {
      u32 a0 = __shfl((int)w[0][0], sA), b0 = __shfl((int)w[1][0], sA);
      u32 a1 = __shfl((int)w[0][1], sA), b1 = __shfl((int)w[1][1], sA);
      u32 a2 = __shfl((int)w[0][0], sB), b2 = __shfl((int)w[1][0], sB);
      u32 a3 = __shfl((int)w[0][1], sB), b3 = __shfl((int)w[1][1], sB);
      pf0.u[0] = hiC ? b0 : a0; pf0.u[1] = hiC ? b1 : a1;
      pf0.u[2] = hiC ? b2 : a2; pf0.u[3] = hiC ? b3 : a3;
      u32 c0 = __shfl((int)w[2][0], sA), d0 = __shfl((int)w[3][0], sA);
      u32 c1 = __shfl((int)w[2][1], sA), d1 = __shfl((int)w[3][1], sA);
      u32 c2 = __shfl((int)w[2][0], sB), d2 = __shfl((int)w[3][0], sB);
      u32 c3 = __shfl((int)w[2][1], sB), d3 = __shfl((int)w[3][1], sB);
      pf1.u[0] = hiC ? d0 : c0; pf1.u[1] = hiC ? d1 : c1;
      pf1.u[2] = hiC ? d2 : c2; pf1.u[3] = hiC ? d3 : c3;
    }

    // prove V(t): queue [V2,K3] -> vmcnt(3); last iter [V2] -> vmcnt(0)
    if (have) __builtin_amdgcn_s_waitcnt(WAIT_VM3);
    else      __builtin_amdgcn_s_waitcnt(WAIT_VM0);
    __builtin_amdgcn_s_barrier();
    __builtin_amdgcn_sched_barrier(0);

    // PV (single pass, 16 MFMA)
    __builtin_amdgcn_s_setprio(1);
#pragma unroll
    for (int ch = 0; ch < 8; ++ch) {
      const int row = ch * 16 + lane15;
      int cX0 = quad ^ (lane15 & 7);
      int cX1 = (4 + quad) ^ (lane15 & 7);
      short8 vf0 = *(const short8*)&Vt[row * 64 + cX0 * 8];
      short8 vf1 = *(const short8*)&Vt[row * 64 + cX1 * 8];
      oacc[ch] = __builtin_amdgcn_mfma_f32_16x16x32_bf16(pf0.s, vf0, oacc[ch], 0, 0, 0);
      oacc[ch] = __builtin_amdgcn_mfma_f32_16x16x32_bf16(pf1.s, vf1, oacc[ch], 0, 0, 0);
    }
    __builtin_amdgcn_s_setprio(0);

    if (have) {
      // all waves done reading Vt (and Ks[cur]) -> Vt free
      __builtin_amdgcn_s_waitcnt(WAIT_LGKM);
      __builtin_amdgcn_s_barrier();
      const size_t tn = (size_t)(kt + 1) * BT;
#pragma unroll
      for (int i = 0; i < 2; ++i) gload16(gV[i] + tn, lV[i]);
      // prove K(t+1): queue [K3,V2] -> vmcnt(2)
      __builtin_amdgcn_s_waitcnt(WAIT_VM2);
      __builtin_amdgcn_s_barrier();
      __builtin_amdgcn_sched_barrier(0);
    }
  }

  // epilogue: write unnormalized partials ([128][128] per slot)
  short* op = Opart + (size_t)slot * (128 * 128);
#pragma unroll
  for (int ch = 0; ch < 8; ++ch)
#pragma unroll
    for (int r = 0; r < 4; ++r)
      op[(wave * 16 + quad * 4 + r) * 128 + ch * 16 + lane15] = f2bf(oacc[ch][r]);

  // row sums: reduce per-lane partials across quads (same lane15)
  float s = lsum_l;
  s += __shfl_xor(s, 16, 64);
  s += __shfl_xor(s, 32, 64);
  if (quad == 0)
    lpart[(size_t)slot * 128 + wave * 16 + lane15] = s;
}

// ---------------------------------------------------------------------------
// Phase B: sum chunk partials, normalize, write COMPACT aob [2048][2048] bf16.
// ---------------------------------------------------------------------------
__global__ __launch_bounds__(256) void attn_combine(
    const short* __restrict__ Opart, const float* __restrict__ lpart,
    short* __restrict__ aob) {   // compact [SEQ][VD], row stride VD=2048
  const int qt64 = blockIdx.x, h = blockIdx.y;
  const int qtb = qt64 >> 1;
  const int half = qt64 & 1;
  const int g = qtb >> 2;
  const int nact = g + 1;
  const int base = h * 40 + (g + 1) * (2 * g + (qtb & 3));
  const int tid = threadIdx.x;
  const int row = tid >> 2;            // 0..63
  const int cg = (tid & 3) * 32;

  float acc[32];
#pragma unroll
  for (int e = 0; e < 32; ++e) acc[e] = 0.f;
  float lsum = 0.f;

  for (int c = 0; c < nact; ++c) {
    const short* sp = Opart + (size_t)(base + c) * (128 * 128) +
                      (half * 64 + row) * 128 + cg;
    lsum += lpart[(size_t)(base + c) * 128 + half * 64 + row];
#pragma unroll
    for (int gg = 0; gg < 4; ++gg) {
      short8 vv = *(const short8*)(sp + gg * 8);
#pragma unroll
      for (int e = 0; e < 8; ++e) acc[gg * 8 + e] += bf2f((unsigned short)vv[e]);
    }
  }

  float inv = 1.f / lsum;
#pragma unroll
  for (int gg = 0; gg < 4; ++gg) {
    short8 ov;
#pragma unroll
    for (int e = 0; e < 8; ++e) ov[e] = f2bf(acc[gg * 8 + e] * inv);
    *(short8*)(aob + (size_t)(qt64 * 64 + row) * VD + h * 128 + cg + gg * 8) = ov;
  }
}

// ---------------------------------------------------------------------------
// Workspace (bytes), peak 75,497,472 (< proven 79,691,776):
//   [0,        8388608)  xb  -> wo_b (after qkv gemm)
//   [8388608, 41943040)  wqkv -> {vtb@8388608, Opart@16777216 (20,971,520),
//                        lpart@37748736 (327,680)}
//   [41943040,75497472)  qkv bf16 [2048][8192]; AFTER attn_combine, qkv is
//                        dead and compact aob [2048][2048] bf16 (8 MB) lives
//                        at the qkv base.
// ---------------------------------------------------------------------------
extern "C" void kernel_launch(void* const* d_in, const int* in_sizes, int n_in,
                              void* d_out, int out_size, void* d_ws, size_t ws_size,
                              hipStream_t stream) {
  const float* x  = (const float*)d_in[0];
  const float* wq = (const float*)d_in[1];
  const float* wk = (const float*)d_in[2];
  const float* wv = (const float*)d_in[3];
  const float* wo = (const float*)d_in[4];
  const float* fc = (const float*)d_in[5];
  const float* fs = (const float*)d_in[6];

  char* ws8 = (char*)d_ws;
  short* xb    = (short*)(ws8 + 0);
  short* wo_b  = (short*)(ws8 + 0);
  short* wqkv  = (short*)(ws8 + 8388608);
  short* vtb   = (short*)(ws8 + 8388608);
  short* Opart = (short*)(ws8 + 16777216);
  float* lpart = (float*)(ws8 + 37748736);
  short* qkv   = (short*)(ws8 + 41943040);
  short* aob   = qkv;   // compact aob overwrites dead qkv after attn_combine
  float* out   = (float*)d_out;

  const int NX4 = DIM * DIM / 4;
  const int NQKV4 = QKVS * DIM / 4;

  // fused input converts (x + wq|wk|wv), one launch
  conv_in<<<(NX4 + NQKV4) / 256, 256, 0, stream>>>(x, wq, wk, wv, xb, wqkv);

  // fused QKV projection: qkv [2048][8192] via 256^2 kernel (m201-layout,
  // per-phase distributed staging).
  gemm256_bt<<<dim3((QKVS / 256) * (SEQ / 256)), 512, 0, stream>>>(
      xb, wqkv, qkv, DIM, DIM, DIM, QKVS);

  // fused post-QKV: RoPE + v-transpose + wo convert (one launch, 3 branches)
  post_qkv<<<ROPE_BLKS + VT_BLKS + WO_BLKS, 256, 0, stream>>>(
      qkv, fc, fs, vtb, wo, wo_b);

  // split-T attention: grid (8 xcd, 80 chunks) = 640 blocks, 512 threads
  attn_part<<<dim3(8, 80), 512, 0, stream>>>(qkv, vtb, Opart, lpart);
  attn_combine<<<dim3(SEQ / 64, NH), 256, 0, stream>>>(Opart, lpart, aob);

  // output projection: A = compact aob (lda = VD), coalesced-staging 128^2
  gemm128_bt<false><<<dim3(256), 256, 0, stream>>>(
      aob, wo_b, out, DIM, VD, DIM, DIM, 1.0f);
}